// Round 1
// baseline (2451.105 us; speedup 1.0000x reference)
//
#include <hip/hip_runtime.h>
#include <hip/hip_bf16.h>
#include <math.h>

#define B_ 2
#define S_ 1024
#define D_ 1024
#define H_ 16
#define HD_ 64
#define F_ 4096
#define M_ 2048
#define DC_ 256
#define NTOK (B_*S_)

// ---------------- GEMM: C[M,N] = A[M,K] @ B[K,N] (+resid / +=) ----------------
// BT: B is stored transposed, i.e. logical B[k][n] = Bm[n*ldb + k]
// ACC: C += A@B  (resid ignored). Otherwise C = A@B + (resid ? resid : 0).
// All dims must be multiples of 64 (M,N) and 16 (K). True for every call here.
template<bool BT, bool ACC>
__global__ __launch_bounds__(256) void gemm_kernel(
    const float* __restrict__ A, const float* __restrict__ Bm,
    const float* __restrict__ resid, float* __restrict__ C,
    int M, int N, int K, int lda, int ldb, int ldc)
{
    __shared__ float As[16][64];
    __shared__ float Bs[16][64];
    const int tx = threadIdx.x, ty = threadIdx.y;
    const int tid = ty * 16 + tx;
    const int row0 = blockIdx.y * 64, col0 = blockIdx.x * 64;
    float acc[4][4] = {};
    const int am  = tid >> 2;          // 0..63
    const int akq = (tid & 3) * 4;     // 0,4,8,12
    const int bkr = tid >> 4;          // 0..15
    const int bn4 = (tid & 15) * 4;    // 0..60

    for (int k0 = 0; k0 < K; k0 += 16) {
        float4 av = *(const float4*)&A[(size_t)(row0 + am) * lda + k0 + akq];
        As[akq + 0][am] = av.x; As[akq + 1][am] = av.y;
        As[akq + 2][am] = av.z; As[akq + 3][am] = av.w;
        if (!BT) {
            float4 bv = *(const float4*)&Bm[(size_t)(k0 + bkr) * ldb + col0 + bn4];
            Bs[bkr][bn4 + 0] = bv.x; Bs[bkr][bn4 + 1] = bv.y;
            Bs[bkr][bn4 + 2] = bv.z; Bs[bkr][bn4 + 3] = bv.w;
        } else {
            float4 bv = *(const float4*)&Bm[(size_t)(col0 + am) * ldb + k0 + akq];
            Bs[akq + 0][am] = bv.x; Bs[akq + 1][am] = bv.y;
            Bs[akq + 2][am] = bv.z; Bs[akq + 3][am] = bv.w;
        }
        __syncthreads();
        #pragma unroll
        for (int kk = 0; kk < 16; ++kk) {
            float a0 = As[kk][ty * 4 + 0], a1 = As[kk][ty * 4 + 1];
            float a2 = As[kk][ty * 4 + 2], a3 = As[kk][ty * 4 + 3];
            float b0 = Bs[kk][tx * 4 + 0], b1 = Bs[kk][tx * 4 + 1];
            float b2 = Bs[kk][tx * 4 + 2], b3 = Bs[kk][tx * 4 + 3];
            acc[0][0] += a0 * b0; acc[0][1] += a0 * b1; acc[0][2] += a0 * b2; acc[0][3] += a0 * b3;
            acc[1][0] += a1 * b0; acc[1][1] += a1 * b1; acc[1][2] += a1 * b2; acc[1][3] += a1 * b3;
            acc[2][0] += a2 * b0; acc[2][1] += a2 * b1; acc[2][2] += a2 * b2; acc[2][3] += a2 * b3;
            acc[3][0] += a3 * b0; acc[3][1] += a3 * b1; acc[3][2] += a3 * b2; acc[3][3] += a3 * b3;
        }
        __syncthreads();
    }
    #pragma unroll
    for (int i = 0; i < 4; ++i) {
        #pragma unroll
        for (int j = 0; j < 4; ++j) {
            size_t idx = (size_t)(row0 + ty * 4 + i) * ldc + col0 + tx * 4 + j;
            float r = ACC ? C[idx] : (resid ? resid[idx] : 0.f);
            C[idx] = r + acc[i][j];
        }
    }
}

// ---------------- RMSNorm: one block per row (D=1024) ----------------
__global__ __launch_bounds__(256) void rmsnorm_kernel(
    const float* __restrict__ x, const float* __restrict__ w, float* __restrict__ out)
{
    __shared__ float red[4];
    const int row = blockIdx.x, tid = threadIdx.x;
    const float* xr = x + (size_t)row * D_;
    float ss = 0.f;
    #pragma unroll
    for (int d = tid; d < D_; d += 256) { float t = xr[d]; ss += t * t; }
    #pragma unroll
    for (int off = 32; off > 0; off >>= 1) ss += __shfl_xor(ss, off);
    if ((tid & 63) == 0) red[tid >> 6] = ss;
    __syncthreads();
    float tot = red[0] + red[1] + red[2] + red[3];
    float scn = rsqrtf(tot * (1.f / D_) + 1e-6f);
    float* orow = out + (size_t)row * D_;
    #pragma unroll
    for (int d = tid; d < D_; d += 256) orow[d] = xr[d] * scn * w[d];
}

// ---------------- RoPE in-place on q and k ----------------
__global__ void rope_kernel(float* __restrict__ q, float* __restrict__ k,
                            const float* __restrict__ cosp, const float* __restrict__ sinp)
{
    int idx = blockIdx.x * 256 + threadIdx.x;     // B*S*H*32 total
    int p  = idx & 31;
    int hh = (idx >> 5) & (H_ - 1);
    int s  = (idx >> 9) & (S_ - 1);
    int b  = idx >> 19;
    size_t base = ((size_t)(b * S_ + s)) * D_ + hh * HD_;
    float c1 = cosp[s * HD_ + p],      s1 = sinp[s * HD_ + p];
    float c2 = cosp[s * HD_ + p + 32], s2 = sinp[s * HD_ + p + 32];
    float q1 = q[base + p], q2 = q[base + p + 32];
    q[base + p]      = q1 * c1 - q2 * s1;
    q[base + p + 32] = q2 * c2 + q1 * s2;
    float k1 = k[base + p], k2 = k[base + p + 32];
    k[base + p]      = k1 * c1 - k2 * s1;
    k[base + p + 32] = k2 * c2 + k1 * s2;
}

// ---------------- Causal flash attention: one wave per (b,h,q-row) ----------------
__global__ __launch_bounds__(64) void attn_kernel(
    const float* __restrict__ q, const float* __restrict__ k,
    const float* __restrict__ v, float* __restrict__ o)
{
    __shared__ float q_lds[64];
    __shared__ float p_lds[64];
    const int lane = threadIdx.x;
    const int bid = blockIdx.x;
    const int qs = bid % S_;
    const int hh = (bid / S_) % H_;
    const int b  = bid / (S_ * H_);
    const size_t qbase = ((size_t)(b * S_ + qs)) * D_ + hh * HD_;
    q_lds[lane] = q[qbase + lane] * 0.125f;   // fold 1/sqrt(64)
    __syncthreads();
    float m = -INFINITY, l = 0.f, acc = 0.f;
    const float* kb_base = k + (size_t)b * S_ * D_ + hh * HD_;
    const float* vb_base = v + (size_t)b * S_ * D_ + hh * HD_ + lane;
    for (int kb = 0; kb <= qs; kb += 64) {
        const float4* krow = (const float4*)(kb_base + (size_t)(kb + lane) * D_);
        float s = 0.f;
        #pragma unroll
        for (int t = 0; t < 16; ++t) {
            float4 kv = krow[t];
            s += kv.x * q_lds[4 * t + 0] + kv.y * q_lds[4 * t + 1]
               + kv.z * q_lds[4 * t + 2] + kv.w * q_lds[4 * t + 3];
        }
        if (kb + lane > qs) s = -1e30f;
        float mt = s;
        #pragma unroll
        for (int off = 32; off > 0; off >>= 1) mt = fmaxf(mt, __shfl_xor(mt, off));
        float mnew = fmaxf(m, mt);
        float sc = __expf(m - mnew);
        float p = __expf(s - mnew);
        float ps = p;
        #pragma unroll
        for (int off = 32; off > 0; off >>= 1) ps += __shfl_xor(ps, off);
        l = l * sc + ps;
        acc *= sc;
        m = mnew;
        __syncthreads();
        p_lds[lane] = p;
        __syncthreads();
        const float* vrow = vb_base + (size_t)kb * D_;
        #pragma unroll 16
        for (int j = 0; j < 64; ++j) acc += p_lds[j] * vrow[(size_t)j * D_];
    }
    o[qbase + lane] = acc / l;
}

// ---------------- strength = sigmoid(h1 @ W_strength): one wave per row ----------------
__global__ __launch_bounds__(64) void strength_kernel(
    const float* __restrict__ h, const float* __restrict__ ws, float* __restrict__ st)
{
    const int row = blockIdx.x, lane = threadIdx.x;
    const float* hr = h + (size_t)row * D_;
    float s = 0.f;
    #pragma unroll
    for (int d = lane; d < D_; d += 64) s += hr[d] * ws[d];
    #pragma unroll
    for (int off = 32; off > 0; off >>= 1) s += __shfl_xor(s, off);
    if (lane == 0) st[row] = 1.f / (1.f + expf(-s));
}

// ---------------- memory scatter updates ----------------
__global__ void scatter_keys_kernel(const float* __restrict__ comp, const float* __restrict__ st,
                                    const float* __restrict__ memk, const int* __restrict__ pos,
                                    float* __restrict__ outk)
{
    int idx = blockIdx.x * 256 + threadIdx.x;    // B*S*DC
    int c = idx & (DC_ - 1);
    int s = (idx >> 8) & (S_ - 1);
    int b = idx >> 18;
    int row = (pos[0] + s) % M_;
    float t = st[b * S_ + s];
    size_t mi = ((size_t)b * M_ + row) * DC_ + c;
    outk[mi] = t * comp[((size_t)b * S_ + s) * DC_ + c] + (1.f - t) * memk[mi];
}

__global__ void scatter_vals_kernel(const float* __restrict__ cont, const float* __restrict__ st,
                                    const float* __restrict__ memv, const int* __restrict__ pos,
                                    float* __restrict__ outv)
{
    int idx = blockIdx.x * 256 + threadIdx.x;    // B*S*D
    int c = idx & (D_ - 1);
    int s = (idx >> 10) & (S_ - 1);
    int b = idx >> 20;
    int row = (pos[0] + s) % M_;
    float t = st[b * S_ + s];
    size_t mi = ((size_t)b * M_ + row) * D_ + c;
    outv[mi] = t * cont[((size_t)b * S_ + s) * D_ + c] + (1.f - t) * memv[mi];
}

// ---------------- softmax over memory dim (rows of len M=2048, scale 1/16) ----------------
__global__ __launch_bounds__(256) void memsoftmax_kernel(float* __restrict__ ms)
{
    __shared__ float red[4];
    const int row = blockIdx.x, tid = threadIdx.x;
    float* r = ms + (size_t)row * M_;
    float mx = -INFINITY;
    for (int i = tid; i < M_; i += 256) mx = fmaxf(mx, r[i]);
    #pragma unroll
    for (int off = 32; off > 0; off >>= 1) mx = fmaxf(mx, __shfl_xor(mx, off));
    if ((tid & 63) == 0) red[tid >> 6] = mx;
    __syncthreads();
    mx = fmaxf(fmaxf(red[0], red[1]), fmaxf(red[2], red[3]));
    __syncthreads();
    float sum = 0.f;
    for (int i = tid; i < M_; i += 256) {
        float p = expf((r[i] - mx) * 0.0625f);
        r[i] = p; sum += p;
    }
    #pragma unroll
    for (int off = 32; off > 0; off >>= 1) sum += __shfl_xor(sum, off);
    if ((tid & 63) == 0) red[tid >> 6] = sum;
    __syncthreads();
    float inv = 1.f / (red[0] + red[1] + red[2] + red[3]);
    for (int i = tid; i < M_; i += 256) r[i] *= inv;
}

// ---------------- h2 = h1 + sigmoid(gate) * proj ----------------
__global__ void gatecomb_kernel(const float* __restrict__ h1, const float* __restrict__ g,
                                const float* __restrict__ p, float* __restrict__ h2)
{
    int i = blockIdx.x * 256 + threadIdx.x;
    float gg = 1.f / (1.f + expf(-g[i]));
    h2[i] = h1[i] + gg * p[i];
}

// ---------------- a1 = silu(a1) * a3 ----------------
__global__ void silumul_kernel(float* __restrict__ a1, const float* __restrict__ a3)
{
    int i = blockIdx.x * 256 + threadIdx.x;
    float x = a1[i];
    a1[i] = (x / (1.f + expf(-x))) * a3[i];
}

extern "C" void kernel_launch(void* const* d_in, const int* in_sizes, int n_in,
                              void* d_out, int out_size, void* d_ws, size_t ws_size,
                              hipStream_t stream)
{
    const float* h0   = (const float*)d_in[0];
    const float* memk = (const float*)d_in[1];
    const float* memv = (const float*)d_in[2];
    const float* cosp = (const float*)d_in[3];
    const float* sinp = (const float*)d_in[4];
    const float* n1w  = (const float*)d_in[5];
    const float* n2w  = (const float*)d_in[6];
    const float* nmw  = (const float*)d_in[7];
    const float* Wq   = (const float*)d_in[8];
    const float* Wk   = (const float*)d_in[9];
    const float* Wv   = (const float*)d_in[10];
    const float* Wo   = (const float*)d_in[11];
    const float* Wct  = (const float*)d_in[12];
    const float* Wcp  = (const float*)d_in[13];
    const float* Wst  = (const float*)d_in[14];
    const float* Wqr  = (const float*)d_in[15];
    const float* Wg   = (const float*)d_in[16];
    const float* Wpj  = (const float*)d_in[17];
    const float* W1   = (const float*)d_in[18];
    const float* W3   = (const float*)d_in[19];
    const float* W2   = (const float*)d_in[20];
    const int*   pos  = (const int*)d_in[21];

    float* out_h = (float*)d_out;
    float* out_k = out_h + (size_t)B_ * S_ * D_;
    float* out_v = out_k + (size_t)B_ * M_ * DC_;

    float* ws   = (float*)d_ws;
    float* nb   = ws + 0;          // 2,097,152 : n / normed / n2
    float* qb   = ws + 2097152;    // q   (later a1 overlay start)
    float* kb   = ws + 4194304;    // k
    float* vb   = ws + 6291456;    // v
    float* aob  = ws + 8388608;    // attn_out, later gate pre-act
    float* h1b  = ws + 10485760;
    float* ctb  = ws + 12582912;   // content, later proj
    float* cpb  = ws + 14680064;   // compressed (524,288)
    float* stb  = ws + 15204352;   // strength (2,048)
    float* qmb  = ws + 15206400;   // qm (524,288)
    float* msb  = ws + 15730688;   // mscores (4,194,304)
    float* retb = ws + 19924992;   // retrieved
    float* h2b  = ws + 22022144;
    float* a1b  = qb;              // overlay: covers q,k,v,ao (all dead by MLP)
    float* a3b  = ws + 24119296;   // total ws use: 32,507,904 floats = 130 MB

    dim3 blk(16, 16);

    // 1. n = rmsnorm(h0, norm1_w)
    rmsnorm_kernel<<<NTOK, 256, 0, stream>>>(h0, n1w, nb);
    // 2. q,k,v projections
    gemm_kernel<false,false><<<dim3(D_/64, NTOK/64), blk, 0, stream>>>(nb, Wq, nullptr, qb, NTOK, D_, D_, D_, D_, D_);
    gemm_kernel<false,false><<<dim3(D_/64, NTOK/64), blk, 0, stream>>>(nb, Wk, nullptr, kb, NTOK, D_, D_, D_, D_, D_);
    gemm_kernel<false,false><<<dim3(D_/64, NTOK/64), blk, 0, stream>>>(nb, Wv, nullptr, vb, NTOK, D_, D_, D_, D_, D_);
    // 3. RoPE
    rope_kernel<<<(B_*S_*H_*32)/256, 256, 0, stream>>>(qb, kb, cosp, sinp);
    // 4. causal attention
    attn_kernel<<<B_*H_*S_, 64, 0, stream>>>(qb, kb, vb, aob);
    // 5. h1 = h0 + attn_out @ Wo
    gemm_kernel<false,false><<<dim3(D_/64, NTOK/64), blk, 0, stream>>>(aob, Wo, h0, h1b, NTOK, D_, D_, D_, D_, D_);
    // 6. content / compressed / strength
    gemm_kernel<false,false><<<dim3(D_/64, NTOK/64), blk, 0, stream>>>(h1b, Wct, nullptr, ctb, NTOK, D_, D_, D_, D_, D_);
    gemm_kernel<false,false><<<dim3(DC_/64, NTOK/64), blk, 0, stream>>>(h1b, Wcp, nullptr, cpb, NTOK, DC_, D_, D_, DC_, DC_);
    strength_kernel<<<NTOK, 64, 0, stream>>>(h1b, Wst, stb);
    // 7. memory update: copy then scatter rows idx=(pos+s)%M
    hipMemcpyAsync(out_k, memk, (size_t)B_*M_*DC_*sizeof(float), hipMemcpyDeviceToDevice, stream);
    hipMemcpyAsync(out_v, memv, (size_t)B_*M_*D_*sizeof(float), hipMemcpyDeviceToDevice, stream);
    scatter_keys_kernel<<<(B_*S_*DC_)/256, 256, 0, stream>>>(cpb, stb, memk, pos, out_k);
    scatter_vals_kernel<<<(B_*S_*D_)/256, 256, 0, stream>>>(ctb, stb, memv, pos, out_v);
    // 8. normed = rmsnorm(h1, norm_mem_w); qm = normed @ W_query
    rmsnorm_kernel<<<NTOK, 256, 0, stream>>>(h1b, nmw, nb);
    gemm_kernel<false,false><<<dim3(DC_/64, NTOK/64), blk, 0, stream>>>(nb, Wqr, nullptr, qmb, NTOK, DC_, D_, D_, DC_, DC_);
    // 9. memory attention
    for (int b = 0; b < B_; ++b)
        gemm_kernel<true,false><<<dim3(M_/64, S_/64), blk, 0, stream>>>(
            qmb + (size_t)b*S_*DC_, out_k + (size_t)b*M_*DC_, nullptr, msb + (size_t)b*S_*M_,
            S_, M_, DC_, DC_, DC_, M_);
    memsoftmax_kernel<<<NTOK, 256, 0, stream>>>(msb);
    for (int b = 0; b < B_; ++b)
        gemm_kernel<false,false><<<dim3(D_/64, S_/64), blk, 0, stream>>>(
            msb + (size_t)b*S_*M_, out_v + (size_t)b*M_*D_, nullptr, retb + (size_t)b*S_*D_,
            S_, D_, M_, M_, D_, D_);
    // 10. gate = sigmoid([h1|retr] @ W_gate); h2 = h1 + gate * (retr @ W_proj)
    gemm_kernel<false,false><<<dim3(D_/64, NTOK/64), blk, 0, stream>>>(h1b, Wg, nullptr, aob, NTOK, D_, D_, D_, D_, D_);
    gemm_kernel<false,true ><<<dim3(D_/64, NTOK/64), blk, 0, stream>>>(retb, Wg + (size_t)D_*D_, nullptr, aob, NTOK, D_, D_, D_, D_, D_);
    gemm_kernel<false,false><<<dim3(D_/64, NTOK/64), blk, 0, stream>>>(retb, Wpj, nullptr, ctb, NTOK, D_, D_, D_, D_, D_);
    gatecomb_kernel<<<(NTOK*D_)/256, 256, 0, stream>>>(h1b, aob, ctb, h2b);
    // 11. MLP: h3 = h2 + (silu(n2@W1) * (n2@W3)) @ W2
    rmsnorm_kernel<<<NTOK, 256, 0, stream>>>(h2b, n2w, nb);
    gemm_kernel<false,false><<<dim3(F_/64, NTOK/64), blk, 0, stream>>>(nb, W1, nullptr, a1b, NTOK, F_, D_, D_, F_, F_);
    gemm_kernel<false,false><<<dim3(F_/64, NTOK/64), blk, 0, stream>>>(nb, W3, nullptr, a3b, NTOK, F_, D_, D_, F_, F_);
    silumul_kernel<<<(NTOK*F_)/256, 256, 0, stream>>>(a1b, a3b);
    gemm_kernel<false,false><<<dim3(D_/64, NTOK/64), blk, 0, stream>>>(a1b, W2, h2b, out_h, NTOK, D_, F_, F_, D_, D_);
}

// Round 2
// 608.403 us; speedup vs baseline: 4.0287x; 4.0287x over previous
//
#include <hip/hip_runtime.h>
#include <hip/hip_bf16.h>
#include <math.h>

typedef __bf16 bf16;
typedef __attribute__((ext_vector_type(8))) __bf16 bf16x8;
typedef __attribute__((ext_vector_type(4))) float f32x4;

#define B_ 2
#define S_ 1024
#define D_ 1024
#define H_ 16
#define HD_ 64
#define F_ 4096
#define M_ 2048
#define DC_ 256
#define NTOK (B_*S_)

__device__ inline void gload16(const void* g, void* l) {
    __builtin_amdgcn_global_load_lds(
        (__attribute__((address_space(1))) void*)(void*)(g),
        (__attribute__((address_space(3))) void*)(l), 16, 0, 0);
}

// ============ MFMA GEMM: C[M,N] = A[M,K] @ Bt[N,K]^T (+resid) ============
// BM=128 fixed. BN in {64,128}. CMODE: 0 none, 1 causal block-skip (scores),
// 2 causal K-limit (PV). OUTBF: write bf16 else f32. Batched via blockIdx.z
// with element strides sA,sB,sC. All dims multiples of tile sizes.
template<int BN, int CMODE, bool OUTBF>
__global__ __launch_bounds__(256) void mgemm(
    const bf16* __restrict__ A, const bf16* __restrict__ Bt,
    const float* __restrict__ resid, void* __restrict__ Cout,
    int K, int lda, int ldb, int ldc,
    long long sA, long long sB, long long sC)
{
    constexpr int FN = BN / 32;
    __shared__ bf16 As[128 * 32];
    __shared__ bf16 Bs[BN * 32];
    const int z = blockIdx.z;
    A  += (size_t)z * sA;
    Bt += (size_t)z * sB;
    const int row0 = blockIdx.y * 128;
    const int col0 = blockIdx.x * BN;
    if (CMODE == 1 && col0 > row0 + 127) return;
    const int kmax = (CMODE == 2) ? min(K, row0 + 128) : K;
    const int tid = threadIdx.x, wid = tid >> 6, lane = tid & 63;
    const int wr = wid >> 1, wc = wid & 1;
    f32x4 acc[4][FN];
    #pragma unroll
    for (int m = 0; m < 4; ++m)
        #pragma unroll
        for (int n = 0; n < FN; ++n) acc[m][n] = (f32x4){0.f, 0.f, 0.f, 0.f};

    const int srow = lane >> 2;          // 0..15 within chunk
    const int scol = (lane & 3) * 8;     // k sub-offset (elements)
    for (int k0 = 0; k0 < kmax; k0 += 32) {
        #pragma unroll
        for (int i = 0; i < 2; ++i) {
            int c = wid * 2 + i;
            gload16(A + (size_t)(row0 + c * 16 + srow) * lda + k0 + scol, As + c * 512);
        }
        #pragma unroll
        for (int i = 0; i < BN / 64; ++i) {
            int c = wid * (BN / 64) + i;
            gload16(Bt + (size_t)(col0 + c * 16 + srow) * ldb + k0 + scol, Bs + c * 512);
        }
        __syncthreads();
        const bf16* ap = As + ((wr << 6) + (lane & 15)) * 32 + (lane >> 4) * 8;
        const bf16* bp = Bs + (wc * (BN / 2) + (lane & 15)) * 32 + (lane >> 4) * 8;
        bf16x8 af[4], bfr[FN];
        #pragma unroll
        for (int m = 0; m < 4; ++m) af[m] = *(const bf16x8*)(ap + m * 16 * 32);
        #pragma unroll
        for (int n = 0; n < FN; ++n) bfr[n] = *(const bf16x8*)(bp + n * 16 * 32);
        #pragma unroll
        for (int m = 0; m < 4; ++m)
            #pragma unroll
            for (int n = 0; n < FN; ++n)
                acc[m][n] = __builtin_amdgcn_mfma_f32_16x16x32_bf16(af[m], bfr[n], acc[m][n], 0, 0, 0);
        __syncthreads();
    }
    const int crow = row0 + (wr << 6) + ((lane >> 4) << 2);
    const int ccol = col0 + wc * (BN / 2) + (lane & 15);
    #pragma unroll
    for (int m = 0; m < 4; ++m)
        #pragma unroll
        for (int n = 0; n < FN; ++n)
            #pragma unroll
            for (int r = 0; r < 4; ++r) {
                size_t idx = (size_t)(crow + m * 16 + r) * ldc + ccol + n * 16;
                float v = acc[m][n][r];
                if (resid) v += resid[idx];
                if (OUTBF) ((bf16*)Cout)[(size_t)z * sC + idx] = (bf16)v;
                else       ((float*)Cout)[(size_t)z * sC + idx] = v;
            }
}

// ============ transpose-cast: in [R][C] (f32 or bf16) -> out bf16 [C][R] ============
template<typename TI>
__global__ __launch_bounds__(256) void tcast(
    const TI* __restrict__ in, bf16* __restrict__ out,
    int lin, int lout, long long sin, long long sout)
{
    __shared__ float t[32][33];
    in  += (size_t)blockIdx.z * sin;
    out += (size_t)blockIdx.z * sout;
    const int c0 = blockIdx.x * 32, r0 = blockIdx.y * 32;
    const int tx = threadIdx.x & 31, ty = threadIdx.x >> 5;
    #pragma unroll
    for (int j = 0; j < 4; ++j)
        t[ty + j * 8][tx] = (float)in[(size_t)(r0 + ty + j * 8) * lin + c0 + tx];
    __syncthreads();
    #pragma unroll
    for (int j = 0; j < 4; ++j)
        out[(size_t)(c0 + ty + j * 8) * lout + r0 + tx] = (bf16)t[tx][ty + j * 8];
}

// ============ RMSNorm -> bf16 out ============
__global__ __launch_bounds__(256) void rmsnorm_bf(
    const float* __restrict__ x, const float* __restrict__ w, bf16* __restrict__ out)
{
    __shared__ float red[4];
    const int row = blockIdx.x, tid = threadIdx.x;
    const float* xr = x + (size_t)row * D_;
    float ss = 0.f;
    #pragma unroll
    for (int d = tid; d < D_; d += 256) { float t = xr[d]; ss += t * t; }
    #pragma unroll
    for (int off = 32; off > 0; off >>= 1) ss += __shfl_xor(ss, off);
    if ((tid & 63) == 0) red[tid >> 6] = ss;
    __syncthreads();
    float scn = rsqrtf((red[0] + red[1] + red[2] + red[3]) * (1.f / D_) + 1e-6f);
    bf16* orow = out + (size_t)row * D_;
    #pragma unroll
    for (int d = tid; d < D_; d += 256) orow[d] = (bf16)(xr[d] * scn * w[d]);
}

// ============ RoPE in-place on bf16 qkv buffer [tok][3072]; q scaled 1/8 ============
__global__ void rope_kernel(bf16* __restrict__ qkv,
                            const float* __restrict__ cosp, const float* __restrict__ sinp)
{
    int idx = blockIdx.x * 256 + threadIdx.x;   // B*S*H*32
    int p = idx & 31, hh = (idx >> 5) & 15, s = (idx >> 9) & 1023, b = idx >> 19;
    size_t base = ((size_t)(b * S_ + s)) * 3072 + hh * 64;
    float c1 = cosp[s * 64 + p],      s1 = sinp[s * 64 + p];
    float c2 = cosp[s * 64 + p + 32], s2 = sinp[s * 64 + p + 32];
    float q1 = (float)qkv[base + p], q2 = (float)qkv[base + p + 32];
    qkv[base + p]      = (bf16)((q1 * c1 - q2 * s1) * 0.125f);
    qkv[base + p + 32] = (bf16)((q2 * c2 + q1 * s2) * 0.125f);
    size_t kb = base + 1024;
    float k1 = (float)qkv[kb + p], k2 = (float)qkv[kb + p + 32];
    qkv[kb + p]      = (bf16)(k1 * c1 - k2 * s1);
    qkv[kb + p + 32] = (bf16)(k2 * c2 + k1 * s2);
}

// ============ causal softmax on bf16 score rows (in-place), zero masked ============
__global__ __launch_bounds__(256) void attn_softmax(bf16* __restrict__ sb)
{
    __shared__ float buf[1024];
    __shared__ float red[4];
    const int row = blockIdx.x;        // h*1024 + qs
    const int qs = row & 1023;
    bf16* r = sb + (size_t)row * 1024;
    const int tid = threadIdx.x;
    float mx = -1e30f;
    for (int j = tid; j < 1024; j += 256) {
        float x = (j <= qs) ? (float)r[j] : -1e30f;
        buf[j] = x; mx = fmaxf(mx, x);
    }
    #pragma unroll
    for (int off = 32; off > 0; off >>= 1) mx = fmaxf(mx, __shfl_xor(mx, off));
    if ((tid & 63) == 0) red[tid >> 6] = mx;
    __syncthreads();
    mx = fmaxf(fmaxf(red[0], red[1]), fmaxf(red[2], red[3]));
    __syncthreads();
    float sum = 0.f;
    for (int j = tid; j < 1024; j += 256) {
        float p = (j <= qs) ? __expf(buf[j] - mx) : 0.f;
        buf[j] = p; sum += p;
    }
    #pragma unroll
    for (int off = 32; off > 0; off >>= 1) sum += __shfl_xor(sum, off);
    if ((tid & 63) == 0) red[tid >> 6] = sum;
    __syncthreads();
    float inv = 1.f / (red[0] + red[1] + red[2] + red[3]);
    for (int j = tid; j < 1024; j += 256) r[j] = (bf16)(buf[j] * inv);
}

// ============ memory softmax: f32 [row][2048] -> bf16 probs, scale 1/16 ============
__global__ __launch_bounds__(256) void mem_softmax(
    const float* __restrict__ ms, bf16* __restrict__ out)
{
    __shared__ float buf[2048];
    __shared__ float red[4];
    const int row = blockIdx.x, tid = threadIdx.x;
    const float* r = ms + (size_t)row * 2048;
    float mx = -1e30f;
    for (int j = tid; j < 2048; j += 256) { float x = r[j]; buf[j] = x; mx = fmaxf(mx, x); }
    #pragma unroll
    for (int off = 32; off > 0; off >>= 1) mx = fmaxf(mx, __shfl_xor(mx, off));
    if ((tid & 63) == 0) red[tid >> 6] = mx;
    __syncthreads();
    mx = fmaxf(fmaxf(red[0], red[1]), fmaxf(red[2], red[3]));
    __syncthreads();
    float sum = 0.f;
    for (int j = tid; j < 2048; j += 256) {
        float p = __expf((buf[j] - mx) * 0.0625f);
        buf[j] = p; sum += p;
    }
    #pragma unroll
    for (int off = 32; off > 0; off >>= 1) sum += __shfl_xor(sum, off);
    if ((tid & 63) == 0) red[tid >> 6] = sum;
    __syncthreads();
    float inv = 1.f / (red[0] + red[1] + red[2] + red[3]);
    bf16* o = out + (size_t)row * 2048;
    for (int j = tid; j < 2048; j += 256) o[j] = (bf16)(buf[j] * inv);
}

// ============ small elementwise kernels ============
__global__ void strength_kernel(const float* __restrict__ h, const float* __restrict__ ws,
                                float* __restrict__ st)
{
    const int row = blockIdx.x, lane = threadIdx.x;
    const float* hr = h + (size_t)row * D_;
    float s = 0.f;
    #pragma unroll
    for (int d = lane; d < D_; d += 64) s += hr[d] * ws[d];
    #pragma unroll
    for (int off = 32; off > 0; off >>= 1) s += __shfl_xor(s, off);
    if (lane == 0) st[row] = 1.f / (1.f + expf(-s));
}

__global__ void scatter_keys_kernel(const float* __restrict__ ctcp, const float* __restrict__ st,
                                    const float* __restrict__ memk, const int* __restrict__ pos,
                                    float* __restrict__ outk)
{
    int idx = blockIdx.x * 256 + threadIdx.x;    // B*S*DC
    int c = idx & (DC_ - 1);
    int s = (idx >> 8) & (S_ - 1);
    int b = idx >> 18;
    int row = (pos[0] + s) % M_;
    float t = st[b * S_ + s];
    size_t mi = ((size_t)b * M_ + row) * DC_ + c;
    outk[mi] = t * ctcp[((size_t)b * S_ + s) * 1280 + 1024 + c] + (1.f - t) * memk[mi];
}

__global__ void scatter_vals_kernel(const float* __restrict__ ctcp, const float* __restrict__ st,
                                    const float* __restrict__ memv, const int* __restrict__ pos,
                                    float* __restrict__ outv)
{
    int idx = blockIdx.x * 256 + threadIdx.x;    // B*S*D
    int c = idx & (D_ - 1);
    int s = (idx >> 10) & (S_ - 1);
    int b = idx >> 20;
    int row = (pos[0] + s) % M_;
    float t = st[b * S_ + s];
    size_t mi = ((size_t)b * M_ + row) * D_ + c;
    outv[mi] = t * ctcp[((size_t)b * S_ + s) * 1280 + c] + (1.f - t) * memv[mi];
}

__global__ void cast_h1_kernel(const float* __restrict__ h1, bf16* __restrict__ cat)
{
    int i = blockIdx.x * 256 + threadIdx.x;      // NTOK*D
    int row = i >> 10, c = i & 1023;
    cat[(size_t)row * 2048 + c] = (bf16)h1[i];
}

__global__ void cast_flat_kernel(const float* __restrict__ in, bf16* __restrict__ out)
{
    int i = blockIdx.x * 256 + threadIdx.x;
    out[i] = (bf16)in[i];
}

__global__ void gatecomb_kernel(const float* __restrict__ h1, const float* __restrict__ g,
                                const float* __restrict__ p, float* __restrict__ h2)
{
    int i = blockIdx.x * 256 + threadIdx.x;
    float gg = 1.f / (1.f + expf(-g[i]));
    h2[i] = h1[i] + gg * p[i];
}

__global__ void silumul_kernel(const float* __restrict__ a13, bf16* __restrict__ a1bf)
{
    int i = blockIdx.x * 256 + threadIdx.x;      // NTOK*F
    int row = i >> 12, c = i & 4095;
    float x = a13[(size_t)row * 8192 + c];
    float y = a13[(size_t)row * 8192 + 4096 + c];
    a1bf[i] = (bf16)((x / (1.f + expf(-x))) * y);
}

extern "C" void kernel_launch(void* const* d_in, const int* in_sizes, int n_in,
                              void* d_out, int out_size, void* d_ws, size_t ws_size,
                              hipStream_t stream)
{
    const float* h0   = (const float*)d_in[0];
    const float* memk = (const float*)d_in[1];
    const float* memv = (const float*)d_in[2];
    const float* cosp = (const float*)d_in[3];
    const float* sinp = (const float*)d_in[4];
    const float* n1w  = (const float*)d_in[5];
    const float* n2w  = (const float*)d_in[6];
    const float* nmw  = (const float*)d_in[7];
    const float* Wq   = (const float*)d_in[8];
    const float* Wk   = (const float*)d_in[9];
    const float* Wv   = (const float*)d_in[10];
    const float* Wo   = (const float*)d_in[11];
    const float* Wct  = (const float*)d_in[12];
    const float* Wcp  = (const float*)d_in[13];
    const float* Wst  = (const float*)d_in[14];
    const float* Wqr  = (const float*)d_in[15];
    const float* Wg   = (const float*)d_in[16];
    const float* Wpj  = (const float*)d_in[17];
    const float* W1   = (const float*)d_in[18];
    const float* W3   = (const float*)d_in[19];
    const float* W2   = (const float*)d_in[20];
    const int*   pos  = (const int*)d_in[21];

    float* out_h = (float*)d_out;
    float* out_k = out_h + (size_t)NTOK * D_;
    float* out_v = out_k + (size_t)B_ * M_ * DC_;

    char* W = (char*)d_ws;
    const size_t MB = 1u << 20;
    // region X (64 MB): attention scores, then mem buffers, then a13
    bf16*  sbf  = (bf16*)(W);               // 32 MB  (per-b scores/probs [16][1024][1024])
    float* msb  = (float*)(W + 32 * MB);    // 16 MB  mem scores f32 [2][1024][2048]
    bf16*  matt = (bf16*)(W + 48 * MB);     // 8 MB   mem probs bf16
    bf16*  nvt  = (bf16*)(W + 56 * MB);     // 8 MB   new_values^T bf16 [2][1024][2048]
    float* a13  = (float*)(W);              // 64 MB  MLP up f32 [2048][8192] (overlays all above)
    // region Y (16 MB): qkv bf16 + v^T, later a1bf
    bf16*  qkvb = (bf16*)(W + 64 * MB);     // 12 MB  [2048][3072]
    bf16*  vtb  = (bf16*)(W + 76 * MB);     // 4 MB   [32][64][1024]
    bf16*  a1bf = (bf16*)(W + 64 * MB);     // 16 MB  [2048][4096] (overlays qkvb+vtb)
    bf16*  abf  = (bf16*)(W + 80 * MB);     // 4 MB   attn out bf16 [2048][1024]
    float* h1b  = (float*)(W + 84 * MB);    // 8 MB
    bf16*  catbf= (bf16*)(W + 92 * MB);     // 8 MB   [2048][2048] = [h1bf | retr]
    bf16*  nbf  = (bf16*)(W + 100 * MB);    // 4 MB   rmsnorm out (reused 3x)
    float* ctcp = (float*)(W + 104 * MB);   // 10.5 MB [2048][1280] content|compressed; later proj
    bf16*  okbf = (bf16*)(W + 115 * MB);    // 2 MB   new_keys bf16
    bf16*  qmbf = (bf16*)(W + 117 * MB);    // 1 MB
    float* aob  = (float*)(W + 118 * MB);   // 8 MB   gate pre-act
    float* h2b  = (float*)(W + 126 * MB);   // 8 MB
    float* stb  = (float*)(W + 134 * MB);   // 8 KB
    bf16*  WqkvT= (bf16*)(W + 135 * MB);    // 6 MB   [3072][1024]
    bf16*  WoT  = (bf16*)(W + 141 * MB);    // 2 MB
    bf16*  WctcpT=(bf16*)(W + 143 * MB);    // 2.5 MB [1280][1024]
    bf16*  WqrT = (bf16*)(W + 146 * MB);    // 0.5 MB [256][1024]
    bf16*  WgT  = (bf16*)(W + 147 * MB);    // 4 MB   [1024][2048]
    bf16*  WpjT = (bf16*)(W + 151 * MB);    // 2 MB
    bf16*  W13T = (bf16*)(W + 153 * MB);    // 16 MB  [8192][1024]
    bf16*  W2T  = (bf16*)(W + 169 * MB);    // 8 MB   [1024][4096]

    // ---- weight transpose-casts ----
    tcast<float><<<dim3(32, 32, 1), 256, 0, stream>>>(Wq,  WqkvT,                1024, 1024, 0, 0);
    tcast<float><<<dim3(32, 32, 1), 256, 0, stream>>>(Wk,  WqkvT + 1024 * 1024,  1024, 1024, 0, 0);
    tcast<float><<<dim3(32, 32, 1), 256, 0, stream>>>(Wv,  WqkvT + 2048 * 1024,  1024, 1024, 0, 0);
    tcast<float><<<dim3(32, 32, 1), 256, 0, stream>>>(Wo,  WoT,                  1024, 1024, 0, 0);
    tcast<float><<<dim3(32, 32, 1), 256, 0, stream>>>(Wct, WctcpT,               1024, 1024, 0, 0);
    tcast<float><<<dim3(8, 32, 1), 256, 0, stream>>>(Wcp,  WctcpT + 1024 * 1024, 256, 1024, 0, 0);
    tcast<float><<<dim3(8, 32, 1), 256, 0, stream>>>(Wqr,  WqrT,                 256, 1024, 0, 0);
    tcast<float><<<dim3(32, 64, 1), 256, 0, stream>>>(Wg,  WgT,                  1024, 2048, 0, 0);
    tcast<float><<<dim3(32, 32, 1), 256, 0, stream>>>(Wpj, WpjT,                 1024, 1024, 0, 0);
    tcast<float><<<dim3(128, 32, 1), 256, 0, stream>>>(W1, W13T,                 4096, 1024, 0, 0);
    tcast<float><<<dim3(128, 32, 1), 256, 0, stream>>>(W3, W13T + 4096 * 1024,   4096, 1024, 0, 0);
    tcast<float><<<dim3(32, 128, 1), 256, 0, stream>>>(W2, W2T,                  1024, 4096, 0, 0);

    // ---- 1. n = rmsnorm(h0); qkv = n @ [Wq|Wk|Wv] ----
    rmsnorm_bf<<<NTOK, 256, 0, stream>>>(h0, n1w, nbf);
    mgemm<128, 0, true><<<dim3(24, 16, 1), 256, 0, stream>>>(
        nbf, WqkvT, nullptr, qkvb, 1024, 1024, 1024, 3072, 0, 0, 0);
    rope_kernel<<<(B_ * S_ * H_ * 32) / 256, 256, 0, stream>>>(qkvb, cosp, sinp);
    for (int b = 0; b < B_; ++b)
        tcast<bf16><<<dim3(2, 32, 16), 256, 0, stream>>>(
            qkvb + (size_t)b * S_ * 3072 + 2048, vtb + (size_t)b * 16 * 65536,
            3072, 1024, 64, 65536);

    // ---- 2. causal attention per batch (scores -> softmax -> PV) ----
    for (int b = 0; b < B_; ++b) {
        const bf16* qbase = qkvb + (size_t)b * S_ * 3072;
        mgemm<128, 1, true><<<dim3(8, 8, 16), 256, 0, stream>>>(
            qbase, qbase + 1024, nullptr, sbf, 64, 3072, 3072, 1024,
            64, 64, 1024 * 1024);
        attn_softmax<<<16 * 1024, 256, 0, stream>>>(sbf);
        mgemm<64, 2, true><<<dim3(1, 8, 16), 256, 0, stream>>>(
            sbf, vtb + (size_t)b * 16 * 65536, nullptr, abf + (size_t)b * S_ * 1024,
            1024, 1024, 1024, 1024, 1024 * 1024, 65536, 64);
    }

    // ---- 3. h1 = h0 + attn @ Wo ----
    mgemm<64, 0, false><<<dim3(16, 16, 1), 256, 0, stream>>>(
        abf, WoT, h0, h1b, 1024, 1024, 1024, 1024, 0, 0, 0);
    cast_h1_kernel<<<(NTOK * D_) / 256, 256, 0, stream>>>(h1b, catbf);
    strength_kernel<<<NTOK, 64, 0, stream>>>(h1b, Wst, stb);

    // ---- 4. content|compressed; memory scatter ----
    mgemm<64, 0, false><<<dim3(20, 16, 1), 256, 0, stream>>>(
        catbf, WctcpT, nullptr, ctcp, 1024, 2048, 1024, 1280, 0, 0, 0);
    hipMemcpyAsync(out_k, memk, (size_t)B_ * M_ * DC_ * sizeof(float), hipMemcpyDeviceToDevice, stream);
    hipMemcpyAsync(out_v, memv, (size_t)B_ * M_ * D_ * sizeof(float), hipMemcpyDeviceToDevice, stream);
    scatter_keys_kernel<<<(B_ * S_ * DC_) / 256, 256, 0, stream>>>(ctcp, stb, memk, pos, out_k);
    scatter_vals_kernel<<<(B_ * S_ * D_) / 256, 256, 0, stream>>>(ctcp, stb, memv, pos, out_v);

    // ---- 5. memory attention ----
    rmsnorm_bf<<<NTOK, 256, 0, stream>>>(h1b, nmw, nbf);
    mgemm<64, 0, true><<<dim3(4, 16, 1), 256, 0, stream>>>(
        nbf, WqrT, nullptr, qmbf, 1024, 1024, 1024, 256, 0, 0, 0);
    cast_flat_kernel<<<(B_ * M_ * DC_) / 256, 256, 0, stream>>>(out_k, okbf);
    mgemm<128, 0, false><<<dim3(16, 8, 2), 256, 0, stream>>>(
        qmbf, okbf, nullptr, msb, 256, 256, 256, 2048,
        (long long)S_ * 256, (long long)M_ * 256, (long long)S_ * 2048);
    mem_softmax<<<NTOK, 256, 0, stream>>>(msb, matt);
    tcast<float><<<dim3(32, 64, 2), 256, 0, stream>>>(
        out_v, nvt, 1024, 2048, (long long)M_ * 1024, (long long)1024 * 2048);
    mgemm<128, 0, true><<<dim3(8, 8, 2), 256, 0, stream>>>(
        matt, nvt, nullptr, catbf + 1024, 2048, 2048, 2048, 2048,
        (long long)S_ * 2048, (long long)1024 * 2048, (long long)S_ * 2048);

    // ---- 6. gate + proj + combine ----
    mgemm<64, 0, false><<<dim3(16, 16, 1), 256, 0, stream>>>(
        catbf, WgT, nullptr, aob, 2048, 2048, 2048, 1024, 0, 0, 0);
    mgemm<64, 0, false><<<dim3(16, 16, 1), 256, 0, stream>>>(
        catbf + 1024, WpjT, nullptr, ctcp, 1024, 2048, 1024, 1024, 0, 0, 0);
    gatecomb_kernel<<<(NTOK * D_) / 256, 256, 0, stream>>>(h1b, aob, ctcp, h2b);

    // ---- 7. MLP ----
    rmsnorm_bf<<<NTOK, 256, 0, stream>>>(h2b, n2w, nbf);
    mgemm<128, 0, false><<<dim3(64, 16, 1), 256, 0, stream>>>(
        nbf, W13T, nullptr, a13, 1024, 1024, 1024, 8192, 0, 0, 0);
    silumul_kernel<<<(NTOK * F_) / 256, 256, 0, stream>>>(a13, a1bf);
    mgemm<64, 0, false><<<dim3(16, 16, 1), 256, 0, stream>>>(
        a1bf, W2T, h2b, out_h, 4096, 4096, 4096, 1024, 0, 0, 0);
}

// Round 3
// 441.322 us; speedup vs baseline: 5.5540x; 1.3786x over previous
//
#include <hip/hip_runtime.h>
#include <hip/hip_bf16.h>
#include <math.h>

typedef __bf16 bf16;
typedef __attribute__((ext_vector_type(8))) __bf16 bf16x8;
typedef __attribute__((ext_vector_type(4))) __bf16 bf16x4;
typedef __attribute__((ext_vector_type(4))) float f32x4;

#define B_ 2
#define S_ 1024
#define D_ 1024
#define H_ 16
#define HD_ 64
#define F_ 4096
#define M_ 2048
#define DC_ 256
#define NTOK (B_*S_)

__device__ inline void gload16(const void* g, void* l) {
    __builtin_amdgcn_global_load_lds(
        (__attribute__((address_space(1))) void*)(void*)(g),
        (__attribute__((address_space(3))) void*)(l), 16, 0, 0);
}

// ============ MFMA GEMM v2: C[M,N] = A[M,K] @ Bt[N,K]^T (+resid) ============
// BM=128, BK=64, double-buffered LDS with XOR-swizzle (pre-swizzled global
// source + swizzled ds_read; LDS dest stays linear for global_load_lds).
// CMODE: 0 none, 1 causal block-skip, 2 causal K-limit. OUTBF: bf16 output.
template<int BN, int CMODE, bool OUTBF>
__global__ __launch_bounds__(256) void mgemm(
    const bf16* __restrict__ A, const bf16* __restrict__ Bt,
    const float* __restrict__ resid, void* __restrict__ Cout,
    int K, int lda, int ldb, int ldc,
    long long sA, long long sB, long long sC)
{
    constexpr int FN = BN / 32;
    constexpr int LA = 128 * 64;   // elems per A buffer
    constexpr int LB = BN * 64;
    __shared__ bf16 lds[2 * (LA + LB)];
    const int z = blockIdx.z;
    A  += (size_t)z * sA;
    Bt += (size_t)z * sB;
    const int row0 = blockIdx.y * 128;
    const int col0 = blockIdx.x * BN;
    if (CMODE == 1 && col0 > row0 + 127) return;
    const int kmax = (CMODE == 2) ? min(K, row0 + 128) : K;
    const int tid = threadIdx.x, wid = tid >> 6, lane = tid & 63;
    const int wr = wid >> 1, wc = wid & 1;
    // stage-source swizzle: lane l fills phys 16B-slot (l&7) of row (l>>3) in
    // its chunk; it must FETCH logical sub (l&7)^(row&7).
    const int srow = lane >> 3;
    const int ssub = (lane & 7) ^ (srow & 7);

    f32x4 acc[4][FN];
    #pragma unroll
    for (int m = 0; m < 4; ++m)
        #pragma unroll
        for (int n = 0; n < FN; ++n) acc[m][n] = (f32x4){0.f, 0.f, 0.f, 0.f};

    auto STAGE = [&](int buf, int k0) {
        bf16* Ab = lds + buf * (LA + LB);
        bf16* Bb = Ab + LA;
        #pragma unroll
        for (int i = 0; i < 4; ++i) {
            int c = wid * 4 + i;   // 16 A-chunks of 8 rows
            gload16(A + (size_t)(row0 + c * 8 + srow) * lda + k0 + ssub * 8, Ab + c * 512);
        }
        #pragma unroll
        for (int i = 0; i < BN / 32; ++i) {
            int c = wid * (BN / 32) + i;   // BN/8 B-chunks
            gload16(Bt + (size_t)(col0 + c * 8 + srow) * ldb + k0 + ssub * 8, Bb + c * 512);
        }
    };

    const int nt = kmax >> 6;
    int cur = 0;
    STAGE(0, 0);
    __syncthreads();
    for (int t = 0; t < nt; ++t) {
        if (t + 1 < nt) STAGE(cur ^ 1, (t + 1) << 6);   // prefetch overlaps compute
        const bf16* Ab = lds + cur * (LA + LB);
        const bf16* Bb = Ab + LA;
        const int ar = (wr << 6) + (lane & 15);
        const int br = wc * (BN / 2) + (lane & 15);
        #pragma unroll
        for (int ksel = 0; ksel < 2; ++ksel) {
            // logical 16B-sub = ksel*4 + (lane>>4); row&7 == lane&7 for all frags
            const int ps = ((ksel << 2) + (lane >> 4)) ^ (lane & 7);
            bf16x8 af[4], bfr[FN];
            #pragma unroll
            for (int m = 0; m < 4; ++m)
                af[m] = *(const bf16x8*)(Ab + (ar + m * 16) * 64 + ps * 8);
            #pragma unroll
            for (int n = 0; n < FN; ++n)
                bfr[n] = *(const bf16x8*)(Bb + (br + n * 16) * 64 + ps * 8);
            #pragma unroll
            for (int m = 0; m < 4; ++m)
                #pragma unroll
                for (int n = 0; n < FN; ++n)
                    acc[m][n] = __builtin_amdgcn_mfma_f32_16x16x32_bf16(af[m], bfr[n], acc[m][n], 0, 0, 0);
        }
        __syncthreads();
        cur ^= 1;
    }
    const int crow = row0 + (wr << 6) + ((lane >> 4) << 2);
    const int ccol = col0 + wc * (BN / 2) + (lane & 15);
    #pragma unroll
    for (int m = 0; m < 4; ++m)
        #pragma unroll
        for (int n = 0; n < FN; ++n)
            #pragma unroll
            for (int r = 0; r < 4; ++r) {
                size_t idx = (size_t)(crow + m * 16 + r) * ldc + ccol + n * 16;
                float v = acc[m][n][r];
                if (resid) v += resid[idx];
                if (OUTBF) ((bf16*)Cout)[(size_t)z * sC + idx] = (bf16)v;
                else       ((float*)Cout)[(size_t)z * sC + idx] = v;
            }
}

// ============ transpose-cast: in [R][C] (f32 or bf16) -> out bf16 [C][R] ============
template<typename TI>
__global__ __launch_bounds__(256) void tcast(
    const TI* __restrict__ in, bf16* __restrict__ out,
    int lin, int lout, long long sin, long long sout)
{
    __shared__ float t[32][33];
    in  += (size_t)blockIdx.z * sin;
    out += (size_t)blockIdx.z * sout;
    const int c0 = blockIdx.x * 32, r0 = blockIdx.y * 32;
    const int tx = threadIdx.x & 31, ty = threadIdx.x >> 5;
    #pragma unroll
    for (int j = 0; j < 4; ++j)
        t[ty + j * 8][tx] = (float)in[(size_t)(r0 + ty + j * 8) * lin + c0 + tx];
    __syncthreads();
    #pragma unroll
    for (int j = 0; j < 4; ++j)
        out[(size_t)(c0 + ty + j * 8) * lout + r0 + tx] = (bf16)t[tx][ty + j * 8];
}

// ============ RMSNorm -> bf16 out (vectorized, D=1024, 256 thr) ============
__global__ __launch_bounds__(256) void rmsnorm_bf(
    const float* __restrict__ x, const float* __restrict__ w, bf16* __restrict__ out)
{
    __shared__ float red[4];
    const int row = blockIdx.x, tid = threadIdx.x;
    const float* xr = x + (size_t)row * D_;
    f32x4 v = *(const f32x4*)(xr + tid * 4);
    float ss = v.x * v.x + v.y * v.y + v.z * v.z + v.w * v.w;
    #pragma unroll
    for (int off = 32; off > 0; off >>= 1) ss += __shfl_xor(ss, off);
    if ((tid & 63) == 0) red[tid >> 6] = ss;
    __syncthreads();
    float scn = rsqrtf((red[0] + red[1] + red[2] + red[3]) * (1.f / D_) + 1e-6f);
    f32x4 wv = *(const f32x4*)(w + tid * 4);
    bf16x4 o;
    o[0] = (bf16)(v.x * scn * wv.x); o[1] = (bf16)(v.y * scn * wv.y);
    o[2] = (bf16)(v.z * scn * wv.z); o[3] = (bf16)(v.w * scn * wv.w);
    *(bf16x4*)(out + (size_t)row * D_ + tid * 4) = o;
}

// ============ RoPE in-place on bf16 qkv buffer [tok][3072]; q scaled 1/8 ============
__global__ void rope_kernel(bf16* __restrict__ qkv,
                            const float* __restrict__ cosp, const float* __restrict__ sinp)
{
    int idx = blockIdx.x * 256 + threadIdx.x;   // B*S*H*32
    int p = idx & 31, hh = (idx >> 5) & 15, s = (idx >> 9) & 1023, b = idx >> 19;
    size_t base = ((size_t)(b * S_ + s)) * 3072 + hh * 64;
    float c1 = cosp[s * 64 + p],      s1 = sinp[s * 64 + p];
    float c2 = cosp[s * 64 + p + 32], s2 = sinp[s * 64 + p + 32];
    float q1 = (float)qkv[base + p], q2 = (float)qkv[base + p + 32];
    qkv[base + p]      = (bf16)((q1 * c1 - q2 * s1) * 0.125f);
    qkv[base + p + 32] = (bf16)((q2 * c2 + q1 * s2) * 0.125f);
    size_t kb = base + 1024;
    float k1 = (float)qkv[kb + p], k2 = (float)qkv[kb + p + 32];
    qkv[kb + p]      = (bf16)(k1 * c1 - k2 * s1);
    qkv[kb + p + 32] = (bf16)(k2 * c2 + k1 * s2);
}

// ============ causal softmax on bf16 score rows (in-place), vectorized ============
__global__ __launch_bounds__(256) void attn_softmax(bf16* __restrict__ sb)
{
    __shared__ float red[4];
    const int row = blockIdx.x, qs = row & 1023, tid = threadIdx.x;
    bf16* r = sb + (size_t)row * 1024;
    bf16x4 v = *(const bf16x4*)(r + tid * 4);
    float xs[4];
    float mx = -1e30f;
    #pragma unroll
    for (int i = 0; i < 4; ++i) {
        int j = tid * 4 + i;
        xs[i] = (j <= qs) ? (float)v[i] : -1e30f;
        mx = fmaxf(mx, xs[i]);
    }
    #pragma unroll
    for (int off = 32; off > 0; off >>= 1) mx = fmaxf(mx, __shfl_xor(mx, off));
    if ((tid & 63) == 0) red[tid >> 6] = mx;
    __syncthreads();
    mx = fmaxf(fmaxf(red[0], red[1]), fmaxf(red[2], red[3]));
    __syncthreads();
    float p[4], sum = 0.f;
    #pragma unroll
    for (int i = 0; i < 4; ++i) {
        p[i] = (tid * 4 + i <= qs) ? __expf(xs[i] - mx) : 0.f;
        sum += p[i];
    }
    #pragma unroll
    for (int off = 32; off > 0; off >>= 1) sum += __shfl_xor(sum, off);
    if ((tid & 63) == 0) red[tid >> 6] = sum;
    __syncthreads();
    float inv = 1.f / (red[0] + red[1] + red[2] + red[3]);
    bf16x4 o;
    #pragma unroll
    for (int i = 0; i < 4; ++i) o[i] = (bf16)(p[i] * inv);
    *(bf16x4*)(r + tid * 4) = o;
}

// ============ memory softmax: f32 [row][2048] -> bf16 probs, scale 1/16 ============
__global__ __launch_bounds__(256) void mem_softmax(
    const float* __restrict__ ms, bf16* __restrict__ out)
{
    __shared__ float red[4];
    const int row = blockIdx.x, tid = threadIdx.x;
    const float* r = ms + (size_t)row * 2048;
    f32x4 a = *(const f32x4*)(r + tid * 8);
    f32x4 b = *(const f32x4*)(r + tid * 8 + 4);
    float xs[8] = {a.x, a.y, a.z, a.w, b.x, b.y, b.z, b.w};
    float mx = -1e30f;
    #pragma unroll
    for (int i = 0; i < 8; ++i) mx = fmaxf(mx, xs[i]);
    #pragma unroll
    for (int off = 32; off > 0; off >>= 1) mx = fmaxf(mx, __shfl_xor(mx, off));
    if ((tid & 63) == 0) red[tid >> 6] = mx;
    __syncthreads();
    mx = fmaxf(fmaxf(red[0], red[1]), fmaxf(red[2], red[3]));
    __syncthreads();
    float sum = 0.f;
    #pragma unroll
    for (int i = 0; i < 8; ++i) { xs[i] = __expf((xs[i] - mx) * 0.0625f); sum += xs[i]; }
    #pragma unroll
    for (int off = 32; off > 0; off >>= 1) sum += __shfl_xor(sum, off);
    if ((tid & 63) == 0) red[tid >> 6] = sum;
    __syncthreads();
    float inv = 1.f / (red[0] + red[1] + red[2] + red[3]);
    bf16x8 o;
    #pragma unroll
    for (int i = 0; i < 8; ++i) o[i] = (bf16)(xs[i] * inv);
    *(bf16x8*)(out + (size_t)row * 2048 + tid * 8) = o;
}

// ============ small elementwise kernels ============
__global__ void strength_kernel(const float* __restrict__ h, const float* __restrict__ ws,
                                float* __restrict__ st)
{
    const int row = blockIdx.x, lane = threadIdx.x;
    const float* hr = h + (size_t)row * D_;
    float s = 0.f;
    #pragma unroll
    for (int it = 0; it < 4; ++it) {
        f32x4 hv = *(const f32x4*)(hr + it * 256 + lane * 4);
        f32x4 wv = *(const f32x4*)(ws + it * 256 + lane * 4);
        s += hv.x * wv.x + hv.y * wv.y + hv.z * wv.z + hv.w * wv.w;
    }
    #pragma unroll
    for (int off = 32; off > 0; off >>= 1) s += __shfl_xor(s, off);
    if (lane == 0) st[row] = 1.f / (1.f + expf(-s));
}

__global__ void scatter_keys_kernel(const float* __restrict__ ctcp, const float* __restrict__ st,
                                    const float* __restrict__ memk, const int* __restrict__ pos,
                                    float* __restrict__ outk)
{
    int idx = blockIdx.x * 256 + threadIdx.x;    // B*S*DC/4
    int c = (idx & 63) * 4;
    int s = (idx >> 6) & (S_ - 1);
    int b = idx >> 16;
    int row = (pos[0] + s) % M_;
    float t = st[b * S_ + s];
    size_t mi = ((size_t)b * M_ + row) * DC_ + c;
    f32x4 cv = *(const f32x4*)(ctcp + ((size_t)b * S_ + s) * 1280 + 1024 + c);
    f32x4 mv = *(const f32x4*)(memk + mi);
    f32x4 o = {t * cv.x + (1.f - t) * mv.x, t * cv.y + (1.f - t) * mv.y,
               t * cv.z + (1.f - t) * mv.z, t * cv.w + (1.f - t) * mv.w};
    *(f32x4*)(outk + mi) = o;
}

__global__ void scatter_vals_kernel(const float* __restrict__ ctcp, const float* __restrict__ st,
                                    const float* __restrict__ memv, const int* __restrict__ pos,
                                    float* __restrict__ outv)
{
    int idx = blockIdx.x * 256 + threadIdx.x;    // B*S*D/4
    int c = (idx & 255) * 4;
    int s = (idx >> 8) & (S_ - 1);
    int b = idx >> 18;
    int row = (pos[0] + s) % M_;
    float t = st[b * S_ + s];
    size_t mi = ((size_t)b * M_ + row) * D_ + c;
    f32x4 cv = *(const f32x4*)(ctcp + ((size_t)b * S_ + s) * 1280 + c);
    f32x4 mv = *(const f32x4*)(memv + mi);
    f32x4 o = {t * cv.x + (1.f - t) * mv.x, t * cv.y + (1.f - t) * mv.y,
               t * cv.z + (1.f - t) * mv.z, t * cv.w + (1.f - t) * mv.w};
    *(f32x4*)(outv + mi) = o;
}

__global__ void cast_h1_kernel(const float* __restrict__ h1, bf16* __restrict__ cat)
{
    int i = blockIdx.x * 256 + threadIdx.x;      // NTOK*D/4
    int row = i >> 8, c = (i & 255) * 4;
    f32x4 v = *(const f32x4*)(h1 + (size_t)row * 1024 + c);
    bf16x4 o = {(bf16)v.x, (bf16)v.y, (bf16)v.z, (bf16)v.w};
    *(bf16x4*)(cat + (size_t)row * 2048 + c) = o;
}

__global__ void cast_flat_kernel(const float* __restrict__ in, bf16* __restrict__ out)
{
    int i = blockIdx.x * 256 + threadIdx.x;
    f32x4 v = *(const f32x4*)(in + (size_t)i * 4);
    bf16x4 o = {(bf16)v.x, (bf16)v.y, (bf16)v.z, (bf16)v.w};
    *(bf16x4*)(out + (size_t)i * 4) = o;
}

__global__ void gatecomb_kernel(const float* __restrict__ h1, const float* __restrict__ g,
                                const float* __restrict__ p, float* __restrict__ h2)
{
    int i = blockIdx.x * 256 + threadIdx.x;
    f32x4 hv = *(const f32x4*)(h1 + (size_t)i * 4);
    f32x4 gv = *(const f32x4*)(g + (size_t)i * 4);
    f32x4 pv = *(const f32x4*)(p + (size_t)i * 4);
    f32x4 o;
    o.x = hv.x + pv.x / (1.f + expf(-gv.x));
    o.y = hv.y + pv.y / (1.f + expf(-gv.y));
    o.z = hv.z + pv.z / (1.f + expf(-gv.z));
    o.w = hv.w + pv.w / (1.f + expf(-gv.w));
    *(f32x4*)(h2 + (size_t)i * 4) = o;
}

__global__ void silumul_kernel(const bf16* __restrict__ a13, bf16* __restrict__ a1bf)
{
    int i = blockIdx.x * 256 + threadIdx.x;      // NTOK*F/4
    int row = i >> 10, c = (i & 1023) * 4;
    bf16x4 xv = *(const bf16x4*)(a13 + (size_t)row * 8192 + c);
    bf16x4 yv = *(const bf16x4*)(a13 + (size_t)row * 8192 + 4096 + c);
    bf16x4 o;
    #pragma unroll
    for (int j = 0; j < 4; ++j) {
        float x = (float)xv[j];
        o[j] = (bf16)((x / (1.f + expf(-x))) * (float)yv[j]);
    }
    *(bf16x4*)(a1bf + (size_t)row * 4096 + c) = o;
}

extern "C" void kernel_launch(void* const* d_in, const int* in_sizes, int n_in,
                              void* d_out, int out_size, void* d_ws, size_t ws_size,
                              hipStream_t stream)
{
    const float* h0   = (const float*)d_in[0];
    const float* memk = (const float*)d_in[1];
    const float* memv = (const float*)d_in[2];
    const float* cosp = (const float*)d_in[3];
    const float* sinp = (const float*)d_in[4];
    const float* n1w  = (const float*)d_in[5];
    const float* n2w  = (const float*)d_in[6];
    const float* nmw  = (const float*)d_in[7];
    const float* Wq   = (const float*)d_in[8];
    const float* Wk   = (const float*)d_in[9];
    const float* Wv   = (const float*)d_in[10];
    const float* Wo   = (const float*)d_in[11];
    const float* Wct  = (const float*)d_in[12];
    const float* Wcp  = (const float*)d_in[13];
    const float* Wst  = (const float*)d_in[14];
    const float* Wqr  = (const float*)d_in[15];
    const float* Wg   = (const float*)d_in[16];
    const float* Wpj  = (const float*)d_in[17];
    const float* W1   = (const float*)d_in[18];
    const float* W3   = (const float*)d_in[19];
    const float* W2   = (const float*)d_in[20];
    const int*   pos  = (const int*)d_in[21];

    float* out_h = (float*)d_out;
    float* out_k = out_h + (size_t)NTOK * D_;
    float* out_v = out_k + (size_t)B_ * M_ * DC_;

    char* W = (char*)d_ws;
    const size_t MB = 1u << 20;
    bf16*  sbf  = (bf16*)(W);               // 32 MB scores/probs per-b [16][1024][1024]
    float* msb  = (float*)(W + 32 * MB);    // 16 MB mem scores f32
    bf16*  matt = (bf16*)(W + 48 * MB);     // 8 MB  mem probs bf16
    bf16*  nvt  = (bf16*)(W + 56 * MB);     // 8 MB  new_values^T bf16
    bf16*  a13  = (bf16*)(W);               // 32 MB MLP up bf16 [2048][8192] (overlays sbf)
    bf16*  qkvb = (bf16*)(W + 64 * MB);     // 12 MB [2048][3072]
    bf16*  vtb  = (bf16*)(W + 76 * MB);     // 4 MB  [32][64][1024]
    bf16*  a1bf = (bf16*)(W + 64 * MB);     // 16 MB (overlays qkvb+vtb)
    bf16*  abf  = (bf16*)(W + 80 * MB);     // 4 MB  attn out bf16
    float* h1b  = (float*)(W + 84 * MB);    // 8 MB
    bf16*  catbf= (bf16*)(W + 92 * MB);     // 8 MB  [2048][2048] = [h1bf | retr]
    bf16*  nbf  = (bf16*)(W + 100 * MB);    // 4 MB  rmsnorm out
    float* ctcp = (float*)(W + 104 * MB);   // 10.5 MB [2048][1280]; later proj
    bf16*  okbf = (bf16*)(W + 115 * MB);    // 2 MB
    bf16*  qmbf = (bf16*)(W + 117 * MB);    // 1 MB
    float* aob  = (float*)(W + 118 * MB);   // 8 MB  gate pre-act
    float* h2b  = (float*)(W + 126 * MB);   // 8 MB
    float* stb  = (float*)(W + 134 * MB);   // 8 KB
    bf16*  WqkvT= (bf16*)(W + 135 * MB);    // 6 MB
    bf16*  WoT  = (bf16*)(W + 141 * MB);    // 2 MB
    bf16*  WctcpT=(bf16*)(W + 143 * MB);    // 2.5 MB
    bf16*  WqrT = (bf16*)(W + 146 * MB);    // 0.5 MB
    bf16*  WgT  = (bf16*)(W + 147 * MB);    // 4 MB
    bf16*  WpjT = (bf16*)(W + 151 * MB);    // 2 MB
    bf16*  W13T = (bf16*)(W + 153 * MB);    // 16 MB
    bf16*  W2T  = (bf16*)(W + 169 * MB);    // 8 MB

    // ---- weight transpose-casts ----
    tcast<float><<<dim3(32, 32, 1), 256, 0, stream>>>(Wq,  WqkvT,                1024, 1024, 0, 0);
    tcast<float><<<dim3(32, 32, 1), 256, 0, stream>>>(Wk,  WqkvT + 1024 * 1024,  1024, 1024, 0, 0);
    tcast<float><<<dim3(32, 32, 1), 256, 0, stream>>>(Wv,  WqkvT + 2048 * 1024,  1024, 1024, 0, 0);
    tcast<float><<<dim3(32, 32, 1), 256, 0, stream>>>(Wo,  WoT,                  1024, 1024, 0, 0);
    tcast<float><<<dim3(32, 32, 1), 256, 0, stream>>>(Wct, WctcpT,               1024, 1024, 0, 0);
    tcast<float><<<dim3(8, 32, 1), 256, 0, stream>>>(Wcp,  WctcpT + 1024 * 1024, 256, 1024, 0, 0);
    tcast<float><<<dim3(8, 32, 1), 256, 0, stream>>>(Wqr,  WqrT,                 256, 1024, 0, 0);
    tcast<float><<<dim3(32, 64, 1), 256, 0, stream>>>(Wg,  WgT,                  1024, 2048, 0, 0);
    tcast<float><<<dim3(32, 32, 1), 256, 0, stream>>>(Wpj, WpjT,                 1024, 1024, 0, 0);
    tcast<float><<<dim3(128, 32, 1), 256, 0, stream>>>(W1, W13T,                 4096, 1024, 0, 0);
    tcast<float><<<dim3(128, 32, 1), 256, 0, stream>>>(W3, W13T + 4096 * 1024,   4096, 1024, 0, 0);
    tcast<float><<<dim3(32, 128, 1), 256, 0, stream>>>(W2, W2T,                  1024, 4096, 0, 0);

    // ---- 1. n = rmsnorm(h0); qkv = n @ [Wq|Wk|Wv]; RoPE; V^T ----
    rmsnorm_bf<<<NTOK, 256, 0, stream>>>(h0, n1w, nbf);
    mgemm<128, 0, true><<<dim3(24, 16, 1), 256, 0, stream>>>(
        nbf, WqkvT, nullptr, qkvb, 1024, 1024, 1024, 3072, 0, 0, 0);
    rope_kernel<<<(B_ * S_ * H_ * 32) / 256, 256, 0, stream>>>(qkvb, cosp, sinp);
    for (int b = 0; b < B_; ++b)
        tcast<bf16><<<dim3(2, 32, 16), 256, 0, stream>>>(
            qkvb + (size_t)b * S_ * 3072 + 2048, vtb + (size_t)b * 16 * 65536,
            3072, 1024, 64, 65536);

    // ---- 2. causal attention per batch ----
    for (int b = 0; b < B_; ++b) {
        const bf16* qbase = qkvb + (size_t)b * S_ * 3072;
        mgemm<128, 1, true><<<dim3(8, 8, 16), 256, 0, stream>>>(
            qbase, qbase + 1024, nullptr, sbf, 64, 3072, 3072, 1024,
            64, 64, 1024 * 1024);
        attn_softmax<<<16 * 1024, 256, 0, stream>>>(sbf);
        mgemm<64, 2, true><<<dim3(1, 8, 16), 256, 0, stream>>>(
            sbf, vtb + (size_t)b * 16 * 65536, nullptr, abf + (size_t)b * S_ * 1024,
            1024, 1024, 1024, 1024, 1024 * 1024, 65536, 64);
    }

    // ---- 3. h1 = h0 + attn @ Wo ----
    mgemm<64, 0, false><<<dim3(16, 16, 1), 256, 0, stream>>>(
        abf, WoT, h0, h1b, 1024, 1024, 1024, 1024, 0, 0, 0);
    cast_h1_kernel<<<(NTOK * D_) / 1024, 256, 0, stream>>>(h1b, catbf);
    strength_kernel<<<NTOK, 64, 0, stream>>>(h1b, Wst, stb);

    // ---- 4. content|compressed; memory scatter ----
    mgemm<64, 0, false><<<dim3(20, 16, 1), 256, 0, stream>>>(
        catbf, WctcpT, nullptr, ctcp, 1024, 2048, 1024, 1280, 0, 0, 0);
    hipMemcpyAsync(out_k, memk, (size_t)B_ * M_ * DC_ * sizeof(float), hipMemcpyDeviceToDevice, stream);
    hipMemcpyAsync(out_v, memv, (size_t)B_ * M_ * D_ * sizeof(float), hipMemcpyDeviceToDevice, stream);
    scatter_keys_kernel<<<(B_ * S_ * DC_) / 1024, 256, 0, stream>>>(ctcp, stb, memk, pos, out_k);
    scatter_vals_kernel<<<(B_ * S_ * D_) / 1024, 256, 0, stream>>>(ctcp, stb, memv, pos, out_v);

    // ---- 5. memory attention ----
    rmsnorm_bf<<<NTOK, 256, 0, stream>>>(h1b, nmw, nbf);
    mgemm<64, 0, true><<<dim3(4, 16, 1), 256, 0, stream>>>(
        nbf, WqrT, nullptr, qmbf, 1024, 1024, 1024, 256, 0, 0, 0);
    cast_flat_kernel<<<(B_ * M_ * DC_) / 1024, 256, 0, stream>>>(out_k, okbf);
    mgemm<128, 0, false><<<dim3(16, 8, 2), 256, 0, stream>>>(
        qmbf, okbf, nullptr, msb, 256, 256, 256, 2048,
        (long long)S_ * 256, (long long)M_ * 256, (long long)S_ * 2048);
    mem_softmax<<<NTOK, 256, 0, stream>>>(msb, matt);
    tcast<float><<<dim3(32, 64, 2), 256, 0, stream>>>(
        out_v, nvt, 1024, 2048, (long long)M_ * 1024, (long long)1024 * 2048);
    mgemm<128, 0, true><<<dim3(8, 8, 2), 256, 0, stream>>>(
        matt, nvt, nullptr, catbf + 1024, 2048, 2048, 2048, 2048,
        (long long)S_ * 2048, (long long)1024 * 2048, (long long)S_ * 2048);

    // ---- 6. gate + proj + combine ----
    mgemm<64, 0, false><<<dim3(16, 16, 1), 256, 0, stream>>>(
        catbf, WgT, nullptr, aob, 2048, 2048, 2048, 1024, 0, 0, 0);
    mgemm<64, 0, false><<<dim3(16, 16, 1), 256, 0, stream>>>(
        catbf + 1024, WpjT, nullptr, ctcp, 1024, 2048, 1024, 1024, 0, 0, 0);
    gatecomb_kernel<<<(NTOK * D_) / 1024, 256, 0, stream>>>(h1b, aob, ctcp, h2b);

    // ---- 7. MLP ----
    rmsnorm_bf<<<NTOK, 256, 0, stream>>>(h2b, n2w, nbf);
    mgemm<128, 0, true><<<dim3(64, 16, 1), 256, 0, stream>>>(
        nbf, W13T, nullptr, a13, 1024, 1024, 1024, 8192, 0, 0, 0);
    silumul_kernel<<<(NTOK * F_) / 1024, 256, 0, stream>>>(a13, a1bf);
    mgemm<64, 0, false><<<dim3(16, 16, 1), 256, 0, stream>>>(
        a1bf, W2T, h2b, out_h, 4096, 4096, 4096, 1024, 0, 0, 0);
}

// Round 4
// 395.857 us; speedup vs baseline: 6.1919x; 1.1148x over previous
//
#include <hip/hip_runtime.h>
#include <hip/hip_bf16.h>
#include <math.h>

typedef __bf16 bf16;
typedef __attribute__((ext_vector_type(8))) __bf16 bf16x8;
typedef __attribute__((ext_vector_type(4))) __bf16 bf16x4;
typedef __attribute__((ext_vector_type(4))) float f32x4;

#define B_ 2
#define S_ 1024
#define D_ 1024
#define H_ 16
#define HD_ 64
#define F_ 4096
#define M_ 2048
#define DC_ 256
#define NTOK (B_*S_)

__device__ __forceinline__ void gload16(const void* g, void* l) {
    __builtin_amdgcn_global_load_lds(
        (__attribute__((address_space(1))) void*)(void*)(g),
        (__attribute__((address_space(3))) void*)(l), 16, 0, 0);
}

template<int N> __device__ __forceinline__ void wait_vm() {
    if constexpr (N == 0)      asm volatile("s_waitcnt vmcnt(0)" ::: "memory");
    else if constexpr (N == 4) asm volatile("s_waitcnt vmcnt(4)" ::: "memory");
    else if constexpr (N == 6) asm volatile("s_waitcnt vmcnt(6)" ::: "memory");
    else                       asm volatile("s_waitcnt vmcnt(8)" ::: "memory");
}

// ============ MFMA GEMM v3: C[M,N] = A[M,K] @ Bt[N,K]^T (+resid) ============
// BK=64, depth-2 prefetch pipeline with counted vmcnt + raw barriers
// (T3+T4 recipe: loads for stage t+1 stay in flight across barriers; never
// drain vmcnt to 0 mid-loop). XOR-swizzled LDS (pre-swizzled global source,
// linear gload_lds dest, swizzled ds_read). Bijective XCD block swizzle.
// CMODE: 0 none, 1 causal block-skip, 2 causal K-limit. OUTBF: bf16 out.
template<int BM, int BN, int CMODE, bool OUTBF>
__global__ __launch_bounds__(256) void mgemm(
    const bf16* __restrict__ A, const bf16* __restrict__ Bt,
    const float* __restrict__ resid, void* __restrict__ Cout,
    int K, int lda, int ldb, int ldc,
    long long sA, long long sB, long long sC)
{
    constexpr int WN   = (BM == 128) ? 2 : 4;    // waves along N
    constexpr int WCOL = BN / WN;                 // cols per wave
    constexpr int FN   = WCOL / 16;
    constexpr int LA = BM * 64, LB = BN * 64;
    constexpr int LPS = BM / 32 + BN / 32;        // per-wave loads per stage
    __shared__ bf16 lds[2 * (LA + LB)];
    const int z = blockIdx.z;
    A  += (size_t)z * sA;
    Bt += (size_t)z * sB;
    // bijective XCD-aware swizzle of the 2D tile grid (m204 formula)
    const int gx = gridDim.x;
    const int nwg = gx * gridDim.y;
    const int flat = blockIdx.y * gx + blockIdx.x;
    const int q8 = nwg >> 3, r8 = nwg & 7;
    const int xcd = flat & 7, lid = flat >> 3;
    const int swz = (xcd < r8 ? xcd * (q8 + 1) : r8 * (q8 + 1) + (xcd - r8) * q8) + lid;
    const int row0 = (swz / gx) * BM;
    const int col0 = (swz % gx) * BN;
    if (CMODE == 1 && col0 > row0 + BM - 1) return;
    const int kmax = (CMODE == 2) ? min(K, row0 + BM) : K;
    const int tid = threadIdx.x, wid = tid >> 6, lane = tid & 63;
    const int wr = wid / WN, wc = wid % WN;
    const int srow = lane >> 3;
    const int ssub = (lane & 7) ^ (srow & 7);    // inverse-swizzled 16B sub

    f32x4 acc[4][FN];
    #pragma unroll
    for (int m = 0; m < 4; ++m)
        #pragma unroll
        for (int n = 0; n < FN; ++n) acc[m][n] = (f32x4){0.f, 0.f, 0.f, 0.f};

    auto STAGE = [&](int buf, int k0) {
        bf16* Ab = lds + buf * (LA + LB);
        bf16* Bb = Ab + LA;
        #pragma unroll
        for (int i = 0; i < BM / 32; ++i) {
            int c = wid * (BM / 32) + i;
            gload16(A + (size_t)(row0 + c * 8 + srow) * lda + k0 + ssub * 8, Ab + c * 512);
        }
        #pragma unroll
        for (int i = 0; i < BN / 32; ++i) {
            int c = wid * (BN / 32) + i;
            gload16(Bt + (size_t)(col0 + c * 8 + srow) * ldb + k0 + ssub * 8, Bb + c * 512);
        }
    };

    const int nt = kmax >> 6;
    STAGE(0, 0);
    if (nt > 1) STAGE(1, 64);
    for (int t = 0; t < nt; ++t) {
        if (t < nt - 1) wait_vm<LPS>();   // stage t landed; t+1 stays in flight
        else            wait_vm<0>();
        __builtin_amdgcn_sched_barrier(0);
        __builtin_amdgcn_s_barrier();
        __builtin_amdgcn_sched_barrier(0);
        const bf16* Ab = lds + (t & 1) * (LA + LB);
        const bf16* Bb = Ab + LA;
        const int ar = wr * 64 + (lane & 15);
        const int br = wc * WCOL + (lane & 15);
        #pragma unroll
        for (int ksel = 0; ksel < 2; ++ksel) {
            const int ps = ((ksel << 2) + (lane >> 4)) ^ (lane & 7);
            bf16x8 af[4], bfr[FN];
            #pragma unroll
            for (int m = 0; m < 4; ++m)
                af[m] = *(const bf16x8*)(Ab + (ar + m * 16) * 64 + ps * 8);
            #pragma unroll
            for (int n = 0; n < FN; ++n)
                bfr[n] = *(const bf16x8*)(Bb + (br + n * 16) * 64 + ps * 8);
            #pragma unroll
            for (int m = 0; m < 4; ++m)
                #pragma unroll
                for (int n = 0; n < FN; ++n)
                    acc[m][n] = __builtin_amdgcn_mfma_f32_16x16x32_bf16(af[m], bfr[n], acc[m][n], 0, 0, 0);
        }
        asm volatile("s_waitcnt lgkmcnt(0)" ::: "memory");
        __builtin_amdgcn_sched_barrier(0);
        __builtin_amdgcn_s_barrier();
        __builtin_amdgcn_sched_barrier(0);
        if (t + 2 < nt) STAGE(t & 1, (t + 2) << 6);
    }
    const int crow = row0 + wr * 64 + ((lane >> 4) << 2);
    const int ccol = col0 + wc * WCOL + (lane & 15);
    #pragma unroll
    for (int m = 0; m < 4; ++m)
        #pragma unroll
        for (int n = 0; n < FN; ++n)
            #pragma unroll
            for (int r = 0; r < 4; ++r) {
                size_t idx = (size_t)(crow + m * 16 + r) * ldc + ccol + n * 16;
                float v = acc[m][n][r];
                if (resid) v += resid[idx];
                if (OUTBF) ((bf16*)Cout)[(size_t)z * sC + idx] = (bf16)v;
                else       ((float*)Cout)[(size_t)z * sC + idx] = v;
            }
}

// ============ transpose-cast: in [R][C] (f32 or bf16) -> out bf16 [C][R] ============
template<typename TI>
__global__ __launch_bounds__(256) void tcast(
    const TI* __restrict__ in, bf16* __restrict__ out,
    int lin, int lout, long long sin, long long sout)
{
    __shared__ float t[32][33];
    in  += (size_t)blockIdx.z * sin;
    out += (size_t)blockIdx.z * sout;
    const int c0 = blockIdx.x * 32, r0 = blockIdx.y * 32;
    const int tx = threadIdx.x & 31, ty = threadIdx.x >> 5;
    #pragma unroll
    for (int j = 0; j < 4; ++j)
        t[ty + j * 8][tx] = (float)in[(size_t)(r0 + ty + j * 8) * lin + c0 + tx];
    __syncthreads();
    #pragma unroll
    for (int j = 0; j < 4; ++j)
        out[(size_t)(c0 + ty + j * 8) * lout + r0 + tx] = (bf16)t[tx][ty + j * 8];
}

// ============ RMSNorm -> bf16 out ============
__global__ __launch_bounds__(256) void rmsnorm_bf(
    const float* __restrict__ x, const float* __restrict__ w, bf16* __restrict__ out)
{
    __shared__ float red[4];
    const int row = blockIdx.x, tid = threadIdx.x;
    const float* xr = x + (size_t)row * D_;
    f32x4 v = *(const f32x4*)(xr + tid * 4);
    float ss = v.x * v.x + v.y * v.y + v.z * v.z + v.w * v.w;
    #pragma unroll
    for (int off = 32; off > 0; off >>= 1) ss += __shfl_xor(ss, off);
    if ((tid & 63) == 0) red[tid >> 6] = ss;
    __syncthreads();
    float scn = rsqrtf((red[0] + red[1] + red[2] + red[3]) * (1.f / D_) + 1e-6f);
    f32x4 wv = *(const f32x4*)(w + tid * 4);
    bf16x4 o;
    o[0] = (bf16)(v.x * scn * wv.x); o[1] = (bf16)(v.y * scn * wv.y);
    o[2] = (bf16)(v.z * scn * wv.z); o[3] = (bf16)(v.w * scn * wv.w);
    *(bf16x4*)(out + (size_t)row * D_ + tid * 4) = o;
}

// ============ RoPE in-place on bf16 qkv buffer [tok][3072]; q scaled 1/8 ============
__global__ void rope_kernel(bf16* __restrict__ qkv,
                            const float* __restrict__ cosp, const float* __restrict__ sinp)
{
    int idx = blockIdx.x * 256 + threadIdx.x;   // B*S*H*32
    int p = idx & 31, hh = (idx >> 5) & 15, s = (idx >> 9) & 1023, b = idx >> 19;
    size_t base = ((size_t)(b * S_ + s)) * 3072 + hh * 64;
    float c1 = cosp[s * 64 + p],      s1 = sinp[s * 64 + p];
    float c2 = cosp[s * 64 + p + 32], s2 = sinp[s * 64 + p + 32];
    float q1 = (float)qkv[base + p], q2 = (float)qkv[base + p + 32];
    qkv[base + p]      = (bf16)((q1 * c1 - q2 * s1) * 0.125f);
    qkv[base + p + 32] = (bf16)((q2 * c2 + q1 * s2) * 0.125f);
    size_t kb = base + 1024;
    float k1 = (float)qkv[kb + p], k2 = (float)qkv[kb + p + 32];
    qkv[kb + p]      = (bf16)(k1 * c1 - k2 * s1);
    qkv[kb + p + 32] = (bf16)(k2 * c2 + k1 * s2);
}

// ============ causal softmax on bf16 score rows (in-place), vectorized ============
__global__ __launch_bounds__(256) void attn_softmax(bf16* __restrict__ sb)
{
    __shared__ float red[4];
    const int row = blockIdx.x, qs = row & 1023, tid = threadIdx.x;
    bf16* r = sb + (size_t)row * 1024;
    bf16x4 v = *(const bf16x4*)(r + tid * 4);
    float xs[4];
    float mx = -1e30f;
    #pragma unroll
    for (int i = 0; i < 4; ++i) {
        int j = tid * 4 + i;
        xs[i] = (j <= qs) ? (float)v[i] : -1e30f;
        mx = fmaxf(mx, xs[i]);
    }
    #pragma unroll
    for (int off = 32; off > 0; off >>= 1) mx = fmaxf(mx, __shfl_xor(mx, off));
    if ((tid & 63) == 0) red[tid >> 6] = mx;
    __syncthreads();
    mx = fmaxf(fmaxf(red[0], red[1]), fmaxf(red[2], red[3]));
    __syncthreads();
    float p[4], sum = 0.f;
    #pragma unroll
    for (int i = 0; i < 4; ++i) {
        p[i] = (tid * 4 + i <= qs) ? __expf(xs[i] - mx) : 0.f;
        sum += p[i];
    }
    #pragma unroll
    for (int off = 32; off > 0; off >>= 1) sum += __shfl_xor(sum, off);
    if ((tid & 63) == 0) red[tid >> 6] = sum;
    __syncthreads();
    float inv = 1.f / (red[0] + red[1] + red[2] + red[3]);
    bf16x4 o;
    #pragma unroll
    for (int i = 0; i < 4; ++i) o[i] = (bf16)(p[i] * inv);
    *(bf16x4*)(r + tid * 4) = o;
}

// ============ memory softmax: f32 [row][2048] -> bf16 probs, scale 1/16 ============
__global__ __launch_bounds__(256) void mem_softmax(
    const float* __restrict__ ms, bf16* __restrict__ out)
{
    __shared__ float red[4];
    const int row = blockIdx.x, tid = threadIdx.x;
    const float* r = ms + (size_t)row * 2048;
    f32x4 a = *(const f32x4*)(r + tid * 8);
    f32x4 b = *(const f32x4*)(r + tid * 8 + 4);
    float xs[8] = {a.x, a.y, a.z, a.w, b.x, b.y, b.z, b.w};
    float mx = -1e30f;
    #pragma unroll
    for (int i = 0; i < 8; ++i) mx = fmaxf(mx, xs[i]);
    #pragma unroll
    for (int off = 32; off > 0; off >>= 1) mx = fmaxf(mx, __shfl_xor(mx, off));
    if ((tid & 63) == 0) red[tid >> 6] = mx;
    __syncthreads();
    mx = fmaxf(fmaxf(red[0], red[1]), fmaxf(red[2], red[3]));
    __syncthreads();
    float sum = 0.f;
    #pragma unroll
    for (int i = 0; i < 8; ++i) { xs[i] = __expf((xs[i] - mx) * 0.0625f); sum += xs[i]; }
    #pragma unroll
    for (int off = 32; off > 0; off >>= 1) sum += __shfl_xor(sum, off);
    if ((tid & 63) == 0) red[tid >> 6] = sum;
    __syncthreads();
    float inv = 1.f / (red[0] + red[1] + red[2] + red[3]);
    bf16x8 o;
    #pragma unroll
    for (int i = 0; i < 8; ++i) o[i] = (bf16)(xs[i] * inv);
    *(bf16x8*)(out + (size_t)row * 2048 + tid * 8) = o;
}

// ============ small elementwise kernels ============
__global__ void strength_kernel(const float* __restrict__ h, const float* __restrict__ ws,
                                float* __restrict__ st)
{
    const int row = blockIdx.x, lane = threadIdx.x;
    const float* hr = h + (size_t)row * D_;
    float s = 0.f;
    #pragma unroll
    for (int it = 0; it < 4; ++it) {
        f32x4 hv = *(const f32x4*)(hr + it * 256 + lane * 4);
        f32x4 wv = *(const f32x4*)(ws + it * 256 + lane * 4);
        s += hv.x * wv.x + hv.y * wv.y + hv.z * wv.z + hv.w * wv.w;
    }
    #pragma unroll
    for (int off = 32; off > 0; off >>= 1) s += __shfl_xor(s, off);
    if (lane == 0) st[row] = 1.f / (1.f + expf(-s));
}

__global__ void scatter_keys_kernel(const float* __restrict__ ctcp, const float* __restrict__ st,
                                    const float* __restrict__ memk, const int* __restrict__ pos,
                                    float* __restrict__ outk)
{
    int idx = blockIdx.x * 256 + threadIdx.x;    // B*S*DC/4
    int c = (idx & 63) * 4;
    int s = (idx >> 6) & (S_ - 1);
    int b = idx >> 16;
    int row = (pos[0] + s) % M_;
    float t = st[b * S_ + s];
    size_t mi = ((size_t)b * M_ + row) * DC_ + c;
    f32x4 cv = *(const f32x4*)(ctcp + ((size_t)b * S_ + s) * 1280 + 1024 + c);
    f32x4 mv = *(const f32x4*)(memk + mi);
    f32x4 o = {t * cv.x + (1.f - t) * mv.x, t * cv.y + (1.f - t) * mv.y,
               t * cv.z + (1.f - t) * mv.z, t * cv.w + (1.f - t) * mv.w};
    *(f32x4*)(outk + mi) = o;
}

__global__ void scatter_vals_kernel(const float* __restrict__ ctcp, const float* __restrict__ st,
                                    const float* __restrict__ memv, const int* __restrict__ pos,
                                    float* __restrict__ outv)
{
    int idx = blockIdx.x * 256 + threadIdx.x;    // B*S*D/4
    int c = (idx & 255) * 4;
    int s = (idx >> 8) & (S_ - 1);
    int b = idx >> 18;
    int row = (pos[0] + s) % M_;
    float t = st[b * S_ + s];
    size_t mi = ((size_t)b * M_ + row) * D_ + c;
    f32x4 cv = *(const f32x4*)(ctcp + ((size_t)b * S_ + s) * 1280 + c);
    f32x4 mv = *(const f32x4*)(memv + mi);
    f32x4 o = {t * cv.x + (1.f - t) * mv.x, t * cv.y + (1.f - t) * mv.y,
               t * cv.z + (1.f - t) * mv.z, t * cv.w + (1.f - t) * mv.w};
    *(f32x4*)(outv + mi) = o;
}

__global__ void cast_h1_kernel(const float* __restrict__ h1, bf16* __restrict__ cat)
{
    int i = blockIdx.x * 256 + threadIdx.x;      // NTOK*D/4
    int row = i >> 8, c = (i & 255) * 4;
    f32x4 v = *(const f32x4*)(h1 + (size_t)row * 1024 + c);
    bf16x4 o = {(bf16)v.x, (bf16)v.y, (bf16)v.z, (bf16)v.w};
    *(bf16x4*)(cat + (size_t)row * 2048 + c) = o;
}

__global__ void cast_flat_kernel(const float* __restrict__ in, bf16* __restrict__ out)
{
    int i = blockIdx.x * 256 + threadIdx.x;
    f32x4 v = *(const f32x4*)(in + (size_t)i * 4);
    bf16x4 o = {(bf16)v.x, (bf16)v.y, (bf16)v.z, (bf16)v.w};
    *(bf16x4*)(out + (size_t)i * 4) = o;
}

__global__ void gatecomb_kernel(const float* __restrict__ h1, const float* __restrict__ g,
                                const float* __restrict__ p, float* __restrict__ h2)
{
    int i = blockIdx.x * 256 + threadIdx.x;
    f32x4 hv = *(const f32x4*)(h1 + (size_t)i * 4);
    f32x4 gv = *(const f32x4*)(g + (size_t)i * 4);
    f32x4 pv = *(const f32x4*)(p + (size_t)i * 4);
    f32x4 o;
    o.x = hv.x + pv.x / (1.f + expf(-gv.x));
    o.y = hv.y + pv.y / (1.f + expf(-gv.y));
    o.z = hv.z + pv.z / (1.f + expf(-gv.z));
    o.w = hv.w + pv.w / (1.f + expf(-gv.w));
    *(f32x4*)(h2 + (size_t)i * 4) = o;
}

__global__ void silumul_kernel(const bf16* __restrict__ a13, bf16* __restrict__ a1bf)
{
    int i = blockIdx.x * 256 + threadIdx.x;      // NTOK*F/4
    int row = i >> 10, c = (i & 1023) * 4;
    bf16x4 xv = *(const bf16x4*)(a13 + (size_t)row * 8192 + c);
    bf16x4 yv = *(const bf16x4*)(a13 + (size_t)row * 8192 + 4096 + c);
    bf16x4 o;
    #pragma unroll
    for (int j = 0; j < 4; ++j) {
        float x = (float)xv[j];
        o[j] = (bf16)((x / (1.f + expf(-x))) * (float)yv[j]);
    }
    *(bf16x4*)(a1bf + (size_t)row * 4096 + c) = o;
}

extern "C" void kernel_launch(void* const* d_in, const int* in_sizes, int n_in,
                              void* d_out, int out_size, void* d_ws, size_t ws_size,
                              hipStream_t stream)
{
    const float* h0   = (const float*)d_in[0];
    const float* memk = (const float*)d_in[1];
    const float* memv = (const float*)d_in[2];
    const float* cosp = (const float*)d_in[3];
    const float* sinp = (const float*)d_in[4];
    const float* n1w  = (const float*)d_in[5];
    const float* n2w  = (const float*)d_in[6];
    const float* nmw  = (const float*)d_in[7];
    const float* Wq   = (const float*)d_in[8];
    const float* Wk   = (const float*)d_in[9];
    const float* Wv   = (const float*)d_in[10];
    const float* Wo   = (const float*)d_in[11];
    const float* Wct  = (const float*)d_in[12];
    const float* Wcp  = (const float*)d_in[13];
    const float* Wst  = (const float*)d_in[14];
    const float* Wqr  = (const float*)d_in[15];
    const float* Wg   = (const float*)d_in[16];
    const float* Wpj  = (const float*)d_in[17];
    const float* W1   = (const float*)d_in[18];
    const float* W3   = (const float*)d_in[19];
    const float* W2   = (const float*)d_in[20];
    const int*   pos  = (const int*)d_in[21];

    float* out_h = (float*)d_out;
    float* out_k = out_h + (size_t)NTOK * D_;
    float* out_v = out_k + (size_t)B_ * M_ * DC_;

    char* W = (char*)d_ws;
    const size_t MB = 1u << 20;
    // phase-overlaid regions (total 165 MB)
    bf16*  sbf  = (bf16*)(W);               // 64 MB scores both batches [2][16][1024][1024]
    float* msb  = (float*)(W);              // 16 MB mem scores (after PV)
    bf16*  matt = (bf16*)(W + 16 * MB);     // 8 MB mem probs
    bf16*  nvt  = (bf16*)(W + 24 * MB);     // 8 MB new_values^T
    bf16*  okbf = (bf16*)(W + 32 * MB);     // 2 MB new_keys bf16
    bf16*  qmbf = (bf16*)(W + 34 * MB);     // 1 MB
    float* aob  = (float*)(W + 36 * MB);    // 8 MB gate pre-act
    bf16*  a13  = (bf16*)(W + 44 * MB);     // 32 MB MLP up (overlays qkvb tail)
    bf16*  a1bf = (bf16*)(W);               // 16 MB MLP silu-mul out
    bf16*  qkvb = (bf16*)(W + 64 * MB);     // 12 MB [2048][3072]
    bf16*  vtb  = (bf16*)(W + 76 * MB);     // 4 MB V^T per head
    bf16*  nbf  = (bf16*)(W + 80 * MB);     // 4 MB rmsnorm out
    bf16*  abf  = (bf16*)(W + 84 * MB);     // 4 MB attn out
    float* h1b  = (float*)(W + 88 * MB);    // 8 MB
    bf16*  catbf= (bf16*)(W + 96 * MB);     // 8 MB [2048][2048] = [h1bf | retr]
    float* ctcp = (float*)(W + 104 * MB);   // 10.5 MB [2048][1280]; later proj
    float* h2b  = (float*)(W + 115 * MB);   // 8 MB
    float* stb  = (float*)(W + 123 * MB);   // 8 KB
    bf16*  WqkvT= (bf16*)(W + 124 * MB);    // 6 MB
    bf16*  WoT  = (bf16*)(W + 130 * MB);    // 2 MB
    bf16*  WctcpT=(bf16*)(W + 132 * MB);    // 2.5 MB
    bf16*  WqrT = (bf16*)(W + 134 * MB + 512 * 1024);  // 0.5 MB
    bf16*  WgT  = (bf16*)(W + 135 * MB);    // 4 MB
    bf16*  WpjT = (bf16*)(W + 139 * MB);    // 2 MB
    bf16*  W13T = (bf16*)(W + 141 * MB);    // 16 MB
    bf16*  W2T  = (bf16*)(W + 157 * MB);    // 8 MB -> end 165 MB

    // ---- weight transpose-casts ----
    tcast<float><<<dim3(32, 32, 1), 256, 0, stream>>>(Wq,  WqkvT,                1024, 1024, 0, 0);
    tcast<float><<<dim3(32, 32, 1), 256, 0, stream>>>(Wk,  WqkvT + 1024 * 1024,  1024, 1024, 0, 0);
    tcast<float><<<dim3(32, 32, 1), 256, 0, stream>>>(Wv,  WqkvT + 2048 * 1024,  1024, 1024, 0, 0);
    tcast<float><<<dim3(32, 32, 1), 256, 0, stream>>>(Wo,  WoT,                  1024, 1024, 0, 0);
    tcast<float><<<dim3(32, 32, 1), 256, 0, stream>>>(Wct, WctcpT,               1024, 1024, 0, 0);
    tcast<float><<<dim3(8, 32, 1), 256, 0, stream>>>(Wcp,  WctcpT + 1024 * 1024, 256, 1024, 0, 0);
    tcast<float><<<dim3(8, 32, 1), 256, 0, stream>>>(Wqr,  WqrT,                 256, 1024, 0, 0);
    tcast<float><<<dim3(32, 64, 1), 256, 0, stream>>>(Wg,  WgT,                  1024, 2048, 0, 0);
    tcast<float><<<dim3(32, 32, 1), 256, 0, stream>>>(Wpj, WpjT,                 1024, 1024, 0, 0);
    tcast<float><<<dim3(128, 32, 1), 256, 0, stream>>>(W1, W13T,                 4096, 1024, 0, 0);
    tcast<float><<<dim3(128, 32, 1), 256, 0, stream>>>(W3, W13T + 4096 * 1024,   4096, 1024, 0, 0);
    tcast<float><<<dim3(32, 128, 1), 256, 0, stream>>>(W2, W2T,                  1024, 4096, 0, 0);

    // ---- 1. n = rmsnorm(h0); qkv = n @ [Wq|Wk|Wv]; RoPE; V^T ----
    rmsnorm_bf<<<NTOK, 256, 0, stream>>>(h0, n1w, nbf);
    mgemm<64, 128, 0, true><<<dim3(24, 32, 1), 256, 0, stream>>>(
        nbf, WqkvT, nullptr, qkvb, 1024, 1024, 1024, 3072, 0, 0, 0);
    rope_kernel<<<(B_ * S_ * H_ * 32) / 256, 256, 0, stream>>>(qkvb, cosp, sinp);
    for (int b = 0; b < B_; ++b)
        tcast<bf16><<<dim3(2, 32, 16), 256, 0, stream>>>(
            qkvb + (size_t)b * S_ * 3072 + 2048, vtb + (size_t)b * 16 * 65536,
            3072, 1024, 64, 65536);

    // ---- 2. causal attention (both batches' scores live) ----
    for (int b = 0; b < B_; ++b) {
        const bf16* qbase = qkvb + (size_t)b * S_ * 3072;
        mgemm<128, 128, 1, true><<<dim3(8, 8, 16), 256, 0, stream>>>(
            qbase, qbase + 1024, nullptr, sbf + (size_t)b * 16 * 1024 * 1024,
            64, 3072, 3072, 1024, 64, 64, 1024 * 1024);
    }
    attn_softmax<<<B_ * 16 * 1024, 256, 0, stream>>>(sbf);
    for (int b = 0; b < B_; ++b)
        mgemm<64, 64, 2, true><<<dim3(1, 16, 16), 256, 0, stream>>>(
            sbf + (size_t)b * 16 * 1024 * 1024, vtb + (size_t)b * 16 * 65536, nullptr,
            abf + (size_t)b * S_ * 1024,
            1024, 1024, 1024, 1024, 1024 * 1024, 65536, 64);

    // ---- 3. h1 = h0 + attn @ Wo ----
    mgemm<64, 64, 0, false><<<dim3(16, 32, 1), 256, 0, stream>>>(
        abf, WoT, h0, h1b, 1024, 1024, 1024, 1024, 0, 0, 0);
    cast_h1_kernel<<<(NTOK * D_) / 1024, 256, 0, stream>>>(h1b, catbf);
    strength_kernel<<<NTOK, 64, 0, stream>>>(h1b, Wst, stb);

    // ---- 4. content|compressed; memory scatter ----
    mgemm<64, 64, 0, false><<<dim3(20, 32, 1), 256, 0, stream>>>(
        catbf, WctcpT, nullptr, ctcp, 1024, 2048, 1024, 1280, 0, 0, 0);
    hipMemcpyAsync(out_k, memk, (size_t)B_ * M_ * DC_ * sizeof(float), hipMemcpyDeviceToDevice, stream);
    hipMemcpyAsync(out_v, memv, (size_t)B_ * M_ * D_ * sizeof(float), hipMemcpyDeviceToDevice, stream);
    scatter_keys_kernel<<<(B_ * S_ * DC_) / 1024, 256, 0, stream>>>(ctcp, stb, memk, pos, out_k);
    scatter_vals_kernel<<<(B_ * S_ * D_) / 1024, 256, 0, stream>>>(ctcp, stb, memv, pos, out_v);

    // ---- 5. memory attention ----
    rmsnorm_bf<<<NTOK, 256, 0, stream>>>(h1b, nmw, nbf);
    mgemm<64, 64, 0, true><<<dim3(4, 32, 1), 256, 0, stream>>>(
        nbf, WqrT, nullptr, qmbf, 1024, 1024, 1024, 256, 0, 0, 0);
    cast_flat_kernel<<<(B_ * M_ * DC_) / 1024, 256, 0, stream>>>(out_k, okbf);
    mgemm<64, 128, 0, false><<<dim3(16, 16, 2), 256, 0, stream>>>(
        qmbf, okbf, nullptr, msb, 256, 256, 256, 2048,
        (long long)S_ * 256, (long long)M_ * 256, (long long)S_ * 2048);
    mem_softmax<<<NTOK, 256, 0, stream>>>(msb, matt);
    tcast<float><<<dim3(32, 64, 2), 256, 0, stream>>>(
        out_v, nvt, 1024, 2048, (long long)M_ * 1024, (long long)1024 * 2048);
    mgemm<64, 128, 0, true><<<dim3(8, 16, 2), 256, 0, stream>>>(
        matt, nvt, nullptr, catbf + 1024, 2048, 2048, 2048, 2048,
        (long long)S_ * 2048, (long long)1024 * 2048, (long long)S_ * 2048);

    // ---- 6. gate + proj + combine ----
    mgemm<64, 64, 0, false><<<dim3(16, 32, 1), 256, 0, stream>>>(
        catbf, WgT, nullptr, aob, 2048, 2048, 2048, 1024, 0, 0, 0);
    mgemm<64, 64, 0, false><<<dim3(16, 32, 1), 256, 0, stream>>>(
        catbf + 1024, WpjT, nullptr, ctcp, 1024, 2048, 1024, 1024, 0, 0, 0);
    gatecomb_kernel<<<(NTOK * D_) / 1024, 256, 0, stream>>>(h1b, aob, ctcp, h2b);

    // ---- 7. MLP ----
    rmsnorm_bf<<<NTOK, 256, 0, stream>>>(h2b, n2w, nbf);
    mgemm<128, 128, 0, true><<<dim3(64, 16, 1), 256, 0, stream>>>(
        nbf, W13T, nullptr, a13, 1024, 1024, 1024, 8192, 0, 0, 0);
    silumul_kernel<<<(NTOK * F_) / 1024, 256, 0, stream>>>(a13, a1bf);
    mgemm<64, 64, 0, false><<<dim3(16, 32, 1), 256, 0, stream>>>(
        a1bf, W2T, h2b, out_h, 4096, 4096, 4096, 1024, 0, 0, 0);
}

// Round 5
// 335.476 us; speedup vs baseline: 7.3063x; 1.1800x over previous
//
#include <hip/hip_runtime.h>
#include <hip/hip_bf16.h>
#include <math.h>

typedef __bf16 bf16;
typedef __attribute__((ext_vector_type(8))) __bf16 bf16x8;
typedef __attribute__((ext_vector_type(4))) __bf16 bf16x4;
typedef __attribute__((ext_vector_type(4))) float f32x4;

#define B_ 2
#define S_ 1024
#define D_ 1024
#define H_ 16
#define HD_ 64
#define F_ 4096
#define M_ 2048
#define DC_ 256
#define NTOK (B_*S_)

__device__ __forceinline__ void gload16(const void* g, void* l) {
    __builtin_amdgcn_global_load_lds(
        (__attribute__((address_space(1))) void*)(void*)(g),
        (__attribute__((address_space(3))) void*)(l), 16, 0, 0);
}

template<int N> __device__ __forceinline__ void wait_vm() {
    if constexpr (N == 0)      asm volatile("s_waitcnt vmcnt(0)" ::: "memory");
    else if constexpr (N == 2) asm volatile("s_waitcnt vmcnt(2)" ::: "memory");
    else if constexpr (N == 4) asm volatile("s_waitcnt vmcnt(4)" ::: "memory");
    else if constexpr (N == 6) asm volatile("s_waitcnt vmcnt(6)" ::: "memory");
    else                       asm volatile("s_waitcnt vmcnt(8)" ::: "memory");
}
__device__ __forceinline__ void wait_lgkm0() {
    asm volatile("s_waitcnt lgkmcnt(0)" ::: "memory");
}

// ============ MFMA GEMM: C[M,N] = A[M,K] @ Bt[N,K]^T (+resid) ============
// BK=64, depth-2 counted-vmcnt pipeline. XOR-swizzled LDS. XCD chunking over
// 8-row bands walked column-major => per-XCD working set = 8 A-panels +
// (chunk/8) B-panels (L2-resident). REQUIRES gridDim.y % 8 == 0.
template<int BM, int BN, bool OUTBF>
__global__ __launch_bounds__(256) void mgemm(
    const bf16* __restrict__ A, const bf16* __restrict__ Bt,
    const float* __restrict__ resid, void* __restrict__ Cout,
    int K, int lda, int ldb, int ldc,
    long long sA, long long sB, long long sC)
{
    constexpr int WN   = (BM == 128) ? 2 : 4;
    constexpr int WCOL = BN / WN;
    constexpr int FN   = WCOL / 16;
    constexpr int LA = BM * 64, LB = BN * 64;
    constexpr int LPS = BM / 32 + BN / 32;
    __shared__ bf16 lds[2 * (LA + LB)];
    const int z = blockIdx.z;
    A  += (size_t)z * sA;
    Bt += (size_t)z * sB;
    const int gx = gridDim.x;
    const int nwg = gx * gridDim.y;
    const int flat = blockIdx.y * gx + blockIdx.x;
    const int q8 = nwg >> 3, r8 = nwg & 7;
    const int xcd = flat & 7, lid = flat >> 3;
    const int swz = (xcd < r8 ? xcd * (q8 + 1) : r8 * (q8 + 1) + (xcd - r8) * q8) + lid;
    // 8-row bands, column-major walk within band
    const int band = swz / (8 * gx);
    const int rem  = swz % (8 * gx);
    const int row0 = (band * 8 + (rem & 7)) * BM;
    const int col0 = (rem >> 3) * BN;
    const int tid = threadIdx.x, wid = tid >> 6, lane = tid & 63;
    const int wr = wid / WN, wc = wid % WN;
    const int srow = lane >> 3;
    const int ssub = (lane & 7) ^ (srow & 7);

    f32x4 acc[4][FN];
    #pragma unroll
    for (int m = 0; m < 4; ++m)
        #pragma unroll
        for (int n = 0; n < FN; ++n) acc[m][n] = (f32x4){0.f, 0.f, 0.f, 0.f};

    auto STAGE = [&](int buf, int k0) {
        bf16* Ab = lds + buf * (LA + LB);
        bf16* Bb = Ab + LA;
        #pragma unroll
        for (int i = 0; i < BM / 32; ++i) {
            int c = wid * (BM / 32) + i;
            gload16(A + (size_t)(row0 + c * 8 + srow) * lda + k0 + ssub * 8, Ab + c * 512);
        }
        #pragma unroll
        for (int i = 0; i < BN / 32; ++i) {
            int c = wid * (BN / 32) + i;
            gload16(Bt + (size_t)(col0 + c * 8 + srow) * ldb + k0 + ssub * 8, Bb + c * 512);
        }
    };

    const int nt = K >> 6;
    STAGE(0, 0);
    if (nt > 1) STAGE(1, 64);
    for (int t = 0; t < nt; ++t) {
        if (t < nt - 1) wait_vm<LPS>();
        else            wait_vm<0>();
        __builtin_amdgcn_sched_barrier(0);
        __builtin_amdgcn_s_barrier();
        __builtin_amdgcn_sched_barrier(0);
        const bf16* Ab = lds + (t & 1) * (LA + LB);
        const bf16* Bb = Ab + LA;
        const int ar = wr * 64 + (lane & 15);
        const int br = wc * WCOL + (lane & 15);
        #pragma unroll
        for (int ksel = 0; ksel < 2; ++ksel) {
            const int ps = ((ksel << 2) + (lane >> 4)) ^ (lane & 7);
            bf16x8 af[4], bfr[FN];
            #pragma unroll
            for (int m = 0; m < 4; ++m)
                af[m] = *(const bf16x8*)(Ab + (ar + m * 16) * 64 + ps * 8);
            #pragma unroll
            for (int n = 0; n < FN; ++n)
                bfr[n] = *(const bf16x8*)(Bb + (br + n * 16) * 64 + ps * 8);
            #pragma unroll
            for (int m = 0; m < 4; ++m)
                #pragma unroll
                for (int n = 0; n < FN; ++n)
                    acc[m][n] = __builtin_amdgcn_mfma_f32_16x16x32_bf16(af[m], bfr[n], acc[m][n], 0, 0, 0);
        }
        wait_lgkm0();
        __builtin_amdgcn_sched_barrier(0);
        __builtin_amdgcn_s_barrier();
        __builtin_amdgcn_sched_barrier(0);
        if (t + 2 < nt) STAGE(t & 1, (t + 2) << 6);
    }
    const int crow = row0 + wr * 64 + ((lane >> 4) << 2);
    const int ccol = col0 + wc * WCOL + (lane & 15);
    #pragma unroll
    for (int m = 0; m < 4; ++m)
        #pragma unroll
        for (int n = 0; n < FN; ++n)
            #pragma unroll
            for (int r = 0; r < 4; ++r) {
                size_t idx = (size_t)(crow + m * 16 + r) * ldc + ccol + n * 16;
                float v = acc[m][n][r];
                if (resid) v += resid[idx];
                if (OUTBF) ((bf16*)Cout)[(size_t)z * sC + idx] = (bf16)v;
                else       ((float*)Cout)[(size_t)z * sC + idx] = v;
            }
}

// ============ Fused causal flash attention ============
// Grid (S/64, H, B), 256 thr. QBLK=64: each wave owns 16 q-rows.
// qkv: [tok][3072] (q scaled 1/8, rope'd). vt: [b*H+h][64 d][1024 s].
// o: [tok][1024] head-major. Online softmax in registers (C/D layout:
// col=lane&15, row=(lane>>4)*4+r). P transposed via per-wave swizzled LDS.
__global__ __launch_bounds__(256) void flash_attn(
    const bf16* __restrict__ qkv, const bf16* __restrict__ vt,
    bf16* __restrict__ o)
{
    __shared__ bf16 qlds[64 * 64];
    __shared__ bf16 klds[2][64 * 64];
    __shared__ bf16 vlds[2][64 * 64];
    __shared__ bf16 plds[4][16 * 64];
    const int qt = blockIdx.x, hh = blockIdx.y, b = blockIdx.z;
    const int qb0 = qt * 64;
    const int tid = threadIdx.x, wid = tid >> 6, lane = tid & 63;
    const bf16* qg = qkv + (size_t)b * S_ * 3072 + hh * 64;
    const bf16* kg = qg + 1024;
    const bf16* vg = vt + (size_t)(b * H_ + hh) * 64 * 1024;
    const int srow = lane >> 3;
    const int ssub = (lane & 7) ^ (srow & 7);

    // stage Q once (8 chunks of 8 rows; wave w does 2)
    #pragma unroll
    for (int i = 0; i < 2; ++i) {
        int c = wid * 2 + i;
        gload16(qg + (size_t)(qb0 + c * 8 + srow) * 3072 + ssub * 8, qlds + c * 512);
    }
    auto STAGE = [&](int buf, int kb) {
        #pragma unroll
        for (int i = 0; i < 2; ++i) {
            int c = wid * 2 + i;
            gload16(kg + (size_t)(kb + c * 8 + srow) * 3072 + ssub * 8, klds[buf] + c * 512);
            gload16(vg + (size_t)(c * 8 + srow) * 1024 + kb + ssub * 8, vlds[buf] + c * 512);
        }
    };

    const int nt = qt + 1;
    STAGE(0, 0);
    if (nt > 1) STAGE(1, 64);

    f32x4 oacc[4];
    #pragma unroll
    for (int n = 0; n < 4; ++n) oacc[n] = (f32x4){0.f, 0.f, 0.f, 0.f};
    float mrow[4] = {-1e30f, -1e30f, -1e30f, -1e30f};
    float lrow[4] = {0.f, 0.f, 0.f, 0.f};
    bf16x8 qf[2];
    bf16* pw = plds[wid];
    const int qlr = (lane >> 4) * 4;   // base row-in-16 this lane accumulates

    for (int t = 0; t < nt; ++t) {
        if (t < nt - 1) wait_vm<4>();
        else            wait_vm<0>();
        __builtin_amdgcn_sched_barrier(0);
        __builtin_amdgcn_s_barrier();
        __builtin_amdgcn_sched_barrier(0);
        if (t == 0) {
            const int ar = wid * 16 + (lane & 15);
            #pragma unroll
            for (int ksel = 0; ksel < 2; ++ksel) {
                const int ps = ((ksel << 2) + (lane >> 4)) ^ (lane & 7);
                qf[ksel] = *(const bf16x8*)(qlds + ar * 64 + ps * 8);
            }
        }
        const bf16* Kb = klds[t & 1];
        const bf16* Vb = vlds[t & 1];
        // S = Q @ K^T  (64q x 64k per block; this wave: 16q x 64k)
        f32x4 sacc[4];
        #pragma unroll
        for (int n = 0; n < 4; ++n) sacc[n] = (f32x4){0.f, 0.f, 0.f, 0.f};
        #pragma unroll
        for (int ksel = 0; ksel < 2; ++ksel) {
            const int ps = ((ksel << 2) + (lane >> 4)) ^ (lane & 7);
            #pragma unroll
            for (int n = 0; n < 4; ++n) {
                bf16x8 kf = *(const bf16x8*)(Kb + (n * 16 + (lane & 15)) * 64 + ps * 8);
                sacc[n] = __builtin_amdgcn_mfma_f32_16x16x32_bf16(qf[ksel], kf, sacc[n], 0, 0, 0);
            }
        }
        // causal mask on diagonal block
        if (t == nt - 1) {
            const int qrow = qb0 + wid * 16 + qlr;
            const int kcol = t * 64 + (lane & 15);
            #pragma unroll
            for (int n = 0; n < 4; ++n)
                #pragma unroll
                for (int r = 0; r < 4; ++r)
                    if (kcol + n * 16 > qrow + r) sacc[n][r] = -1e30f;
        }
        // online softmax (row = q, lane-local across lane&15 groups)
        #pragma unroll
        for (int r = 0; r < 4; ++r) {
            float mx = fmaxf(fmaxf(sacc[0][r], sacc[1][r]), fmaxf(sacc[2][r], sacc[3][r]));
            #pragma unroll
            for (int off = 8; off > 0; off >>= 1) mx = fmaxf(mx, __shfl_xor(mx, off));
            float mnew = fmaxf(mrow[r], mx);
            float scale = __expf(mrow[r] - mnew);
            float rs = 0.f;
            #pragma unroll
            for (int n = 0; n < 4; ++n) {
                float p = __expf(sacc[n][r] - mnew);
                sacc[n][r] = p;
                rs += p;
            }
            #pragma unroll
            for (int off = 8; off > 0; off >>= 1) rs += __shfl_xor(rs, off);
            lrow[r] = lrow[r] * scale + rs;
            mrow[r] = mnew;
            #pragma unroll
            for (int n = 0; n < 4; ++n) oacc[n][r] *= scale;
        }
        // write P (16q x 64k bf16) to wave-local LDS, XOR-swizzled 16B units
        #pragma unroll
        for (int n = 0; n < 4; ++n)
            #pragma unroll
            for (int r = 0; r < 4; ++r) {
                const int qr = qlr + r;
                const int k = n * 16 + (lane & 15);
                const int su = (k >> 3) ^ (qr & 7);
                pw[qr * 64 + su * 8 + (k & 7)] = (bf16)sacc[n][r];
            }
        // O += P @ V  (A-frags from plds, B-frags from vlds rows=d)
        #pragma unroll
        for (int ksel = 0; ksel < 2; ++ksel) {
            const int ps = ((ksel << 2) + (lane >> 4)) ^ (lane & 7);
            bf16x8 pa = *(const bf16x8*)(pw + (lane & 15) * 64 + ps * 8);
            #pragma unroll
            for (int n = 0; n < 4; ++n) {
                bf16x8 vf = *(const bf16x8*)(Vb + (n * 16 + (lane & 15)) * 64 + ps * 8);
                oacc[n] = __builtin_amdgcn_mfma_f32_16x16x32_bf16(pa, vf, oacc[n], 0, 0, 0);
            }
        }
        wait_lgkm0();
        __builtin_amdgcn_sched_barrier(0);
        __builtin_amdgcn_s_barrier();
        __builtin_amdgcn_sched_barrier(0);
        if (t + 2 < nt) STAGE(t & 1, (t + 2) * 64);
    }
    // write O / l
    float inv[4];
    #pragma unroll
    for (int r = 0; r < 4; ++r) inv[r] = 1.f / lrow[r];
    #pragma unroll
    for (int n = 0; n < 4; ++n)
        #pragma unroll
        for (int r = 0; r < 4; ++r) {
            const int q = qb0 + wid * 16 + qlr + r;
            const int d = n * 16 + (lane & 15);
            o[(size_t)(b * S_ + q) * 1024 + hh * 64 + d] = (bf16)(oacc[n][r] * inv[r]);
        }
}

// ============ transpose-cast: in [R][C] (f32 or bf16) -> out bf16 [C][R] ============
template<typename TI>
__global__ __launch_bounds__(256) void tcast(
    const TI* __restrict__ in, bf16* __restrict__ out,
    int lin, int lout, long long sin, long long sout)
{
    __shared__ float t[32][33];
    in  += (size_t)blockIdx.z * sin;
    out += (size_t)blockIdx.z * sout;
    const int c0 = blockIdx.x * 32, r0 = blockIdx.y * 32;
    const int tx = threadIdx.x & 31, ty = threadIdx.x >> 5;
    #pragma unroll
    for (int j = 0; j < 4; ++j)
        t[ty + j * 8][tx] = (float)in[(size_t)(r0 + ty + j * 8) * lin + c0 + tx];
    __syncthreads();
    #pragma unroll
    for (int j = 0; j < 4; ++j)
        out[(size_t)(c0 + ty + j * 8) * lout + r0 + tx] = (bf16)t[tx][ty + j * 8];
}

// ============ RMSNorm -> bf16 out ============
__global__ __launch_bounds__(256) void rmsnorm_bf(
    const float* __restrict__ x, const float* __restrict__ w, bf16* __restrict__ out)
{
    __shared__ float red[4];
    const int row = blockIdx.x, tid = threadIdx.x;
    const float* xr = x + (size_t)row * D_;
    f32x4 v = *(const f32x4*)(xr + tid * 4);
    float ss = v.x * v.x + v.y * v.y + v.z * v.z + v.w * v.w;
    #pragma unroll
    for (int off = 32; off > 0; off >>= 1) ss += __shfl_xor(ss, off);
    if ((tid & 63) == 0) red[tid >> 6] = ss;
    __syncthreads();
    float scn = rsqrtf((red[0] + red[1] + red[2] + red[3]) * (1.f / D_) + 1e-6f);
    f32x4 wv = *(const f32x4*)(w + tid * 4);
    bf16x4 o;
    o[0] = (bf16)(v.x * scn * wv.x); o[1] = (bf16)(v.y * scn * wv.y);
    o[2] = (bf16)(v.z * scn * wv.z); o[3] = (bf16)(v.w * scn * wv.w);
    *(bf16x4*)(out + (size_t)row * D_ + tid * 4) = o;
}

// ============ RoPE in-place on bf16 qkv buffer [tok][3072]; q scaled 1/8 ============
__global__ void rope_kernel(bf16* __restrict__ qkv,
                            const float* __restrict__ cosp, const float* __restrict__ sinp)
{
    int idx = blockIdx.x * 256 + threadIdx.x;   // B*S*H*32
    int p = idx & 31, hh = (idx >> 5) & 15, s = (idx >> 9) & 1023, b = idx >> 19;
    size_t base = ((size_t)(b * S_ + s)) * 3072 + hh * 64;
    float c1 = cosp[s * 64 + p],      s1 = sinp[s * 64 + p];
    float c2 = cosp[s * 64 + p + 32], s2 = sinp[s * 64 + p + 32];
    float q1 = (float)qkv[base + p], q2 = (float)qkv[base + p + 32];
    qkv[base + p]      = (bf16)((q1 * c1 - q2 * s1) * 0.125f);
    qkv[base + p + 32] = (bf16)((q2 * c2 + q1 * s2) * 0.125f);
    size_t kb = base + 1024;
    float k1 = (float)qkv[kb + p], k2 = (float)qkv[kb + p + 32];
    qkv[kb + p]      = (bf16)(k1 * c1 - k2 * s1);
    qkv[kb + p + 32] = (bf16)(k2 * c2 + k1 * s2);
}

// ============ memory softmax: f32 [row][2048] -> bf16 probs, scale 1/16 ============
__global__ __launch_bounds__(256) void mem_softmax(
    const float* __restrict__ ms, bf16* __restrict__ out)
{
    __shared__ float red[4];
    const int row = blockIdx.x, tid = threadIdx.x;
    const float* r = ms + (size_t)row * 2048;
    f32x4 a = *(const f32x4*)(r + tid * 8);
    f32x4 b = *(const f32x4*)(r + tid * 8 + 4);
    float xs[8] = {a.x, a.y, a.z, a.w, b.x, b.y, b.z, b.w};
    float mx = -1e30f;
    #pragma unroll
    for (int i = 0; i < 8; ++i) mx = fmaxf(mx, xs[i]);
    #pragma unroll
    for (int off = 32; off > 0; off >>= 1) mx = fmaxf(mx, __shfl_xor(mx, off));
    if ((tid & 63) == 0) red[tid >> 6] = mx;
    __syncthreads();
    mx = fmaxf(fmaxf(red[0], red[1]), fmaxf(red[2], red[3]));
    __syncthreads();
    float sum = 0.f;
    #pragma unroll
    for (int i = 0; i < 8; ++i) { xs[i] = __expf((xs[i] - mx) * 0.0625f); sum += xs[i]; }
    #pragma unroll
    for (int off = 32; off > 0; off >>= 1) sum += __shfl_xor(sum, off);
    if ((tid & 63) == 0) red[tid >> 6] = sum;
    __syncthreads();
    float inv = 1.f / (red[0] + red[1] + red[2] + red[3]);
    bf16x8 o;
    #pragma unroll
    for (int i = 0; i < 8; ++i) o[i] = (bf16)(xs[i] * inv);
    *(bf16x8*)(out + (size_t)row * 2048 + tid * 8) = o;
}

// ============ small elementwise kernels ============
__global__ void strength_kernel(const float* __restrict__ h, const float* __restrict__ ws,
                                float* __restrict__ st)
{
    const int row = blockIdx.x, lane = threadIdx.x;
    const float* hr = h + (size_t)row * D_;
    float s = 0.f;
    #pragma unroll
    for (int it = 0; it < 4; ++it) {
        f32x4 hv = *(const f32x4*)(hr + it * 256 + lane * 4);
        f32x4 wv = *(const f32x4*)(ws + it * 256 + lane * 4);
        s += hv.x * wv.x + hv.y * wv.y + hv.z * wv.z + hv.w * wv.w;
    }
    #pragma unroll
    for (int off = 32; off > 0; off >>= 1) s += __shfl_xor(s, off);
    if (lane == 0) st[row] = 1.f / (1.f + expf(-s));
}

__global__ void scatter_keys_kernel(const float* __restrict__ ctcp, const float* __restrict__ st,
                                    const float* __restrict__ memk, const int* __restrict__ pos,
                                    float* __restrict__ outk)
{
    int idx = blockIdx.x * 256 + threadIdx.x;    // B*S*DC/4
    int c = (idx & 63) * 4;
    int s = (idx >> 6) & (S_ - 1);
    int b = idx >> 16;
    int row = (pos[0] + s) % M_;
    float t = st[b * S_ + s];
    size_t mi = ((size_t)b * M_ + row) * DC_ + c;
    f32x4 cv = *(const f32x4*)(ctcp + ((size_t)b * S_ + s) * 1280 + 1024 + c);
    f32x4 mv = *(const f32x4*)(memk + mi);
    f32x4 o = {t * cv.x + (1.f - t) * mv.x, t * cv.y + (1.f - t) * mv.y,
               t * cv.z + (1.f - t) * mv.z, t * cv.w + (1.f - t) * mv.w};
    *(f32x4*)(outk + mi) = o;
}

__global__ void scatter_vals_kernel(const float* __restrict__ ctcp, const float* __restrict__ st,
                                    const float* __restrict__ memv, const int* __restrict__ pos,
                                    float* __restrict__ outv)
{
    int idx = blockIdx.x * 256 + threadIdx.x;    // B*S*D/4
    int c = (idx & 255) * 4;
    int s = (idx >> 8) & (S_ - 1);
    int b = idx >> 18;
    int row = (pos[0] + s) % M_;
    float t = st[b * S_ + s];
    size_t mi = ((size_t)b * M_ + row) * D_ + c;
    f32x4 cv = *(const f32x4*)(ctcp + ((size_t)b * S_ + s) * 1280 + c);
    f32x4 mv = *(const f32x4*)(memv + mi);
    f32x4 o = {t * cv.x + (1.f - t) * mv.x, t * cv.y + (1.f - t) * mv.y,
               t * cv.z + (1.f - t) * mv.z, t * cv.w + (1.f - t) * mv.w};
    *(f32x4*)(outv + mi) = o;
}

__global__ void cast_h1_kernel(const float* __restrict__ h1, bf16* __restrict__ cat)
{
    int i = blockIdx.x * 256 + threadIdx.x;      // NTOK*D/4
    int row = i >> 8, c = (i & 255) * 4;
    f32x4 v = *(const f32x4*)(h1 + (size_t)row * 1024 + c);
    bf16x4 o = {(bf16)v.x, (bf16)v.y, (bf16)v.z, (bf16)v.w};
    *(bf16x4*)(cat + (size_t)row * 2048 + c) = o;
}

__global__ void cast_flat_kernel(const float* __restrict__ in, bf16* __restrict__ out)
{
    int i = blockIdx.x * 256 + threadIdx.x;
    f32x4 v = *(const f32x4*)(in + (size_t)i * 4);
    bf16x4 o = {(bf16)v.x, (bf16)v.y, (bf16)v.z, (bf16)v.w};
    *(bf16x4*)(out + (size_t)i * 4) = o;
}

__global__ void gatecomb_kernel(const float* __restrict__ h1, const float* __restrict__ g,
                                const float* __restrict__ p, float* __restrict__ h2)
{
    int i = blockIdx.x * 256 + threadIdx.x;
    f32x4 hv = *(const f32x4*)(h1 + (size_t)i * 4);
    f32x4 gv = *(const f32x4*)(g + (size_t)i * 4);
    f32x4 pv = *(const f32x4*)(p + (size_t)i * 4);
    f32x4 o;
    o.x = hv.x + pv.x / (1.f + expf(-gv.x));
    o.y = hv.y + pv.y / (1.f + expf(-gv.y));
    o.z = hv.z + pv.z / (1.f + expf(-gv.z));
    o.w = hv.w + pv.w / (1.f + expf(-gv.w));
    *(f32x4*)(h2 + (size_t)i * 4) = o;
}

__global__ void silumul_kernel(const bf16* __restrict__ a13, bf16* __restrict__ a1bf)
{
    int i = blockIdx.x * 256 + threadIdx.x;      // NTOK*F/4
    int row = i >> 10, c = (i & 1023) * 4;
    bf16x4 xv = *(const bf16x4*)(a13 + (size_t)row * 8192 + c);
    bf16x4 yv = *(const bf16x4*)(a13 + (size_t)row * 8192 + 4096 + c);
    bf16x4 o;
    #pragma unroll
    for (int j = 0; j < 4; ++j) {
        float x = (float)xv[j];
        o[j] = (bf16)((x / (1.f + expf(-x))) * (float)yv[j]);
    }
    *(bf16x4*)(a1bf + (size_t)row * 4096 + c) = o;
}

extern "C" void kernel_launch(void* const* d_in, const int* in_sizes, int n_in,
                              void* d_out, int out_size, void* d_ws, size_t ws_size,
                              hipStream_t stream)
{
    const float* h0   = (const float*)d_in[0];
    const float* memk = (const float*)d_in[1];
    const float* memv = (const float*)d_in[2];
    const float* cosp = (const float*)d_in[3];
    const float* sinp = (const float*)d_in[4];
    const float* n1w  = (const float*)d_in[5];
    const float* n2w  = (const float*)d_in[6];
    const float* nmw  = (const float*)d_in[7];
    const float* Wq   = (const float*)d_in[8];
    const float* Wk   = (const float*)d_in[9];
    const float* Wv   = (const float*)d_in[10];
    const float* Wo   = (const float*)d_in[11];
    const float* Wct  = (const float*)d_in[12];
    const float* Wcp  = (const float*)d_in[13];
    const float* Wst  = (const float*)d_in[14];
    const float* Wqr  = (const float*)d_in[15];
    const float* Wg   = (const float*)d_in[16];
    const float* Wpj  = (const float*)d_in[17];
    const float* W1   = (const float*)d_in[18];
    const float* W3   = (const float*)d_in[19];
    const float* W2   = (const float*)d_in[20];
    const int*   pos  = (const int*)d_in[21];

    float* out_h = (float*)d_out;
    float* out_k = out_h + (size_t)NTOK * D_;
    float* out_v = out_k + (size_t)B_ * M_ * DC_;

    char* W = (char*)d_ws;
    const size_t MB = 1u << 20;
    bf16*  qkvb = (bf16*)(W);               // 0..12 MB [2048][3072]
    bf16*  vtb  = (bf16*)(W + 12 * MB);     // 12..16 V^T [b*h][64][1024]
    bf16*  nbf  = (bf16*)(W + 16 * MB);     // 16..20 rmsnorm out
    bf16*  abf  = (bf16*)(W + 20 * MB);     // 20..24 attn out
    float* h1b  = (float*)(W + 24 * MB);    // 24..32
    bf16*  catbf= (bf16*)(W + 32 * MB);     // 32..40 [2048][2048] = [h1bf | retr]
    float* ctcp = (float*)(W + 40 * MB);    // 40..50.5 [2048][1280]; later proj
    float* stb  = (float*)(W + 51 * MB);    // 8 KB
    float* msb  = (float*)(W + 52 * MB);    // 52..68 mem scores f32
    bf16*  matt = (bf16*)(W + 68 * MB);     // 68..76 mem probs
    bf16*  nvt  = (bf16*)(W + 76 * MB);     // 76..84 new_values^T
    bf16*  a13  = (bf16*)(W + 52 * MB);     // 52..84 MLP up (overlays msb/matt/nvt)
    bf16*  a1bf = (bf16*)(W);               // 0..16 (overlays qkvb+vtb)
    bf16*  okbf = (bf16*)(W + 84 * MB);     // 84..86 new_keys bf16
    bf16*  qmbf = (bf16*)(W + 86 * MB);     // 86..87
    float* aob  = (float*)(W + 88 * MB);    // 88..96 gate pre-act
    float* h2b  = (float*)(W + 96 * MB);    // 96..104
    bf16*  WqkvT= (bf16*)(W + 104 * MB);    // 104..110
    bf16*  WoT  = (bf16*)(W + 110 * MB);    // 110..112
    bf16*  WctcpT=(bf16*)(W + 112 * MB);    // 112..114.5
    bf16*  WqrT = (bf16*)(W + 115 * MB);    // 115..115.5
    bf16*  WgT  = (bf16*)(W + 116 * MB);    // 116..120
    bf16*  WpjT = (bf16*)(W + 120 * MB);    // 120..122
    bf16*  W13T = (bf16*)(W + 122 * MB);    // 122..138
    bf16*  W2T  = (bf16*)(W + 138 * MB);    // 138..146

    // ---- weight transpose-casts ----
    tcast<float><<<dim3(32, 32, 1), 256, 0, stream>>>(Wq,  WqkvT,                1024, 1024, 0, 0);
    tcast<float><<<dim3(32, 32, 1), 256, 0, stream>>>(Wk,  WqkvT + 1024 * 1024,  1024, 1024, 0, 0);
    tcast<float><<<dim3(32, 32, 1), 256, 0, stream>>>(Wv,  WqkvT + 2048 * 1024,  1024, 1024, 0, 0);
    tcast<float><<<dim3(32, 32, 1), 256, 0, stream>>>(Wo,  WoT,                  1024, 1024, 0, 0);
    tcast<float><<<dim3(32, 32, 1), 256, 0, stream>>>(Wct, WctcpT,               1024, 1024, 0, 0);
    tcast<float><<<dim3(8, 32, 1), 256, 0, stream>>>(Wcp,  WctcpT + 1024 * 1024, 256, 1024, 0, 0);
    tcast<float><<<dim3(8, 32, 1), 256, 0, stream>>>(Wqr,  WqrT,                 256, 1024, 0, 0);
    tcast<float><<<dim3(32, 64, 1), 256, 0, stream>>>(Wg,  WgT,                  1024, 2048, 0, 0);
    tcast<float><<<dim3(32, 32, 1), 256, 0, stream>>>(Wpj, WpjT,                 1024, 1024, 0, 0);
    tcast<float><<<dim3(128, 32, 1), 256, 0, stream>>>(W1, W13T,                 4096, 1024, 0, 0);
    tcast<float><<<dim3(128, 32, 1), 256, 0, stream>>>(W3, W13T + 4096 * 1024,   4096, 1024, 0, 0);
    tcast<float><<<dim3(32, 128, 1), 256, 0, stream>>>(W2, W2T,                  1024, 4096, 0, 0);

    // ---- 1. n = rmsnorm(h0); qkv = n @ [Wq|Wk|Wv]; RoPE; V^T ----
    rmsnorm_bf<<<NTOK, 256, 0, stream>>>(h0, n1w, nbf);
    mgemm<64, 128, true><<<dim3(24, 32, 1), 256, 0, stream>>>(
        nbf, WqkvT, nullptr, qkvb, 1024, 1024, 1024, 3072, 0, 0, 0);
    rope_kernel<<<(B_ * S_ * H_ * 32) / 256, 256, 0, stream>>>(qkvb, cosp, sinp);
    for (int b = 0; b < B_; ++b)
        tcast<bf16><<<dim3(2, 32, 16), 256, 0, stream>>>(
            qkvb + (size_t)b * S_ * 3072 + 2048, vtb + (size_t)b * 16 * 65536,
            3072, 1024, 64, 65536);

    // ---- 2. fused causal flash attention ----
    flash_attn<<<dim3(S_ / 64, H_, B_), 256, 0, stream>>>(qkvb, vtb, abf);

    // ---- 3. h1 = h0 + attn @ Wo ----
    mgemm<64, 64, false><<<dim3(16, 32, 1), 256, 0, stream>>>(
        abf, WoT, h0, h1b, 1024, 1024, 1024, 1024, 0, 0, 0);
    cast_h1_kernel<<<(NTOK * D_) / 1024, 256, 0, stream>>>(h1b, catbf);
    strength_kernel<<<NTOK, 64, 0, stream>>>(h1b, Wst, stb);

    // ---- 4. content|compressed; memory scatter ----
    mgemm<64, 64, false><<<dim3(20, 32, 1), 256, 0, stream>>>(
        catbf, WctcpT, nullptr, ctcp, 1024, 2048, 1024, 1280, 0, 0, 0);
    hipMemcpyAsync(out_k, memk, (size_t)B_ * M_ * DC_ * sizeof(float), hipMemcpyDeviceToDevice, stream);
    hipMemcpyAsync(out_v, memv, (size_t)B_ * M_ * D_ * sizeof(float), hipMemcpyDeviceToDevice, stream);
    scatter_keys_kernel<<<(B_ * S_ * DC_) / 1024, 256, 0, stream>>>(ctcp, stb, memk, pos, out_k);
    scatter_vals_kernel<<<(B_ * S_ * D_) / 1024, 256, 0, stream>>>(ctcp, stb, memv, pos, out_v);

    // ---- 5. memory attention ----
    rmsnorm_bf<<<NTOK, 256, 0, stream>>>(h1b, nmw, nbf);
    mgemm<64, 64, true><<<dim3(4, 32, 1), 256, 0, stream>>>(
        nbf, WqrT, nullptr, qmbf, 1024, 1024, 1024, 256, 0, 0, 0);
    cast_flat_kernel<<<(B_ * M_ * DC_) / 1024, 256, 0, stream>>>(out_k, okbf);
    mgemm<64, 128, false><<<dim3(16, 16, 2), 256, 0, stream>>>(
        qmbf, okbf, nullptr, msb, 256, 256, 256, 2048,
        (long long)S_ * 256, (long long)M_ * 256, (long long)S_ * 2048);
    mem_softmax<<<NTOK, 256, 0, stream>>>(msb, matt);
    tcast<float><<<dim3(32, 64, 2), 256, 0, stream>>>(
        out_v, nvt, 1024, 2048, (long long)M_ * 1024, (long long)1024 * 2048);
    mgemm<64, 128, true><<<dim3(8, 16, 2), 256, 0, stream>>>(
        matt, nvt, nullptr, catbf + 1024, 2048, 2048, 2048, 2048,
        (long long)S_ * 2048, (long long)1024 * 2048, (long long)S_ * 2048);

    // ---- 6. gate + proj + combine ----
    mgemm<64, 64, false><<<dim3(16, 32, 1), 256, 0, stream>>>(
        catbf, WgT, nullptr, aob, 2048, 2048, 2048, 1024, 0, 0, 0);
    mgemm<64, 64, false><<<dim3(16, 32, 1), 256, 0, stream>>>(
        catbf + 1024, WpjT, nullptr, ctcp, 1024, 2048, 1024, 1024, 0, 0, 0);
    gatecomb_kernel<<<(NTOK * D_) / 1024, 256, 0, stream>>>(h1b, aob, ctcp, h2b);

    // ---- 7. MLP ----
    rmsnorm_bf<<<NTOK, 256, 0, stream>>>(h2b, n2w, nbf);
    mgemm<128, 128, true><<<dim3(64, 16, 1), 256, 0, stream>>>(
        nbf, W13T, nullptr, a13, 1024, 1024, 1024, 8192, 0, 0, 0);
    silumul_kernel<<<(NTOK * F_) / 1024, 256, 0, stream>>>(a13, a1bf);
    mgemm<64, 64, false><<<dim3(16, 32, 1), 256, 0, stream>>>(
        a1bf, W2T, h2b, out_h, 4096, 4096, 4096, 1024, 0, 0, 0);
}

// Round 6
// 296.756 us; speedup vs baseline: 8.2597x; 1.1305x over previous
//
#include <hip/hip_runtime.h>
#include <hip/hip_bf16.h>
#include <math.h>

typedef __bf16 bf16;
typedef __attribute__((ext_vector_type(8))) __bf16 bf16x8;
typedef __attribute__((ext_vector_type(4))) __bf16 bf16x4;
typedef __attribute__((ext_vector_type(4))) float f32x4;

#define B_ 2
#define S_ 1024
#define D_ 1024
#define H_ 16
#define HD_ 64
#define F_ 4096
#define M_ 2048
#define DC_ 256
#define NTOK (B_*S_)

__device__ __forceinline__ void gload16(const void* g, void* l) {
    __builtin_amdgcn_global_load_lds(
        (__attribute__((address_space(1))) void*)(void*)(g),
        (__attribute__((address_space(3))) void*)(l), 16, 0, 0);
}

template<int N> __device__ __forceinline__ void wait_vm() {
    if constexpr (N == 0)      asm volatile("s_waitcnt vmcnt(0)" ::: "memory");
    else if constexpr (N == 2) asm volatile("s_waitcnt vmcnt(2)" ::: "memory");
    else if constexpr (N == 4) asm volatile("s_waitcnt vmcnt(4)" ::: "memory");
    else if constexpr (N == 6) asm volatile("s_waitcnt vmcnt(6)" ::: "memory");
    else                       asm volatile("s_waitcnt vmcnt(8)" ::: "memory");
}
__device__ __forceinline__ void wait_lgkm0() {
    asm volatile("s_waitcnt lgkmcnt(0)" ::: "memory");
}
__device__ __forceinline__ float sigm(float x) { return 1.f / (1.f + expf(-x)); }

// ============ MFMA GEMM: C[M,N] = A[M,K] @ Bt[N,K]^T (+resid) ============
// BK=64, depth-2 counted-vmcnt pipeline, XOR-swizzled LDS, XCD chunking over
// 8-row bands walked column-major (needs gridDim.y % 8 == 0).
// EPI 0: normal (resid optional; OUTBF picks bf16/f32 at Cout)
// EPI 1: Wo-fusion: Cout=f32 (+resid), aux1=bf16 buffer ld=2048 (dual write)
// EPI 2: gate-fusion: Cout f32 = aux2[idx] + sigmoid(aux1[idx]) * acc
template<int BM, int BN, bool OUTBF, int EPI>
__global__ __launch_bounds__(256) void mgemm(
    const bf16* __restrict__ A, const bf16* __restrict__ Bt,
    const float* __restrict__ resid, void* __restrict__ Cout,
    int K, int lda, int ldb, int ldc,
    long long sA, long long sB, long long sC,
    const void* __restrict__ aux1, const void* __restrict__ aux2)
{
    constexpr int WN   = (BM == 128) ? 2 : 4;
    constexpr int WCOL = BN / WN;
    constexpr int FN   = WCOL / 16;
    constexpr int LA = BM * 64, LB = BN * 64;
    constexpr int LPS = BM / 32 + BN / 32;
    __shared__ bf16 lds[2 * (LA + LB)];
    const int z = blockIdx.z;
    A  += (size_t)z * sA;
    Bt += (size_t)z * sB;
    const int gx = gridDim.x;
    const int nwg = gx * gridDim.y;
    const int flat = blockIdx.y * gx + blockIdx.x;
    const int q8 = nwg >> 3, r8 = nwg & 7;
    const int xcd = flat & 7, lid = flat >> 3;
    const int swz = (xcd < r8 ? xcd * (q8 + 1) : r8 * (q8 + 1) + (xcd - r8) * q8) + lid;
    const int band = swz / (8 * gx);
    const int rem  = swz % (8 * gx);
    const int row0 = (band * 8 + (rem & 7)) * BM;
    const int col0 = (rem >> 3) * BN;
    const int tid = threadIdx.x, wid = tid >> 6, lane = tid & 63;
    const int wr = wid / WN, wc = wid % WN;
    const int srow = lane >> 3;
    const int ssub = (lane & 7) ^ (srow & 7);

    f32x4 acc[4][FN];
    #pragma unroll
    for (int m = 0; m < 4; ++m)
        #pragma unroll
        for (int n = 0; n < FN; ++n) acc[m][n] = (f32x4){0.f, 0.f, 0.f, 0.f};

    auto STAGE = [&](int buf, int k0) {
        bf16* Ab = lds + buf * (LA + LB);
        bf16* Bb = Ab + LA;
        #pragma unroll
        for (int i = 0; i < BM / 32; ++i) {
            int c = wid * (BM / 32) + i;
            gload16(A + (size_t)(row0 + c * 8 + srow) * lda + k0 + ssub * 8, Ab + c * 512);
        }
        #pragma unroll
        for (int i = 0; i < BN / 32; ++i) {
            int c = wid * (BN / 32) + i;
            gload16(Bt + (size_t)(col0 + c * 8 + srow) * ldb + k0 + ssub * 8, Bb + c * 512);
        }
    };

    const int nt = K >> 6;
    STAGE(0, 0);
    if (nt > 1) STAGE(1, 64);
    for (int t = 0; t < nt; ++t) {
        if (t < nt - 1) wait_vm<LPS>();
        else            wait_vm<0>();
        __builtin_amdgcn_sched_barrier(0);
        __builtin_amdgcn_s_barrier();
        __builtin_amdgcn_sched_barrier(0);
        const bf16* Ab = lds + (t & 1) * (LA + LB);
        const bf16* Bb = Ab + LA;
        const int ar = wr * 64 + (lane & 15);
        const int br = wc * WCOL + (lane & 15);
        #pragma unroll
        for (int ksel = 0; ksel < 2; ++ksel) {
            const int ps = ((ksel << 2) + (lane >> 4)) ^ (lane & 7);
            bf16x8 af[4], bfr[FN];
            #pragma unroll
            for (int m = 0; m < 4; ++m)
                af[m] = *(const bf16x8*)(Ab + (ar + m * 16) * 64 + ps * 8);
            #pragma unroll
            for (int n = 0; n < FN; ++n)
                bfr[n] = *(const bf16x8*)(Bb + (br + n * 16) * 64 + ps * 8);
            #pragma unroll
            for (int m = 0; m < 4; ++m)
                #pragma unroll
                for (int n = 0; n < FN; ++n)
                    acc[m][n] = __builtin_amdgcn_mfma_f32_16x16x32_bf16(af[m], bfr[n], acc[m][n], 0, 0, 0);
        }
        wait_lgkm0();
        __builtin_amdgcn_sched_barrier(0);
        __builtin_amdgcn_s_barrier();
        __builtin_amdgcn_sched_barrier(0);
        if (t + 2 < nt) STAGE(t & 1, (t + 2) << 6);
    }
    const int crow = row0 + wr * 64 + ((lane >> 4) << 2);
    const int ccol = col0 + wc * WCOL + (lane & 15);
    #pragma unroll
    for (int m = 0; m < 4; ++m)
        #pragma unroll
        for (int n = 0; n < FN; ++n)
            #pragma unroll
            for (int r = 0; r < 4; ++r) {
                const int rr = crow + m * 16 + r, cc = ccol + n * 16;
                size_t idx = (size_t)rr * ldc + cc;
                float v = acc[m][n][r];
                if (EPI == 2) {
                    float g = sigm(((const float*)aux1)[idx]);
                    v = ((const float*)aux2)[idx] + g * v;
                    ((float*)Cout)[idx] = v;
                } else {
                    if (resid) v += resid[idx];
                    if (OUTBF) ((bf16*)Cout)[(size_t)z * sC + idx] = (bf16)v;
                    else       ((float*)Cout)[(size_t)z * sC + idx] = v;
                    if (EPI == 1)
                        ((bf16*)aux1)[(size_t)rr * 2048 + cc] = (bf16)v;
                }
            }
}

// ============ Fused MLP-up: a1 = silu(A@W1t^T) * (A@W3t^T), bf16 out ============
// BM=128, per-side BN=64 (block covers 64 cols of BOTH W1 and W3).
__global__ __launch_bounds__(256) void mgemm13(
    const bf16* __restrict__ A, const bf16* __restrict__ B1t, const bf16* __restrict__ B3t,
    bf16* __restrict__ Cout, int K, int lda, int ldb, int ldc)
{
    constexpr int LA = 128 * 64, LB = 64 * 64;
    __shared__ bf16 lds[2 * (LA + 2 * LB)];
    const int gx = gridDim.x;
    const int nwg = gx * gridDim.y;
    const int flat = blockIdx.y * gx + blockIdx.x;
    const int q8 = nwg >> 3, r8 = nwg & 7;
    const int xcd = flat & 7, lid = flat >> 3;
    const int swz = (xcd < r8 ? xcd * (q8 + 1) : r8 * (q8 + 1) + (xcd - r8) * q8) + lid;
    const int band = swz / (8 * gx);
    const int rem  = swz % (8 * gx);
    const int row0 = (band * 8 + (rem & 7)) * 128;
    const int col0 = (rem >> 3) * 64;
    const int tid = threadIdx.x, wid = tid >> 6, lane = tid & 63;
    const int wr = wid >> 1, wc = wid & 1;
    const int srow = lane >> 3;
    const int ssub = (lane & 7) ^ (srow & 7);

    f32x4 acc1[4][2], acc3[4][2];
    #pragma unroll
    for (int m = 0; m < 4; ++m)
        #pragma unroll
        for (int n = 0; n < 2; ++n) {
            acc1[m][n] = (f32x4){0.f, 0.f, 0.f, 0.f};
            acc3[m][n] = (f32x4){0.f, 0.f, 0.f, 0.f};
        }

    auto STAGE = [&](int buf, int k0) {
        bf16* Ab = lds + buf * (LA + 2 * LB);
        bf16* B1b = Ab + LA;
        bf16* B3b = B1b + LB;
        #pragma unroll
        for (int i = 0; i < 4; ++i) {
            int c = wid * 4 + i;
            gload16(A + (size_t)(row0 + c * 8 + srow) * lda + k0 + ssub * 8, Ab + c * 512);
        }
        #pragma unroll
        for (int i = 0; i < 2; ++i) {
            int c = wid * 2 + i;
            gload16(B1t + (size_t)(col0 + c * 8 + srow) * ldb + k0 + ssub * 8, B1b + c * 512);
            gload16(B3t + (size_t)(col0 + c * 8 + srow) * ldb + k0 + ssub * 8, B3b + c * 512);
        }
    };

    const int nt = K >> 6;
    STAGE(0, 0);
    if (nt > 1) STAGE(1, 64);
    for (int t = 0; t < nt; ++t) {
        if (t < nt - 1) wait_vm<8>();
        else            wait_vm<0>();
        __builtin_amdgcn_sched_barrier(0);
        __builtin_amdgcn_s_barrier();
        __builtin_amdgcn_sched_barrier(0);
        const bf16* Ab = lds + (t & 1) * (LA + 2 * LB);
        const bf16* B1b = Ab + LA;
        const bf16* B3b = B1b + LB;
        const int ar = wr * 64 + (lane & 15);
        const int br = wc * 32 + (lane & 15);
        #pragma unroll
        for (int ksel = 0; ksel < 2; ++ksel) {
            const int ps = ((ksel << 2) + (lane >> 4)) ^ (lane & 7);
            bf16x8 af[4], b1f[2], b3f[2];
            #pragma unroll
            for (int m = 0; m < 4; ++m)
                af[m] = *(const bf16x8*)(Ab + (ar + m * 16) * 64 + ps * 8);
            #pragma unroll
            for (int n = 0; n < 2; ++n) {
                b1f[n] = *(const bf16x8*)(B1b + (br + n * 16) * 64 + ps * 8);
                b3f[n] = *(const bf16x8*)(B3b + (br + n * 16) * 64 + ps * 8);
            }
            #pragma unroll
            for (int m = 0; m < 4; ++m)
                #pragma unroll
                for (int n = 0; n < 2; ++n) {
                    acc1[m][n] = __builtin_amdgcn_mfma_f32_16x16x32_bf16(af[m], b1f[n], acc1[m][n], 0, 0, 0);
                    acc3[m][n] = __builtin_amdgcn_mfma_f32_16x16x32_bf16(af[m], b3f[n], acc3[m][n], 0, 0, 0);
                }
        }
        wait_lgkm0();
        __builtin_amdgcn_sched_barrier(0);
        __builtin_amdgcn_s_barrier();
        __builtin_amdgcn_sched_barrier(0);
        if (t + 2 < nt) STAGE(t & 1, (t + 2) << 6);
    }
    const int crow = row0 + wr * 64 + ((lane >> 4) << 2);
    const int ccol = col0 + wc * 32 + (lane & 15);
    #pragma unroll
    for (int m = 0; m < 4; ++m)
        #pragma unroll
        for (int n = 0; n < 2; ++n)
            #pragma unroll
            for (int r = 0; r < 4; ++r) {
                float x = acc1[m][n][r];
                float v = (x * sigm(x)) * acc3[m][n][r];
                Cout[(size_t)(crow + m * 16 + r) * ldc + ccol + n * 16] = (bf16)v;
            }
}

// ============ Fused causal flash attention ============
__global__ __launch_bounds__(256) void flash_attn(
    const bf16* __restrict__ qkv, const bf16* __restrict__ vt,
    bf16* __restrict__ o)
{
    __shared__ bf16 qlds[64 * 64];
    __shared__ bf16 klds[2][64 * 64];
    __shared__ bf16 vlds[2][64 * 64];
    __shared__ bf16 plds[4][16 * 64];
    const int qt = blockIdx.x, hh = blockIdx.y, b = blockIdx.z;
    const int qb0 = qt * 64;
    const int tid = threadIdx.x, wid = tid >> 6, lane = tid & 63;
    const bf16* qg = qkv + (size_t)b * S_ * 3072 + hh * 64;
    const bf16* kg = qg + 1024;
    const bf16* vg = vt + (size_t)(b * H_ + hh) * 64 * 1024;
    const int srow = lane >> 3;
    const int ssub = (lane & 7) ^ (srow & 7);

    #pragma unroll
    for (int i = 0; i < 2; ++i) {
        int c = wid * 2 + i;
        gload16(qg + (size_t)(qb0 + c * 8 + srow) * 3072 + ssub * 8, qlds + c * 512);
    }
    auto STAGE = [&](int buf, int kb) {
        #pragma unroll
        for (int i = 0; i < 2; ++i) {
            int c = wid * 2 + i;
            gload16(kg + (size_t)(kb + c * 8 + srow) * 3072 + ssub * 8, klds[buf] + c * 512);
            gload16(vg + (size_t)(c * 8 + srow) * 1024 + kb + ssub * 8, vlds[buf] + c * 512);
        }
    };

    const int nt = qt + 1;
    STAGE(0, 0);
    if (nt > 1) STAGE(1, 64);

    f32x4 oacc[4];
    #pragma unroll
    for (int n = 0; n < 4; ++n) oacc[n] = (f32x4){0.f, 0.f, 0.f, 0.f};
    float mrow[4] = {-1e30f, -1e30f, -1e30f, -1e30f};
    float lrow[4] = {0.f, 0.f, 0.f, 0.f};
    bf16x8 qf[2];
    bf16* pw = plds[wid];
    const int qlr = (lane >> 4) * 4;

    for (int t = 0; t < nt; ++t) {
        if (t < nt - 1) wait_vm<4>();
        else            wait_vm<0>();
        __builtin_amdgcn_sched_barrier(0);
        __builtin_amdgcn_s_barrier();
        __builtin_amdgcn_sched_barrier(0);
        if (t == 0) {
            const int ar = wid * 16 + (lane & 15);
            #pragma unroll
            for (int ksel = 0; ksel < 2; ++ksel) {
                const int ps = ((ksel << 2) + (lane >> 4)) ^ (lane & 7);
                qf[ksel] = *(const bf16x8*)(qlds + ar * 64 + ps * 8);
            }
        }
        const bf16* Kb = klds[t & 1];
        const bf16* Vb = vlds[t & 1];
        f32x4 sacc[4];
        #pragma unroll
        for (int n = 0; n < 4; ++n) sacc[n] = (f32x4){0.f, 0.f, 0.f, 0.f};
        #pragma unroll
        for (int ksel = 0; ksel < 2; ++ksel) {
            const int ps = ((ksel << 2) + (lane >> 4)) ^ (lane & 7);
            #pragma unroll
            for (int n = 0; n < 4; ++n) {
                bf16x8 kf = *(const bf16x8*)(Kb + (n * 16 + (lane & 15)) * 64 + ps * 8);
                sacc[n] = __builtin_amdgcn_mfma_f32_16x16x32_bf16(qf[ksel], kf, sacc[n], 0, 0, 0);
            }
        }
        if (t == nt - 1) {
            const int qrow = qb0 + wid * 16 + qlr;
            const int kcol = t * 64 + (lane & 15);
            #pragma unroll
            for (int n = 0; n < 4; ++n)
                #pragma unroll
                for (int r = 0; r < 4; ++r)
                    if (kcol + n * 16 > qrow + r) sacc[n][r] = -1e30f;
        }
        #pragma unroll
        for (int r = 0; r < 4; ++r) {
            float mx = fmaxf(fmaxf(sacc[0][r], sacc[1][r]), fmaxf(sacc[2][r], sacc[3][r]));
            #pragma unroll
            for (int off = 8; off > 0; off >>= 1) mx = fmaxf(mx, __shfl_xor(mx, off));
            float mnew = fmaxf(mrow[r], mx);
            float scale = __expf(mrow[r] - mnew);
            float rs = 0.f;
            #pragma unroll
            for (int n = 0; n < 4; ++n) {
                float p = __expf(sacc[n][r] - mnew);
                sacc[n][r] = p;
                rs += p;
            }
            #pragma unroll
            for (int off = 8; off > 0; off >>= 1) rs += __shfl_xor(rs, off);
            lrow[r] = lrow[r] * scale + rs;
            mrow[r] = mnew;
            #pragma unroll
            for (int n = 0; n < 4; ++n) oacc[n][r] *= scale;
        }
        #pragma unroll
        for (int n = 0; n < 4; ++n)
            #pragma unroll
            for (int r = 0; r < 4; ++r) {
                const int qr = qlr + r;
                const int k = n * 16 + (lane & 15);
                const int su = (k >> 3) ^ (qr & 7);
                pw[qr * 64 + su * 8 + (k & 7)] = (bf16)sacc[n][r];
            }
        #pragma unroll
        for (int ksel = 0; ksel < 2; ++ksel) {
            const int ps = ((ksel << 2) + (lane >> 4)) ^ (lane & 7);
            bf16x8 pa = *(const bf16x8*)(pw + (lane & 15) * 64 + ps * 8);
            #pragma unroll
            for (int n = 0; n < 4; ++n) {
                bf16x8 vf = *(const bf16x8*)(Vb + (n * 16 + (lane & 15)) * 64 + ps * 8);
                oacc[n] = __builtin_amdgcn_mfma_f32_16x16x32_bf16(pa, vf, oacc[n], 0, 0, 0);
            }
        }
        wait_lgkm0();
        __builtin_amdgcn_sched_barrier(0);
        __builtin_amdgcn_s_barrier();
        __builtin_amdgcn_sched_barrier(0);
        if (t + 2 < nt) STAGE(t & 1, (t + 2) * 64);
    }
    float inv[4];
    #pragma unroll
    for (int r = 0; r < 4; ++r) inv[r] = 1.f / lrow[r];
    #pragma unroll
    for (int n = 0; n < 4; ++n)
        #pragma unroll
        for (int r = 0; r < 4; ++r) {
            const int q = qb0 + wid * 16 + qlr + r;
            const int d = n * 16 + (lane & 15);
            o[(size_t)(b * S_ + q) * 1024 + hh * 64 + d] = (bf16)(oacc[n][r] * inv[r]);
        }
}

// ============ transpose-cast kernels ============
template<typename TI>
__global__ __launch_bounds__(256) void tcast(
    const TI* __restrict__ in, bf16* __restrict__ out,
    int lin, int lout, long long sin, long long sout)
{
    __shared__ float t[32][33];
    in  += (size_t)blockIdx.z * sin;
    out += (size_t)blockIdx.z * sout;
    const int c0 = blockIdx.x * 32, r0 = blockIdx.y * 32;
    const int tx = threadIdx.x & 31, ty = threadIdx.x >> 5;
    #pragma unroll
    for (int j = 0; j < 4; ++j)
        t[ty + j * 8][tx] = (float)in[(size_t)(r0 + ty + j * 8) * lin + c0 + tx];
    __syncthreads();
    #pragma unroll
    for (int j = 0; j < 4; ++j)
        out[(size_t)(c0 + ty + j * 8) * lout + r0 + tx] = (bf16)t[tx][ty + j * 8];
}

struct TC6 { const float* in[6]; bf16* out[6]; };
__global__ __launch_bounds__(256) void tcast_b(TC6 p, int lin, int lout)
{
    __shared__ float t[32][33];
    const float* in = p.in[blockIdx.z];
    bf16* out = p.out[blockIdx.z];
    const int c0 = blockIdx.x * 32, r0 = blockIdx.y * 32;
    const int tx = threadIdx.x & 31, ty = threadIdx.x >> 5;
    #pragma unroll
    for (int j = 0; j < 4; ++j)
        t[ty + j * 8][tx] = in[(size_t)(r0 + ty + j * 8) * lin + c0 + tx];
    __syncthreads();
    #pragma unroll
    for (int j = 0; j < 4; ++j)
        out[(size_t)(c0 + ty + j * 8) * lout + r0 + tx] = (bf16)t[tx][ty + j * 8];
}

// ============ RMSNorm -> bf16 out ============
__global__ __launch_bounds__(256) void rmsnorm_bf(
    const float* __restrict__ x, const float* __restrict__ w, bf16* __restrict__ out)
{
    __shared__ float red[4];
    const int row = blockIdx.x, tid = threadIdx.x;
    const float* xr = x + (size_t)row * D_;
    f32x4 v = *(const f32x4*)(xr + tid * 4);
    float ss = v.x * v.x + v.y * v.y + v.z * v.z + v.w * v.w;
    #pragma unroll
    for (int off = 32; off > 0; off >>= 1) ss += __shfl_xor(ss, off);
    if ((tid & 63) == 0) red[tid >> 6] = ss;
    __syncthreads();
    float scn = rsqrtf((red[0] + red[1] + red[2] + red[3]) * (1.f / D_) + 1e-6f);
    f32x4 wv = *(const f32x4*)(w + tid * 4);
    bf16x4 o;
    o[0] = (bf16)(v.x * scn * wv.x); o[1] = (bf16)(v.y * scn * wv.y);
    o[2] = (bf16)(v.z * scn * wv.z); o[3] = (bf16)(v.w * scn * wv.w);
    *(bf16x4*)(out + (size_t)row * D_ + tid * 4) = o;
}

// ============ RoPE in-place on bf16 qkv [tok][3072]; q scaled 1/8 ============
__global__ void rope_kernel(bf16* __restrict__ qkv,
                            const float* __restrict__ cosp, const float* __restrict__ sinp)
{
    int idx = blockIdx.x * 256 + threadIdx.x;
    int p = idx & 31, hh = (idx >> 5) & 15, s = (idx >> 9) & 1023, b = idx >> 19;
    size_t base = ((size_t)(b * S_ + s)) * 3072 + hh * 64;
    float c1 = cosp[s * 64 + p],      s1 = sinp[s * 64 + p];
    float c2 = cosp[s * 64 + p + 32], s2 = sinp[s * 64 + p + 32];
    float q1 = (float)qkv[base + p], q2 = (float)qkv[base + p + 32];
    qkv[base + p]      = (bf16)((q1 * c1 - q2 * s1) * 0.125f);
    qkv[base + p + 32] = (bf16)((q2 * c2 + q1 * s2) * 0.125f);
    size_t kb = base + 1024;
    float k1 = (float)qkv[kb + p], k2 = (float)qkv[kb + p + 32];
    qkv[kb + p]      = (bf16)(k1 * c1 - k2 * s1);
    qkv[kb + p + 32] = (bf16)(k2 * c2 + k1 * s2);
}

// ============ memory softmax: f32 [row][2048] -> bf16 probs, scale 1/16 ============
__global__ __launch_bounds__(256) void mem_softmax(
    const float* __restrict__ ms, bf16* __restrict__ out)
{
    __shared__ float red[4];
    const int row = blockIdx.x, tid = threadIdx.x;
    const float* r = ms + (size_t)row * 2048;
    f32x4 a = *(const f32x4*)(r + tid * 8);
    f32x4 b = *(const f32x4*)(r + tid * 8 + 4);
    float xs[8] = {a.x, a.y, a.z, a.w, b.x, b.y, b.z, b.w};
    float mx = -1e30f;
    #pragma unroll
    for (int i = 0; i < 8; ++i) mx = fmaxf(mx, xs[i]);
    #pragma unroll
    for (int off = 32; off > 0; off >>= 1) mx = fmaxf(mx, __shfl_xor(mx, off));
    if ((tid & 63) == 0) red[tid >> 6] = mx;
    __syncthreads();
    mx = fmaxf(fmaxf(red[0], red[1]), fmaxf(red[2], red[3]));
    __syncthreads();
    float sum = 0.f;
    #pragma unroll
    for (int i = 0; i < 8; ++i) { xs[i] = __expf((xs[i] - mx) * 0.0625f); sum += xs[i]; }
    #pragma unroll
    for (int off = 32; off > 0; off >>= 1) sum += __shfl_xor(sum, off);
    if ((tid & 63) == 0) red[tid >> 6] = sum;
    __syncthreads();
    float inv = 1.f / (red[0] + red[1] + red[2] + red[3]);
    bf16x8 o;
    #pragma unroll
    for (int i = 0; i < 8; ++i) o[i] = (bf16)(xs[i] * inv);
    *(bf16x8*)(out + (size_t)row * 2048 + tid * 8) = o;
}

// ============ strength = sigmoid(h1 @ W_strength) ============
__global__ void strength_kernel(const float* __restrict__ h, const float* __restrict__ ws,
                                float* __restrict__ st)
{
    const int row = blockIdx.x, lane = threadIdx.x;
    const float* hr = h + (size_t)row * D_;
    float s = 0.f;
    #pragma unroll
    for (int it = 0; it < 4; ++it) {
        f32x4 hv = *(const f32x4*)(hr + it * 256 + lane * 4);
        f32x4 wv = *(const f32x4*)(ws + it * 256 + lane * 4);
        s += hv.x * wv.x + hv.y * wv.y + hv.z * wv.z + hv.w * wv.w;
    }
    #pragma unroll
    for (int off = 32; off > 0; off >>= 1) s += __shfl_xor(s, off);
    if (lane == 0) st[row] = sigm(s);
}

// ============ fused memory updates: write full out_k/out_v (+okbf) ============
__global__ void mem_upd_k(const float* __restrict__ ctcp, const float* __restrict__ st,
                          const float* __restrict__ memk, const int* __restrict__ pos,
                          float* __restrict__ outk, bf16* __restrict__ okbf)
{
    int idx = blockIdx.x * 256 + threadIdx.x;   // B*M*DC/4
    int c = (idx & 63) * 4;
    int row = (idx >> 6) & (M_ - 1);
    int b = idx >> 17;
    int s = (row - pos[0]) % M_; if (s < 0) s += M_;
    size_t mi = ((size_t)b * M_ + row) * DC_ + c;
    f32x4 o = *(const f32x4*)(memk + mi);
    if (s < S_) {
        float t = st[b * S_ + s];
        f32x4 cv = *(const f32x4*)(ctcp + ((size_t)b * S_ + s) * 1280 + 1024 + c);
        o.x = t * cv.x + (1.f - t) * o.x; o.y = t * cv.y + (1.f - t) * o.y;
        o.z = t * cv.z + (1.f - t) * o.z; o.w = t * cv.w + (1.f - t) * o.w;
    }
    *(f32x4*)(outk + mi) = o;
    bf16x4 ob = {(bf16)o.x, (bf16)o.y, (bf16)o.z, (bf16)o.w};
    *(bf16x4*)(okbf + mi) = ob;
}

__global__ void mem_upd_v(const float* __restrict__ ctcp, const float* __restrict__ st,
                          const float* __restrict__ memv, const int* __restrict__ pos,
                          float* __restrict__ outv)
{
    int idx = blockIdx.x * 256 + threadIdx.x;   // B*M*D/4
    int c = (idx & 255) * 4;
    int row = (idx >> 8) & (M_ - 1);
    int b = idx >> 19;
    int s = (row - pos[0]) % M_; if (s < 0) s += M_;
    size_t mi = ((size_t)b * M_ + row) * D_ + c;
    f32x4 o = *(const f32x4*)(memv + mi);
    if (s < S_) {
        float t = st[b * S_ + s];
        f32x4 cv = *(const f32x4*)(ctcp + ((size_t)b * S_ + s) * 1280 + c);
        o.x = t * cv.x + (1.f - t) * o.x; o.y = t * cv.y + (1.f - t) * o.y;
        o.z = t * cv.z + (1.f - t) * o.z; o.w = t * cv.w + (1.f - t) * o.w;
    }
    *(f32x4*)(outv + mi) = o;
}

extern "C" void kernel_launch(void* const* d_in, const int* in_sizes, int n_in,
                              void* d_out, int out_size, void* d_ws, size_t ws_size,
                              hipStream_t stream)
{
    const float* h0   = (const float*)d_in[0];
    const float* memk = (const float*)d_in[1];
    const float* memv = (const float*)d_in[2];
    const float* cosp = (const float*)d_in[3];
    const float* sinp = (const float*)d_in[4];
    const float* n1w  = (const float*)d_in[5];
    const float* n2w  = (const float*)d_in[6];
    const float* nmw  = (const float*)d_in[7];
    const float* Wq   = (const float*)d_in[8];
    const float* Wk   = (const float*)d_in[9];
    const float* Wv   = (const float*)d_in[10];
    const float* Wo   = (const float*)d_in[11];
    const float* Wct  = (const float*)d_in[12];
    const float* Wcp  = (const float*)d_in[13];
    const float* Wst  = (const float*)d_in[14];
    const float* Wqr  = (const float*)d_in[15];
    const float* Wg   = (const float*)d_in[16];
    const float* Wpj  = (const float*)d_in[17];
    const float* W1   = (const float*)d_in[18];
    const float* W3   = (const float*)d_in[19];
    const float* W2   = (const float*)d_in[20];
    const int*   pos  = (const int*)d_in[21];

    float* out_h = (float*)d_out;
    float* out_k = out_h + (size_t)NTOK * D_;
    float* out_v = out_k + (size_t)B_ * M_ * DC_;

    char* W = (char*)d_ws;
    const size_t MB = 1u << 20;
    bf16*  qkvb = (bf16*)(W);               // 0..12 MB [2048][3072]
    bf16*  vtb  = (bf16*)(W + 12 * MB);     // 12..16 V^T
    bf16*  nbf  = (bf16*)(W + 16 * MB);     // 16..20 rmsnorm out
    bf16*  abf  = (bf16*)(W + 20 * MB);     // 20..24 attn out
    float* h1b  = (float*)(W + 24 * MB);    // 24..32
    bf16*  catbf= (bf16*)(W + 32 * MB);     // 32..40 [2048][2048] = [h1bf | retr]
    float* ctcp = (float*)(W + 40 * MB);    // 40..50.5 [2048][1280]
    float* stb  = (float*)(W + 51 * MB);    // 8 KB
    float* msb  = (float*)(W + 52 * MB);    // 52..68 mem scores f32
    bf16*  matt = (bf16*)(W + 68 * MB);     // 68..76 mem probs
    bf16*  nvt  = (bf16*)(W + 76 * MB);     // 76..84 new_values^T
    bf16*  a1bf = (bf16*)(W);               // 0..16 MLP act (overlays qkvb+vtb)
    bf16*  okbf = (bf16*)(W + 84 * MB);     // 84..86
    bf16*  qmbf = (bf16*)(W + 86 * MB);     // 86..87
    float* aob  = (float*)(W + 88 * MB);    // 88..96 gate pre-act
    float* h2b  = (float*)(W + 96 * MB);    // 96..104
    bf16*  WqkvT= (bf16*)(W + 104 * MB);    // 104..110
    bf16*  WoT  = (bf16*)(W + 110 * MB);    // 110..112
    bf16*  WctcpT=(bf16*)(W + 112 * MB);    // 112..114.5
    bf16*  WqrT = (bf16*)(W + 115 * MB);    // 115..115.5
    bf16*  WgT  = (bf16*)(W + 116 * MB);    // 116..120
    bf16*  WpjT = (bf16*)(W + 120 * MB);    // 120..122
    bf16*  W13T = (bf16*)(W + 122 * MB);    // 122..138
    bf16*  W2T  = (bf16*)(W + 138 * MB);    // 138..146

    // ---- weight transpose-casts (batched) ----
    {
        TC6 pa;
        pa.in[0] = Wq;  pa.out[0] = WqkvT;
        pa.in[1] = Wk;  pa.out[1] = WqkvT + 1024 * 1024;
        pa.in[2] = Wv;  pa.out[2] = WqkvT + 2048 * 1024;
        pa.in[3] = Wo;  pa.out[3] = WoT;
        pa.in[4] = Wct; pa.out[4] = WctcpT;
        pa.in[5] = Wpj; pa.out[5] = WpjT;
        tcast_b<<<dim3(32, 32, 6), 256, 0, stream>>>(pa, 1024, 1024);
        TC6 pb;
        pb.in[0] = Wcp; pb.out[0] = WctcpT + 1024 * 1024;
        pb.in[1] = Wqr; pb.out[1] = WqrT;
        pb.in[2] = Wcp; pb.out[2] = WctcpT + 1024 * 1024;   // unused z
        pb.in[3] = Wcp; pb.out[3] = WctcpT + 1024 * 1024;
        pb.in[4] = Wcp; pb.out[4] = WctcpT + 1024 * 1024;
        pb.in[5] = Wcp; pb.out[5] = WctcpT + 1024 * 1024;
        tcast_b<<<dim3(8, 32, 2), 256, 0, stream>>>(pb, 256, 1024);
        TC6 pc;
        pc.in[0] = W1; pc.out[0] = W13T;
        pc.in[1] = W3; pc.out[1] = W13T + 4096 * 1024;
        pc.in[2] = W1; pc.out[2] = W13T;
        pc.in[3] = W1; pc.out[3] = W13T;
        pc.in[4] = W1; pc.out[4] = W13T;
        pc.in[5] = W1; pc.out[5] = W13T;
        tcast_b<<<dim3(128, 32, 2), 256, 0, stream>>>(pc, 4096, 1024);
    }
    tcast<float><<<dim3(32, 64, 1), 256, 0, stream>>>(Wg, WgT, 1024, 2048, 0, 0);
    tcast<float><<<dim3(32, 128, 1), 256, 0, stream>>>(W2, W2T, 1024, 4096, 0, 0);

    // ---- 1. rmsnorm; QKV; RoPE; V^T ----
    rmsnorm_bf<<<NTOK, 256, 0, stream>>>(h0, n1w, nbf);
    mgemm<64, 128, true, 0><<<dim3(24, 32, 1), 256, 0, stream>>>(
        nbf, WqkvT, nullptr, qkvb, 1024, 1024, 1024, 3072, 0, 0, 0, nullptr, nullptr);
    rope_kernel<<<(B_ * S_ * H_ * 32) / 256, 256, 0, stream>>>(qkvb, cosp, sinp);
    for (int b = 0; b < B_; ++b)
        tcast<bf16><<<dim3(2, 32, 16), 256, 0, stream>>>(
            qkvb + (size_t)b * S_ * 3072 + 2048, vtb + (size_t)b * 16 * 65536,
            3072, 1024, 64, 65536);

    // ---- 2. fused causal flash attention ----
    flash_attn<<<dim3(S_ / 64, H_, B_), 256, 0, stream>>>(qkvb, vtb, abf);

    // ---- 3. h1 = h0 + attn @ Wo (dual write: f32 h1b + bf16 catbf) ----
    mgemm<64, 64, false, 1><<<dim3(16, 32, 1), 256, 0, stream>>>(
        abf, WoT, h0, h1b, 1024, 1024, 1024, 1024, 0, 0, 0, catbf, nullptr);
    strength_kernel<<<NTOK, 64, 0, stream>>>(h1b, Wst, stb);

    // ---- 4. content|compressed; fused memory update ----
    mgemm<64, 64, false, 0><<<dim3(20, 32, 1), 256, 0, stream>>>(
        catbf, WctcpT, nullptr, ctcp, 1024, 2048, 1024, 1280, 0, 0, 0, nullptr, nullptr);
    mem_upd_k<<<(B_ * M_ * DC_) / 1024, 256, 0, stream>>>(ctcp, stb, memk, pos, out_k, okbf);
    mem_upd_v<<<(B_ * M_ * D_) / 1024, 256, 0, stream>>>(ctcp, stb, memv, pos, out_v);

    // ---- 5. memory attention ----
    rmsnorm_bf<<<NTOK, 256, 0, stream>>>(h1b, nmw, nbf);
    mgemm<64, 64, true, 0><<<dim3(4, 32, 1), 256, 0, stream>>>(
        nbf, WqrT, nullptr, qmbf, 1024, 1024, 1024, 256, 0, 0, 0, nullptr, nullptr);
    mgemm<64, 128, false, 0><<<dim3(16, 16, 2), 256, 0, stream>>>(
        qmbf, okbf, nullptr, msb, 256, 256, 256, 2048,
        (long long)S_ * 256, (long long)M_ * 256, (long long)S_ * 2048, nullptr, nullptr);
    mem_softmax<<<NTOK, 256, 0, stream>>>(msb, matt);
    tcast<float><<<dim3(32, 64, 2), 256, 0, stream>>>(
        out_v, nvt, 1024, 2048, (long long)M_ * 1024, (long long)1024 * 2048);
    mgemm<64, 128, true, 0><<<dim3(8, 16, 2), 256, 0, stream>>>(
        matt, nvt, nullptr, catbf + 1024, 2048, 2048, 2048, 2048,
        (long long)S_ * 2048, (long long)1024 * 2048, (long long)S_ * 2048, nullptr, nullptr);

    // ---- 6. gate GEMM; proj GEMM fused with sigmoid-gate combine ----
    mgemm<64, 64, false, 0><<<dim3(16, 32, 1), 256, 0, stream>>>(
        catbf, WgT, nullptr, aob, 2048, 2048, 2048, 1024, 0, 0, 0, nullptr, nullptr);
    mgemm<64, 64, false, 2><<<dim3(16, 32, 1), 256, 0, stream>>>(
        catbf + 1024, WpjT, nullptr, h2b, 1024, 2048, 1024, 1024, 0, 0, 0, aob, h1b);

    // ---- 7. MLP (fused up+silu-mul, then down) ----
    rmsnorm_bf<<<NTOK, 256, 0, stream>>>(h2b, n2w, nbf);
    mgemm13<<<dim3(64, 16, 1), 256, 0, stream>>>(
        nbf, W13T, W13T + 4096 * 1024, a1bf, 1024, 1024, 1024, 4096);
    mgemm<64, 64, false, 0><<<dim3(16, 32, 1), 256, 0, stream>>>(
        a1bf, W2T, h2b, out_h, 4096, 4096, 4096, 1024, 0, 0, 0, nullptr, nullptr);
}

// Round 7
// 284.276 us; speedup vs baseline: 8.6223x; 1.0439x over previous
//
#include <hip/hip_runtime.h>
#include <hip/hip_bf16.h>
#include <math.h>

typedef __bf16 bf16;
typedef __attribute__((ext_vector_type(8))) __bf16 bf16x8;
typedef __attribute__((ext_vector_type(4))) __bf16 bf16x4;
typedef __attribute__((ext_vector_type(4))) float f32x4;

#define B_ 2
#define S_ 1024
#define D_ 1024
#define H_ 16
#define HD_ 64
#define F_ 4096
#define M_ 2048
#define DC_ 256
#define NTOK (B_*S_)

__device__ __forceinline__ void gload16(const void* g, void* l) {
    __builtin_amdgcn_global_load_lds(
        (__attribute__((address_space(1))) void*)(void*)(g),
        (__attribute__((address_space(3))) void*)(l), 16, 0, 0);
}

template<int N> __device__ __forceinline__ void wait_vm() {
    if constexpr (N == 0)      asm volatile("s_waitcnt vmcnt(0)" ::: "memory");
    else if constexpr (N == 2) asm volatile("s_waitcnt vmcnt(2)" ::: "memory");
    else if constexpr (N == 4) asm volatile("s_waitcnt vmcnt(4)" ::: "memory");
    else if constexpr (N == 6) asm volatile("s_waitcnt vmcnt(6)" ::: "memory");
    else                       asm volatile("s_waitcnt vmcnt(8)" ::: "memory");
}
__device__ __forceinline__ void wait_lgkm0() {
    asm volatile("s_waitcnt lgkmcnt(0)" ::: "memory");
}
__device__ __forceinline__ float sigm(float x) { return 1.f / (1.f + expf(-x)); }

// ============ MFMA GEMM: C[M,N] = A[M,K] @ Bt[N,K]^T (+resid) ============
// BK=64, depth-2 counted-vmcnt pipeline, XOR-swizzled LDS, XCD chunking over
// 8-row bands walked column-major (needs gridDim.y % 8 == 0).
// EPI 0: normal. EPI 1: dual write f32 Cout + bf16 aux1 (ld 2048).
// EPI 2: Cout f32 = aux2[idx] + sigmoid((bf16)aux1[idx]) * acc.
template<int BM, int BN, bool OUTBF, int EPI>
__global__ __launch_bounds__(256) void mgemm(
    const bf16* __restrict__ A, const bf16* __restrict__ Bt,
    const float* __restrict__ resid, void* __restrict__ Cout,
    int K, int lda, int ldb, int ldc,
    long long sA, long long sB, long long sC,
    const void* __restrict__ aux1, const void* __restrict__ aux2)
{
    constexpr int WN   = (BM == 128) ? 2 : 4;
    constexpr int WCOL = BN / WN;
    constexpr int FN   = WCOL / 16;
    constexpr int LA = BM * 64, LB = BN * 64;
    constexpr int LPS = BM / 32 + BN / 32;
    __shared__ bf16 lds[2 * (LA + LB)];
    const int z = blockIdx.z;
    A  += (size_t)z * sA;
    Bt += (size_t)z * sB;
    const int gx = gridDim.x;
    const int nwg = gx * gridDim.y;
    const int flat = blockIdx.y * gx + blockIdx.x;
    const int q8 = nwg >> 3, r8 = nwg & 7;
    const int xcd = flat & 7, lid = flat >> 3;
    const int swz = (xcd < r8 ? xcd * (q8 + 1) : r8 * (q8 + 1) + (xcd - r8) * q8) + lid;
    const int band = swz / (8 * gx);
    const int rem  = swz % (8 * gx);
    const int row0 = (band * 8 + (rem & 7)) * BM;
    const int col0 = (rem >> 3) * BN;
    const int tid = threadIdx.x, wid = tid >> 6, lane = tid & 63;
    const int wr = wid / WN, wc = wid % WN;
    const int srow = lane >> 3;
    const int ssub = (lane & 7) ^ (srow & 7);

    f32x4 acc[4][FN];
    #pragma unroll
    for (int m = 0; m < 4; ++m)
        #pragma unroll
        for (int n = 0; n < FN; ++n) acc[m][n] = (f32x4){0.f, 0.f, 0.f, 0.f};

    auto STAGE = [&](int buf, int k0) {
        bf16* Ab = lds + buf * (LA + LB);
        bf16* Bb = Ab + LA;
        #pragma unroll
        for (int i = 0; i < BM / 32; ++i) {
            int c = wid * (BM / 32) + i;
            gload16(A + (size_t)(row0 + c * 8 + srow) * lda + k0 + ssub * 8, Ab + c * 512);
        }
        #pragma unroll
        for (int i = 0; i < BN / 32; ++i) {
            int c = wid * (BN / 32) + i;
            gload16(Bt + (size_t)(col0 + c * 8 + srow) * ldb + k0 + ssub * 8, Bb + c * 512);
        }
    };

    const int nt = K >> 6;
    STAGE(0, 0);
    if (nt > 1) STAGE(1, 64);
    for (int t = 0; t < nt; ++t) {
        if (t < nt - 1) wait_vm<LPS>();
        else            wait_vm<0>();
        __builtin_amdgcn_sched_barrier(0);
        __builtin_amdgcn_s_barrier();
        __builtin_amdgcn_sched_barrier(0);
        const bf16* Ab = lds + (t & 1) * (LA + LB);
        const bf16* Bb = Ab + LA;
        const int ar = wr * 64 + (lane & 15);
        const int br = wc * WCOL + (lane & 15);
        #pragma unroll
        for (int ksel = 0; ksel < 2; ++ksel) {
            const int ps = ((ksel << 2) + (lane >> 4)) ^ (lane & 7);
            bf16x8 af[4], bfr[FN];
            #pragma unroll
            for (int m = 0; m < 4; ++m)
                af[m] = *(const bf16x8*)(Ab + (ar + m * 16) * 64 + ps * 8);
            #pragma unroll
            for (int n = 0; n < FN; ++n)
                bfr[n] = *(const bf16x8*)(Bb + (br + n * 16) * 64 + ps * 8);
            #pragma unroll
            for (int m = 0; m < 4; ++m)
                #pragma unroll
                for (int n = 0; n < FN; ++n)
                    acc[m][n] = __builtin_amdgcn_mfma_f32_16x16x32_bf16(af[m], bfr[n], acc[m][n], 0, 0, 0);
        }
        wait_lgkm0();
        __builtin_amdgcn_sched_barrier(0);
        __builtin_amdgcn_s_barrier();
        __builtin_amdgcn_sched_barrier(0);
        if (t + 2 < nt) STAGE(t & 1, (t + 2) << 6);
    }
    const int crow = row0 + wr * 64 + ((lane >> 4) << 2);
    const int ccol = col0 + wc * WCOL + (lane & 15);
    #pragma unroll
    for (int m = 0; m < 4; ++m)
        #pragma unroll
        for (int n = 0; n < FN; ++n)
            #pragma unroll
            for (int r = 0; r < 4; ++r) {
                const int rr = crow + m * 16 + r, cc = ccol + n * 16;
                size_t idx = (size_t)rr * ldc + cc;
                float v = acc[m][n][r];
                if (EPI == 2) {
                    float g = sigm((float)((const bf16*)aux1)[idx]);
                    v = ((const float*)aux2)[idx] + g * v;
                    ((float*)Cout)[idx] = v;
                } else {
                    if (resid) v += resid[idx];
                    if (OUTBF) ((bf16*)Cout)[(size_t)z * sC + idx] = (bf16)v;
                    else       ((float*)Cout)[(size_t)z * sC + idx] = v;
                    if (EPI == 1)
                        ((bf16*)aux1)[(size_t)rr * 2048 + cc] = (bf16)v;
                }
            }
}

// ============ Fused MLP-up: a1 = silu(A@W1t^T) * (A@W3t^T), bf16 out ============
__global__ __launch_bounds__(256) void mgemm13(
    const bf16* __restrict__ A, const bf16* __restrict__ B1t, const bf16* __restrict__ B3t,
    bf16* __restrict__ Cout, int K, int lda, int ldb, int ldc)
{
    constexpr int LA = 128 * 64, LB = 64 * 64;
    __shared__ bf16 lds[2 * (LA + 2 * LB)];
    const int gx = gridDim.x;
    const int nwg = gx * gridDim.y;
    const int flat = blockIdx.y * gx + blockIdx.x;
    const int q8 = nwg >> 3, r8 = nwg & 7;
    const int xcd = flat & 7, lid = flat >> 3;
    const int swz = (xcd < r8 ? xcd * (q8 + 1) : r8 * (q8 + 1) + (xcd - r8) * q8) + lid;
    const int band = swz / (8 * gx);
    const int rem  = swz % (8 * gx);
    const int row0 = (band * 8 + (rem & 7)) * 128;
    const int col0 = (rem >> 3) * 64;
    const int tid = threadIdx.x, wid = tid >> 6, lane = tid & 63;
    const int wr = wid >> 1, wc = wid & 1;
    const int srow = lane >> 3;
    const int ssub = (lane & 7) ^ (srow & 7);

    f32x4 acc1[4][2], acc3[4][2];
    #pragma unroll
    for (int m = 0; m < 4; ++m)
        #pragma unroll
        for (int n = 0; n < 2; ++n) {
            acc1[m][n] = (f32x4){0.f, 0.f, 0.f, 0.f};
            acc3[m][n] = (f32x4){0.f, 0.f, 0.f, 0.f};
        }

    auto STAGE = [&](int buf, int k0) {
        bf16* Ab = lds + buf * (LA + 2 * LB);
        bf16* B1b = Ab + LA;
        bf16* B3b = B1b + LB;
        #pragma unroll
        for (int i = 0; i < 4; ++i) {
            int c = wid * 4 + i;
            gload16(A + (size_t)(row0 + c * 8 + srow) * lda + k0 + ssub * 8, Ab + c * 512);
        }
        #pragma unroll
        for (int i = 0; i < 2; ++i) {
            int c = wid * 2 + i;
            gload16(B1t + (size_t)(col0 + c * 8 + srow) * ldb + k0 + ssub * 8, B1b + c * 512);
            gload16(B3t + (size_t)(col0 + c * 8 + srow) * ldb + k0 + ssub * 8, B3b + c * 512);
        }
    };

    const int nt = K >> 6;
    STAGE(0, 0);
    if (nt > 1) STAGE(1, 64);
    for (int t = 0; t < nt; ++t) {
        if (t < nt - 1) wait_vm<8>();
        else            wait_vm<0>();
        __builtin_amdgcn_sched_barrier(0);
        __builtin_amdgcn_s_barrier();
        __builtin_amdgcn_sched_barrier(0);
        const bf16* Ab = lds + (t & 1) * (LA + 2 * LB);
        const bf16* B1b = Ab + LA;
        const bf16* B3b = B1b + LB;
        const int ar = wr * 64 + (lane & 15);
        const int br = wc * 32 + (lane & 15);
        #pragma unroll
        for (int ksel = 0; ksel < 2; ++ksel) {
            const int ps = ((ksel << 2) + (lane >> 4)) ^ (lane & 7);
            bf16x8 af[4], b1f[2], b3f[2];
            #pragma unroll
            for (int m = 0; m < 4; ++m)
                af[m] = *(const bf16x8*)(Ab + (ar + m * 16) * 64 + ps * 8);
            #pragma unroll
            for (int n = 0; n < 2; ++n) {
                b1f[n] = *(const bf16x8*)(B1b + (br + n * 16) * 64 + ps * 8);
                b3f[n] = *(const bf16x8*)(B3b + (br + n * 16) * 64 + ps * 8);
            }
            #pragma unroll
            for (int m = 0; m < 4; ++m)
                #pragma unroll
                for (int n = 0; n < 2; ++n) {
                    acc1[m][n] = __builtin_amdgcn_mfma_f32_16x16x32_bf16(af[m], b1f[n], acc1[m][n], 0, 0, 0);
                    acc3[m][n] = __builtin_amdgcn_mfma_f32_16x16x32_bf16(af[m], b3f[n], acc3[m][n], 0, 0, 0);
                }
        }
        wait_lgkm0();
        __builtin_amdgcn_sched_barrier(0);
        __builtin_amdgcn_s_barrier();
        __builtin_amdgcn_sched_barrier(0);
        if (t + 2 < nt) STAGE(t & 1, (t + 2) << 6);
    }
    const int crow = row0 + wr * 64 + ((lane >> 4) << 2);
    const int ccol = col0 + wc * 32 + (lane & 15);
    #pragma unroll
    for (int m = 0; m < 4; ++m)
        #pragma unroll
        for (int n = 0; n < 2; ++n)
            #pragma unroll
            for (int r = 0; r < 4; ++r) {
                float x = acc1[m][n][r];
                float v = (x * sigm(x)) * acc3[m][n][r];
                Cout[(size_t)(crow + m * 16 + r) * ldc + ccol + n * 16] = (bf16)v;
            }
}

// ============ Fused causal flash attention ============
__global__ __launch_bounds__(256) void flash_attn(
    const bf16* __restrict__ qkv, const bf16* __restrict__ vt,
    bf16* __restrict__ o)
{
    __shared__ bf16 qlds[64 * 64];
    __shared__ bf16 klds[2][64 * 64];
    __shared__ bf16 vlds[2][64 * 64];
    __shared__ bf16 plds[4][16 * 64];
    const int qt = blockIdx.x, hh = blockIdx.y, b = blockIdx.z;
    const int qb0 = qt * 64;
    const int tid = threadIdx.x, wid = tid >> 6, lane = tid & 63;
    const bf16* qg = qkv + (size_t)b * S_ * 3072 + hh * 64;
    const bf16* kg = qg + 1024;
    const bf16* vg = vt + (size_t)(b * H_ + hh) * 64 * 1024;
    const int srow = lane >> 3;
    const int ssub = (lane & 7) ^ (srow & 7);

    #pragma unroll
    for (int i = 0; i < 2; ++i) {
        int c = wid * 2 + i;
        gload16(qg + (size_t)(qb0 + c * 8 + srow) * 3072 + ssub * 8, qlds + c * 512);
    }
    auto STAGE = [&](int buf, int kb) {
        #pragma unroll
        for (int i = 0; i < 2; ++i) {
            int c = wid * 2 + i;
            gload16(kg + (size_t)(kb + c * 8 + srow) * 3072 + ssub * 8, klds[buf] + c * 512);
            gload16(vg + (size_t)(c * 8 + srow) * 1024 + kb + ssub * 8, vlds[buf] + c * 512);
        }
    };

    const int nt = qt + 1;
    STAGE(0, 0);
    if (nt > 1) STAGE(1, 64);

    f32x4 oacc[4];
    #pragma unroll
    for (int n = 0; n < 4; ++n) oacc[n] = (f32x4){0.f, 0.f, 0.f, 0.f};
    float mrow[4] = {-1e30f, -1e30f, -1e30f, -1e30f};
    float lrow[4] = {0.f, 0.f, 0.f, 0.f};
    bf16x8 qf[2];
    bf16* pw = plds[wid];
    const int qlr = (lane >> 4) * 4;

    for (int t = 0; t < nt; ++t) {
        if (t < nt - 1) wait_vm<4>();
        else            wait_vm<0>();
        __builtin_amdgcn_sched_barrier(0);
        __builtin_amdgcn_s_barrier();
        __builtin_amdgcn_sched_barrier(0);
        if (t == 0) {
            const int ar = wid * 16 + (lane & 15);
            #pragma unroll
            for (int ksel = 0; ksel < 2; ++ksel) {
                const int ps = ((ksel << 2) + (lane >> 4)) ^ (lane & 7);
                qf[ksel] = *(const bf16x8*)(qlds + ar * 64 + ps * 8);
            }
        }
        const bf16* Kb = klds[t & 1];
        const bf16* Vb = vlds[t & 1];
        f32x4 sacc[4];
        #pragma unroll
        for (int n = 0; n < 4; ++n) sacc[n] = (f32x4){0.f, 0.f, 0.f, 0.f};
        #pragma unroll
        for (int ksel = 0; ksel < 2; ++ksel) {
            const int ps = ((ksel << 2) + (lane >> 4)) ^ (lane & 7);
            #pragma unroll
            for (int n = 0; n < 4; ++n) {
                bf16x8 kf = *(const bf16x8*)(Kb + (n * 16 + (lane & 15)) * 64 + ps * 8);
                sacc[n] = __builtin_amdgcn_mfma_f32_16x16x32_bf16(qf[ksel], kf, sacc[n], 0, 0, 0);
            }
        }
        if (t == nt - 1) {
            const int qrow = qb0 + wid * 16 + qlr;
            const int kcol = t * 64 + (lane & 15);
            #pragma unroll
            for (int n = 0; n < 4; ++n)
                #pragma unroll
                for (int r = 0; r < 4; ++r)
                    if (kcol + n * 16 > qrow + r) sacc[n][r] = -1e30f;
        }
        #pragma unroll
        for (int r = 0; r < 4; ++r) {
            float mx = fmaxf(fmaxf(sacc[0][r], sacc[1][r]), fmaxf(sacc[2][r], sacc[3][r]));
            #pragma unroll
            for (int off = 8; off > 0; off >>= 1) mx = fmaxf(mx, __shfl_xor(mx, off));
            float mnew = fmaxf(mrow[r], mx);
            float scale = __expf(mrow[r] - mnew);
            float rs = 0.f;
            #pragma unroll
            for (int n = 0; n < 4; ++n) {
                float p = __expf(sacc[n][r] - mnew);
                sacc[n][r] = p;
                rs += p;
            }
            #pragma unroll
            for (int off = 8; off > 0; off >>= 1) rs += __shfl_xor(rs, off);
            lrow[r] = lrow[r] * scale + rs;
            mrow[r] = mnew;
            #pragma unroll
            for (int n = 0; n < 4; ++n) oacc[n][r] *= scale;
        }
        #pragma unroll
        for (int n = 0; n < 4; ++n)
            #pragma unroll
            for (int r = 0; r < 4; ++r) {
                const int qr = qlr + r;
                const int k = n * 16 + (lane & 15);
                const int su = (k >> 3) ^ (qr & 7);
                pw[qr * 64 + su * 8 + (k & 7)] = (bf16)sacc[n][r];
            }
        #pragma unroll
        for (int ksel = 0; ksel < 2; ++ksel) {
            const int ps = ((ksel << 2) + (lane >> 4)) ^ (lane & 7);
            bf16x8 pa = *(const bf16x8*)(pw + (lane & 15) * 64 + ps * 8);
            #pragma unroll
            for (int n = 0; n < 4; ++n) {
                bf16x8 vf = *(const bf16x8*)(Vb + (n * 16 + (lane & 15)) * 64 + ps * 8);
                oacc[n] = __builtin_amdgcn_mfma_f32_16x16x32_bf16(pa, vf, oacc[n], 0, 0, 0);
            }
        }
        wait_lgkm0();
        __builtin_amdgcn_sched_barrier(0);
        __builtin_amdgcn_s_barrier();
        __builtin_amdgcn_sched_barrier(0);
        if (t + 2 < nt) STAGE(t & 1, (t + 2) * 64);
    }
    float inv[4];
    #pragma unroll
    for (int r = 0; r < 4; ++r) inv[r] = 1.f / lrow[r];
    #pragma unroll
    for (int n = 0; n < 4; ++n)
        #pragma unroll
        for (int r = 0; r < 4; ++r) {
            const int q = qb0 + wid * 16 + qlr + r;
            const int d = n * 16 + (lane & 15);
            o[(size_t)(b * S_ + q) * 1024 + hh * 64 + d] = (bf16)(oacc[n][r] * inv[r]);
        }
}

// ============ transpose-cast kernels ============
template<typename TI>
__global__ __launch_bounds__(256) void tcast(
    const TI* __restrict__ in, bf16* __restrict__ out,
    int lin, int lout, long long sin, long long sout)
{
    __shared__ float t[32][33];
    in  += (size_t)blockIdx.z * sin;
    out += (size_t)blockIdx.z * sout;
    const int c0 = blockIdx.x * 32, r0 = blockIdx.y * 32;
    const int tx = threadIdx.x & 31, ty = threadIdx.x >> 5;
    #pragma unroll
    for (int j = 0; j < 4; ++j)
        t[ty + j * 8][tx] = (float)in[(size_t)(r0 + ty + j * 8) * lin + c0 + tx];
    __syncthreads();
    #pragma unroll
    for (int j = 0; j < 4; ++j)
        out[(size_t)(c0 + ty + j * 8) * lout + r0 + tx] = (bf16)t[tx][ty + j * 8];
}

struct TC6 { const float* in[6]; bf16* out[6]; };
__global__ __launch_bounds__(256) void tcast_b(TC6 p, int lin, int lout)
{
    __shared__ float t[32][33];
    const float* in = p.in[blockIdx.z];
    bf16* out = p.out[blockIdx.z];
    const int c0 = blockIdx.x * 32, r0 = blockIdx.y * 32;
    const int tx = threadIdx.x & 31, ty = threadIdx.x >> 5;
    #pragma unroll
    for (int j = 0; j < 4; ++j)
        t[ty + j * 8][tx] = in[(size_t)(r0 + ty + j * 8) * lin + c0 + tx];
    __syncthreads();
    #pragma unroll
    for (int j = 0; j < 4; ++j)
        out[(size_t)(c0 + ty + j * 8) * lout + r0 + tx] = (bf16)t[tx][ty + j * 8];
}

// ============ RMSNorm -> bf16 out ============
__global__ __launch_bounds__(256) void rmsnorm_bf(
    const float* __restrict__ x, const float* __restrict__ w, bf16* __restrict__ out)
{
    __shared__ float red[4];
    const int row = blockIdx.x, tid = threadIdx.x;
    const float* xr = x + (size_t)row * D_;
    f32x4 v = *(const f32x4*)(xr + tid * 4);
    float ss = v.x * v.x + v.y * v.y + v.z * v.z + v.w * v.w;
    #pragma unroll
    for (int off = 32; off > 0; off >>= 1) ss += __shfl_xor(ss, off);
    if ((tid & 63) == 0) red[tid >> 6] = ss;
    __syncthreads();
    float scn = rsqrtf((red[0] + red[1] + red[2] + red[3]) * (1.f / D_) + 1e-6f);
    f32x4 wv = *(const f32x4*)(w + tid * 4);
    bf16x4 o;
    o[0] = (bf16)(v.x * scn * wv.x); o[1] = (bf16)(v.y * scn * wv.y);
    o[2] = (bf16)(v.z * scn * wv.z); o[3] = (bf16)(v.w * scn * wv.w);
    *(bf16x4*)(out + (size_t)row * D_ + tid * 4) = o;
}

// ============ Fused h1 postlude: strength GEMV + rmsnorm(h1, nmw) ============
__global__ __launch_bounds__(256) void h1_post(
    const float* __restrict__ h1, const float* __restrict__ nmw,
    const float* __restrict__ wst, bf16* __restrict__ nbf, float* __restrict__ stb)
{
    __shared__ float red[4], red2[4];
    const int row = blockIdx.x, tid = threadIdx.x;
    const float* xr = h1 + (size_t)row * D_;
    f32x4 v = *(const f32x4*)(xr + tid * 4);
    f32x4 wv = *(const f32x4*)(wst + tid * 4);
    float ss = v.x * v.x + v.y * v.y + v.z * v.z + v.w * v.w;
    float dt = v.x * wv.x + v.y * wv.y + v.z * wv.z + v.w * wv.w;
    #pragma unroll
    for (int off = 32; off > 0; off >>= 1) {
        ss += __shfl_xor(ss, off);
        dt += __shfl_xor(dt, off);
    }
    if ((tid & 63) == 0) { red[tid >> 6] = ss; red2[tid >> 6] = dt; }
    __syncthreads();
    float scn = rsqrtf((red[0] + red[1] + red[2] + red[3]) * (1.f / D_) + 1e-6f);
    f32x4 nw = *(const f32x4*)(nmw + tid * 4);
    bf16x4 o;
    o[0] = (bf16)(v.x * scn * nw.x); o[1] = (bf16)(v.y * scn * nw.y);
    o[2] = (bf16)(v.z * scn * nw.z); o[3] = (bf16)(v.w * scn * nw.w);
    *(bf16x4*)(nbf + (size_t)row * D_ + tid * 4) = o;
    if (tid == 0) stb[row] = sigm(red2[0] + red2[1] + red2[2] + red2[3]);
}

// ============ Fused RoPE (q,k in-place) + V^T staging ============
// Grid (S/64, H, B), 256 thr. vt[(b*H+h)][64 d][1024 s].
__global__ __launch_bounds__(256) void rope_vt(
    bf16* __restrict__ qkv, const float* __restrict__ cosp,
    const float* __restrict__ sinp, bf16* __restrict__ vt)
{
    __shared__ bf16 vl[64][72];
    const int st = blockIdx.x, hh = blockIdx.y, b = blockIdx.z;
    const int tid = threadIdx.x;
    const int r = tid >> 2;
    const int p0 = (tid & 3) * 8;
    const int s = st * 64 + r;
    bf16* base = qkv + ((size_t)(b * S_ + s)) * 3072 + hh * 64;
    // rope q and k (pairs p, p+32; q scaled 1/8)
    {
        f32x4 c1a = *(const f32x4*)(cosp + s * 64 + p0);
        f32x4 c1b = *(const f32x4*)(cosp + s * 64 + p0 + 4);
        f32x4 s1a = *(const f32x4*)(sinp + s * 64 + p0);
        f32x4 s1b = *(const f32x4*)(sinp + s * 64 + p0 + 4);
        f32x4 c2a = *(const f32x4*)(cosp + s * 64 + p0 + 32);
        f32x4 c2b = *(const f32x4*)(cosp + s * 64 + p0 + 36);
        f32x4 s2a = *(const f32x4*)(sinp + s * 64 + p0 + 32);
        f32x4 s2b = *(const f32x4*)(sinp + s * 64 + p0 + 36);
        float c1[8] = {c1a.x,c1a.y,c1a.z,c1a.w,c1b.x,c1b.y,c1b.z,c1b.w};
        float s1[8] = {s1a.x,s1a.y,s1a.z,s1a.w,s1b.x,s1b.y,s1b.z,s1b.w};
        float c2[8] = {c2a.x,c2a.y,c2a.z,c2a.w,c2b.x,c2b.y,c2b.z,c2b.w};
        float s2[8] = {s2a.x,s2a.y,s2a.z,s2a.w,s2b.x,s2b.y,s2b.z,s2b.w};
        #pragma unroll
        for (int which = 0; which < 2; ++which) {
            bf16* ptr = base + which * 1024;
            bf16x8 x1 = *(const bf16x8*)(ptr + p0);
            bf16x8 x2 = *(const bf16x8*)(ptr + p0 + 32);
            bf16x8 o1, o2;
            float qs = which ? 1.f : 0.125f;
            #pragma unroll
            for (int j = 0; j < 8; ++j) {
                float a = (float)x1[j], bb = (float)x2[j];
                o1[j] = (bf16)((a * c1[j] - bb * s1[j]) * qs);
                o2[j] = (bf16)((bb * c2[j] + a * s2[j]) * qs);
            }
            *(bf16x8*)(ptr + p0) = o1;
            *(bf16x8*)(ptr + p0 + 32) = o2;
        }
    }
    // V transpose via LDS
    {
        const int d0 = (tid & 3) * 16;
        bf16x8 v0 = *(const bf16x8*)(base + 2048 + d0);
        bf16x8 v1 = *(const bf16x8*)(base + 2048 + d0 + 8);
        #pragma unroll
        for (int j = 0; j < 8; ++j) { vl[r][d0 + j] = v0[j]; vl[r][d0 + 8 + j] = v1[j]; }
    }
    __syncthreads();
    {
        const int d = tid >> 2;
        const int sq = (tid & 3) * 16;
        bf16x8 o0, o1;
        #pragma unroll
        for (int j = 0; j < 8; ++j) { o0[j] = vl[sq + j][d]; o1[j] = vl[sq + 8 + j][d]; }
        bf16* dst = vt + (size_t)(b * H_ + hh) * 65536 + (size_t)d * 1024 + st * 64 + sq;
        *(bf16x8*)(dst) = o0;
        *(bf16x8*)(dst + 8) = o1;
    }
}

// ============ memory softmax: bf16 [row][2048] -> bf16 probs, scale 1/16 ============
__global__ __launch_bounds__(256) void mem_softmax(
    const bf16* __restrict__ ms, bf16* __restrict__ out)
{
    __shared__ float red[4];
    const int row = blockIdx.x, tid = threadIdx.x;
    bf16x8 iv = *(const bf16x8*)(ms + (size_t)row * 2048 + tid * 8);
    float xs[8];
    float mx = -1e30f;
    #pragma unroll
    for (int i = 0; i < 8; ++i) { xs[i] = (float)iv[i]; mx = fmaxf(mx, xs[i]); }
    #pragma unroll
    for (int off = 32; off > 0; off >>= 1) mx = fmaxf(mx, __shfl_xor(mx, off));
    if ((tid & 63) == 0) red[tid >> 6] = mx;
    __syncthreads();
    mx = fmaxf(fmaxf(red[0], red[1]), fmaxf(red[2], red[3]));
    __syncthreads();
    float sum = 0.f;
    #pragma unroll
    for (int i = 0; i < 8; ++i) { xs[i] = __expf((xs[i] - mx) * 0.0625f); sum += xs[i]; }
    #pragma unroll
    for (int off = 32; off > 0; off >>= 1) sum += __shfl_xor(sum, off);
    if ((tid & 63) == 0) red[tid >> 6] = sum;
    __syncthreads();
    float inv = 1.f / (red[0] + red[1] + red[2] + red[3]);
    bf16x8 o;
    #pragma unroll
    for (int i = 0; i < 8; ++i) o[i] = (bf16)(xs[i] * inv);
    *(bf16x8*)(out + (size_t)row * 2048 + tid * 8) = o;
}

// ============ merged memory update: out_v, out_k (+okbf bf16) ============
__global__ void mem_upd(const float* __restrict__ ctcp, const float* __restrict__ st,
                        const float* __restrict__ memk, const float* __restrict__ memv,
                        const int* __restrict__ pos,
                        float* __restrict__ outk, float* __restrict__ outv,
                        bf16* __restrict__ okbf)
{
    int idx = blockIdx.x * 256 + threadIdx.x;
    const int NV = B_ * M_ * D_ / 4;
    if (idx < NV) {
        int c = (idx & 255) * 4;
        int row = (idx >> 8) & (M_ - 1);
        int b = idx >> 19;
        int s = (row - pos[0]) % M_; if (s < 0) s += M_;
        size_t mi = ((size_t)b * M_ + row) * D_ + c;
        f32x4 o = *(const f32x4*)(memv + mi);
        if (s < S_) {
            float t = st[b * S_ + s];
            f32x4 cv = *(const f32x4*)(ctcp + ((size_t)b * S_ + s) * 1280 + c);
            o.x = t * cv.x + (1.f - t) * o.x; o.y = t * cv.y + (1.f - t) * o.y;
            o.z = t * cv.z + (1.f - t) * o.z; o.w = t * cv.w + (1.f - t) * o.w;
        }
        *(f32x4*)(outv + mi) = o;
    } else {
        idx -= NV;
        int c = (idx & 63) * 4;
        int row = (idx >> 6) & (M_ - 1);
        int b = idx >> 17;
        int s = (row - pos[0]) % M_; if (s < 0) s += M_;
        size_t mi = ((size_t)b * M_ + row) * DC_ + c;
        f32x4 o = *(const f32x4*)(memk + mi);
        if (s < S_) {
            float t = st[b * S_ + s];
            f32x4 cv = *(const f32x4*)(ctcp + ((size_t)b * S_ + s) * 1280 + 1024 + c);
            o.x = t * cv.x + (1.f - t) * o.x; o.y = t * cv.y + (1.f - t) * o.y;
            o.z = t * cv.z + (1.f - t) * o.z; o.w = t * cv.w + (1.f - t) * o.w;
        }
        *(f32x4*)(outk + mi) = o;
        bf16x4 ob = {(bf16)o.x, (bf16)o.y, (bf16)o.z, (bf16)o.w};
        *(bf16x4*)(okbf + mi) = ob;
    }
}

extern "C" void kernel_launch(void* const* d_in, const int* in_sizes, int n_in,
                              void* d_out, int out_size, void* d_ws, size_t ws_size,
                              hipStream_t stream)
{
    const float* h0   = (const float*)d_in[0];
    const float* memk = (const float*)d_in[1];
    const float* memv = (const float*)d_in[2];
    const float* cosp = (const float*)d_in[3];
    const float* sinp = (const float*)d_in[4];
    const float* n1w  = (const float*)d_in[5];
    const float* n2w  = (const float*)d_in[6];
    const float* nmw  = (const float*)d_in[7];
    const float* Wq   = (const float*)d_in[8];
    const float* Wk   = (const float*)d_in[9];
    const float* Wv   = (const float*)d_in[10];
    const float* Wo   = (const float*)d_in[11];
    const float* Wct  = (const float*)d_in[12];
    const float* Wcp  = (const float*)d_in[13];
    const float* Wst  = (const float*)d_in[14];
    const float* Wqr  = (const float*)d_in[15];
    const float* Wg   = (const float*)d_in[16];
    const float* Wpj  = (const float*)d_in[17];
    const float* W1   = (const float*)d_in[18];
    const float* W3   = (const float*)d_in[19];
    const float* W2   = (const float*)d_in[20];
    const int*   pos  = (const int*)d_in[21];

    float* out_h = (float*)d_out;
    float* out_k = out_h + (size_t)NTOK * D_;
    float* out_v = out_k + (size_t)B_ * M_ * DC_;

    char* W = (char*)d_ws;
    const size_t MB = 1u << 20;
    bf16*  qkvb = (bf16*)(W);               // 0..12 MB [2048][3072]
    bf16*  vtb  = (bf16*)(W + 12 * MB);     // 12..16 V^T
    bf16*  nbf  = (bf16*)(W + 16 * MB);     // 16..20 rmsnorm out
    bf16*  abf  = (bf16*)(W + 20 * MB);     // 20..24 attn out
    float* h1b  = (float*)(W + 24 * MB);    // 24..32
    bf16*  catbf= (bf16*)(W + 32 * MB);     // 32..40 [2048][2048] = [h1bf | retr]
    float* ctcp = (float*)(W + 40 * MB);    // 40..50.5 [2048][1280]
    float* stb  = (float*)(W + 51 * MB);    // 8 KB
    bf16*  msbf = (bf16*)(W + 52 * MB);     // 52..60 mem scores bf16
    bf16*  matt = (bf16*)(W + 68 * MB);     // 68..76 mem probs
    bf16*  nvt  = (bf16*)(W + 76 * MB);     // 76..84 new_values^T
    bf16*  a1bf = (bf16*)(W);               // 0..16 MLP act (overlays qkvb+vtb)
    bf16*  okbf = (bf16*)(W + 84 * MB);     // 84..86
    bf16*  qmbf = (bf16*)(W + 86 * MB);     // 86..87
    bf16*  aobf = (bf16*)(W + 88 * MB);     // 88..92 gate pre-act bf16
    float* h2b  = (float*)(W + 96 * MB);    // 96..104
    bf16*  WqkvT= (bf16*)(W + 104 * MB);    // 104..110
    bf16*  WoT  = (bf16*)(W + 110 * MB);    // 110..112
    bf16*  WctcpT=(bf16*)(W + 112 * MB);    // 112..114.5
    bf16*  WqrT = (bf16*)(W + 115 * MB);    // 115..115.5
    bf16*  WgT  = (bf16*)(W + 116 * MB);    // 116..120
    bf16*  WpjT = (bf16*)(W + 120 * MB);    // 120..122
    bf16*  W13T = (bf16*)(W + 122 * MB);    // 122..138
    bf16*  W2T  = (bf16*)(W + 138 * MB);    // 138..146

    // ---- weight transpose-casts (batched) ----
    {
        TC6 pa;
        pa.in[0] = Wq;  pa.out[0] = WqkvT;
        pa.in[1] = Wk;  pa.out[1] = WqkvT + 1024 * 1024;
        pa.in[2] = Wv;  pa.out[2] = WqkvT + 2048 * 1024;
        pa.in[3] = Wo;  pa.out[3] = WoT;
        pa.in[4] = Wct; pa.out[4] = WctcpT;
        pa.in[5] = Wpj; pa.out[5] = WpjT;
        tcast_b<<<dim3(32, 32, 6), 256, 0, stream>>>(pa, 1024, 1024);
        TC6 pb;
        pb.in[0] = Wcp; pb.out[0] = WctcpT + 1024 * 1024;
        pb.in[1] = Wqr; pb.out[1] = WqrT;
        pb.in[2] = Wcp; pb.out[2] = WctcpT + 1024 * 1024;
        pb.in[3] = Wcp; pb.out[3] = WctcpT + 1024 * 1024;
        pb.in[4] = Wcp; pb.out[4] = WctcpT + 1024 * 1024;
        pb.in[5] = Wcp; pb.out[5] = WctcpT + 1024 * 1024;
        tcast_b<<<dim3(8, 32, 2), 256, 0, stream>>>(pb, 256, 1024);
        TC6 pc;
        pc.in[0] = W1; pc.out[0] = W13T;
        pc.in[1] = W3; pc.out[1] = W13T + 4096 * 1024;
        pc.in[2] = W1; pc.out[2] = W13T;
        pc.in[3] = W1; pc.out[3] = W13T;
        pc.in[4] = W1; pc.out[4] = W13T;
        pc.in[5] = W1; pc.out[5] = W13T;
        tcast_b<<<dim3(128, 32, 2), 256, 0, stream>>>(pc, 4096, 1024);
    }
    tcast<float><<<dim3(32, 64, 1), 256, 0, stream>>>(Wg, WgT, 1024, 2048, 0, 0);
    tcast<float><<<dim3(32, 128, 1), 256, 0, stream>>>(W2, W2T, 1024, 4096, 0, 0);

    // ---- 1. rmsnorm; QKV; fused RoPE + V^T ----
    rmsnorm_bf<<<NTOK, 256, 0, stream>>>(h0, n1w, nbf);
    mgemm<64, 128, true, 0><<<dim3(24, 32, 1), 256, 0, stream>>>(
        nbf, WqkvT, nullptr, qkvb, 1024, 1024, 1024, 3072, 0, 0, 0, nullptr, nullptr);
    rope_vt<<<dim3(S_ / 64, H_, B_), 256, 0, stream>>>(qkvb, cosp, sinp, vtb);

    // ---- 2. fused causal flash attention ----
    flash_attn<<<dim3(S_ / 64, H_, B_), 256, 0, stream>>>(qkvb, vtb, abf);

    // ---- 3. h1 = h0 + attn @ Wo (dual write) + fused strength/rmsnorm ----
    mgemm<64, 64, false, 1><<<dim3(16, 32, 1), 256, 0, stream>>>(
        abf, WoT, h0, h1b, 1024, 1024, 1024, 1024, 0, 0, 0, catbf, nullptr);
    h1_post<<<NTOK, 256, 0, stream>>>(h1b, nmw, Wst, nbf, stb);

    // ---- 4. content|compressed; merged memory update ----
    mgemm<64, 64, false, 0><<<dim3(20, 32, 1), 256, 0, stream>>>(
        catbf, WctcpT, nullptr, ctcp, 1024, 2048, 1024, 1280, 0, 0, 0, nullptr, nullptr);
    mem_upd<<<(B_ * M_ * D_ / 4 + B_ * M_ * DC_ / 4) / 256, 256, 0, stream>>>(
        ctcp, stb, memk, memv, pos, out_k, out_v, okbf);

    // ---- 5. memory attention ----
    mgemm<64, 64, true, 0><<<dim3(4, 32, 1), 256, 0, stream>>>(
        nbf, WqrT, nullptr, qmbf, 1024, 1024, 1024, 256, 0, 0, 0, nullptr, nullptr);
    mgemm<64, 128, true, 0><<<dim3(16, 16, 2), 256, 0, stream>>>(
        qmbf, okbf, nullptr, msbf, 256, 256, 256, 2048,
        (long long)S_ * 256, (long long)M_ * 256, (long long)S_ * 2048, nullptr, nullptr);
    mem_softmax<<<NTOK, 256, 0, stream>>>(msbf, matt);
    tcast<float><<<dim3(32, 64, 2), 256, 0, stream>>>(
        out_v, nvt, 1024, 2048, (long long)M_ * 1024, (long long)1024 * 2048);
    mgemm<64, 128, true, 0><<<dim3(8, 16, 2), 256, 0, stream>>>(
        matt, nvt, nullptr, catbf + 1024, 2048, 2048, 2048, 2048,
        (long long)S_ * 2048, (long long)1024 * 2048, (long long)S_ * 2048, nullptr, nullptr);

    // ---- 6. gate GEMM (bf16 out); proj GEMM fused with gate combine ----
    mgemm<64, 64, true, 0><<<dim3(16, 32, 1), 256, 0, stream>>>(
        catbf, WgT, nullptr, aobf, 2048, 2048, 2048, 1024, 0, 0, 0, nullptr, nullptr);
    mgemm<64, 64, false, 2><<<dim3(16, 32, 1), 256, 0, stream>>>(
        catbf + 1024, WpjT, nullptr, h2b, 1024, 2048, 1024, 1024, 0, 0, 0, aobf, h1b);

    // ---- 7. MLP (fused up+silu-mul, then down) ----
    rmsnorm_bf<<<NTOK, 256, 0, stream>>>(h2b, n2w, nbf);
    mgemm13<<<dim3(64, 16, 1), 256, 0, stream>>>(
        nbf, W13T, W13T + 4096 * 1024, a1bf, 1024, 1024, 1024, 4096);
    mgemm<64, 64, false, 0><<<dim3(16, 32, 1), 256, 0, stream>>>(
        a1bf, W2T, h2b, out_h, 4096, 4096, 4096, 1024, 0, 0, 0, nullptr, nullptr);
}

// Round 8
// 275.055 us; speedup vs baseline: 8.9113x; 1.0335x over previous
//
#include <hip/hip_runtime.h>
#include <hip/hip_bf16.h>
#include <math.h>

typedef __bf16 bf16;
typedef __attribute__((ext_vector_type(8))) __bf16 bf16x8;
typedef __attribute__((ext_vector_type(4))) __bf16 bf16x4;
typedef __attribute__((ext_vector_type(4))) float f32x4;

#define B_ 2
#define S_ 1024
#define D_ 1024
#define H_ 16
#define HD_ 64
#define F_ 4096
#define M_ 2048
#define DC_ 256
#define NTOK (B_*S_)

__device__ __forceinline__ void gload16(const void* g, void* l) {
    __builtin_amdgcn_global_load_lds(
        (__attribute__((address_space(1))) void*)(void*)(g),
        (__attribute__((address_space(3))) void*)(l), 16, 0, 0);
}

template<int N> __device__ __forceinline__ void wait_vm() {
    if constexpr (N == 0)      asm volatile("s_waitcnt vmcnt(0)" ::: "memory");
    else if constexpr (N == 2) asm volatile("s_waitcnt vmcnt(2)" ::: "memory");
    else if constexpr (N == 4) asm volatile("s_waitcnt vmcnt(4)" ::: "memory");
    else if constexpr (N == 6) asm volatile("s_waitcnt vmcnt(6)" ::: "memory");
    else                       asm volatile("s_waitcnt vmcnt(8)" ::: "memory");
}
__device__ __forceinline__ void wait_lgkm0() {
    asm volatile("s_waitcnt lgkmcnt(0)" ::: "memory");
}
__device__ __forceinline__ float sigm(float x) { return 1.f / (1.f + expf(-x)); }

// ============ MFMA GEMM: C[M,N] = A[M,K] @ Bt[N,K]^T (+resid) ============
// BK=64, depth-2 counted-vmcnt pipeline, XOR-swizzled LDS, XCD chunking over
// 8-row bands walked column-major (needs gridDim.y % 8 == 0).
// EPI 0: normal. EPI 1: dual write f32 Cout + bf16 aux1 (ld 2048).
template<int BM, int BN, bool OUTBF, int EPI>
__global__ __launch_bounds__(256) void mgemm(
    const bf16* __restrict__ A, const bf16* __restrict__ Bt,
    const float* __restrict__ resid, void* __restrict__ Cout,
    int K, int lda, int ldb, int ldc,
    long long sA, long long sB, long long sC,
    void* __restrict__ aux1)
{
    constexpr int WN   = (BM == 128) ? 2 : 4;
    constexpr int WCOL = BN / WN;
    constexpr int FN   = WCOL / 16;
    constexpr int LA = BM * 64, LB = BN * 64;
    constexpr int LPS = BM / 32 + BN / 32;
    __shared__ bf16 lds[2 * (LA + LB)];
    const int z = blockIdx.z;
    A  += (size_t)z * sA;
    Bt += (size_t)z * sB;
    const int gx = gridDim.x;
    const int nwg = gx * gridDim.y;
    const int flat = blockIdx.y * gx + blockIdx.x;
    const int q8 = nwg >> 3, r8 = nwg & 7;
    const int xcd = flat & 7, lid = flat >> 3;
    const int swz = (xcd < r8 ? xcd * (q8 + 1) : r8 * (q8 + 1) + (xcd - r8) * q8) + lid;
    const int band = swz / (8 * gx);
    const int rem  = swz % (8 * gx);
    const int row0 = (band * 8 + (rem & 7)) * BM;
    const int col0 = (rem >> 3) * BN;
    const int tid = threadIdx.x, wid = tid >> 6, lane = tid & 63;
    const int wr = wid / WN, wc = wid % WN;
    const int srow = lane >> 3;
    const int ssub = (lane & 7) ^ (srow & 7);

    f32x4 acc[4][FN];
    #pragma unroll
    for (int m = 0; m < 4; ++m)
        #pragma unroll
        for (int n = 0; n < FN; ++n) acc[m][n] = (f32x4){0.f, 0.f, 0.f, 0.f};

    auto STAGE = [&](int buf, int k0) {
        bf16* Ab = lds + buf * (LA + LB);
        bf16* Bb = Ab + LA;
        #pragma unroll
        for (int i = 0; i < BM / 32; ++i) {
            int c = wid * (BM / 32) + i;
            gload16(A + (size_t)(row0 + c * 8 + srow) * lda + k0 + ssub * 8, Ab + c * 512);
        }
        #pragma unroll
        for (int i = 0; i < BN / 32; ++i) {
            int c = wid * (BN / 32) + i;
            gload16(Bt + (size_t)(col0 + c * 8 + srow) * ldb + k0 + ssub * 8, Bb + c * 512);
        }
    };

    const int nt = K >> 6;
    STAGE(0, 0);
    if (nt > 1) STAGE(1, 64);
    for (int t = 0; t < nt; ++t) {
        if (t < nt - 1) wait_vm<LPS>();
        else            wait_vm<0>();
        __builtin_amdgcn_sched_barrier(0);
        __builtin_amdgcn_s_barrier();
        __builtin_amdgcn_sched_barrier(0);
        const bf16* Ab = lds + (t & 1) * (LA + LB);
        const bf16* Bb = Ab + LA;
        const int ar = wr * 64 + (lane & 15);
        const int br = wc * WCOL + (lane & 15);
        #pragma unroll
        for (int ksel = 0; ksel < 2; ++ksel) {
            const int ps = ((ksel << 2) + (lane >> 4)) ^ (lane & 7);
            bf16x8 af[4], bfr[FN];
            #pragma unroll
            for (int m = 0; m < 4; ++m)
                af[m] = *(const bf16x8*)(Ab + (ar + m * 16) * 64 + ps * 8);
            #pragma unroll
            for (int n = 0; n < FN; ++n)
                bfr[n] = *(const bf16x8*)(Bb + (br + n * 16) * 64 + ps * 8);
            #pragma unroll
            for (int m = 0; m < 4; ++m)
                #pragma unroll
                for (int n = 0; n < FN; ++n)
                    acc[m][n] = __builtin_amdgcn_mfma_f32_16x16x32_bf16(af[m], bfr[n], acc[m][n], 0, 0, 0);
        }
        wait_lgkm0();
        __builtin_amdgcn_sched_barrier(0);
        __builtin_amdgcn_s_barrier();
        __builtin_amdgcn_sched_barrier(0);
        if (t + 2 < nt) STAGE(t & 1, (t + 2) << 6);
    }
    const int crow = row0 + wr * 64 + ((lane >> 4) << 2);
    const int ccol = col0 + wc * WCOL + (lane & 15);
    #pragma unroll
    for (int m = 0; m < 4; ++m)
        #pragma unroll
        for (int n = 0; n < FN; ++n)
            #pragma unroll
            for (int r = 0; r < 4; ++r) {
                const int rr = crow + m * 16 + r, cc = ccol + n * 16;
                size_t idx = (size_t)rr * ldc + cc;
                float v = acc[m][n][r];
                if (resid) v += resid[idx];
                if (OUTBF) ((bf16*)Cout)[(size_t)z * sC + idx] = (bf16)v;
                else       ((float*)Cout)[(size_t)z * sC + idx] = v;
                if (EPI == 1)
                    ((bf16*)aux1)[(size_t)rr * 2048 + cc] = (bf16)v;
            }
}

// ============ Merged gate+proj GEMM ============
// gate = cat[2048,2048] @ WgT^T ; proj = retr(=cat cols 1024..) @ WpjT^T
// h2 = h1 + sigmoid(gate) * proj.  BM=64, BN=64, K=2048; proj accumulates
// only on k>=1024 (same A tile, B3 from WpjT at k-1024).
__global__ __launch_bounds__(256) void mgemm_gp(
    const bf16* __restrict__ A, const bf16* __restrict__ B1t, const bf16* __restrict__ B3t,
    const float* __restrict__ h1, float* __restrict__ h2)
{
    constexpr int LA = 64 * 64, LB = 64 * 64;
    __shared__ bf16 lds[2 * (LA + 2 * LB)];
    const int gx = gridDim.x;
    const int nwg = gx * gridDim.y;
    const int flat = blockIdx.y * gx + blockIdx.x;
    const int q8 = nwg >> 3, r8 = nwg & 7;
    const int xcd = flat & 7, lid = flat >> 3;
    const int swz = (xcd < r8 ? xcd * (q8 + 1) : r8 * (q8 + 1) + (xcd - r8) * q8) + lid;
    const int band = swz / (8 * gx);
    const int rem  = swz % (8 * gx);
    const int row0 = (band * 8 + (rem & 7)) * 64;
    const int col0 = (rem >> 3) * 64;
    const int tid = threadIdx.x, wid = tid >> 6, lane = tid & 63;
    const int wc = wid;                 // WN=4, wr=0
    const int srow = lane >> 3;
    const int ssub = (lane & 7) ^ (srow & 7);

    f32x4 acc1[4], acc3[4];
    #pragma unroll
    for (int m = 0; m < 4; ++m) {
        acc1[m] = (f32x4){0.f, 0.f, 0.f, 0.f};
        acc3[m] = (f32x4){0.f, 0.f, 0.f, 0.f};
    }

    auto STAGE = [&](int buf, int tt) {
        bf16* Ab = lds + buf * (LA + 2 * LB);
        bf16* B1b = Ab + LA;
        bf16* B3b = B1b + LB;
        const int k0 = tt << 6;
        #pragma unroll
        for (int i = 0; i < 2; ++i) {
            int c = wid * 2 + i;
            gload16(A + (size_t)(row0 + c * 8 + srow) * 2048 + k0 + ssub * 8, Ab + c * 512);
        }
        #pragma unroll
        for (int i = 0; i < 2; ++i) {
            int c = wid * 2 + i;
            gload16(B1t + (size_t)(col0 + c * 8 + srow) * 2048 + k0 + ssub * 8, B1b + c * 512);
        }
        if (tt >= 16) {
            const int k3 = (tt - 16) << 6;
            #pragma unroll
            for (int i = 0; i < 2; ++i) {
                int c = wid * 2 + i;
                gload16(B3t + (size_t)(col0 + c * 8 + srow) * 1024 + k3 + ssub * 8, B3b + c * 512);
            }
        }
    };

    STAGE(0, 0);
    STAGE(1, 1);
    for (int t = 0; t < 32; ++t) {
        if (t < 31) { if (t + 1 >= 16) wait_vm<6>(); else wait_vm<4>(); }
        else wait_vm<0>();
        __builtin_amdgcn_sched_barrier(0);
        __builtin_amdgcn_s_barrier();
        __builtin_amdgcn_sched_barrier(0);
        const bf16* Ab = lds + (t & 1) * (LA + 2 * LB);
        const bf16* B1b = Ab + LA;
        const bf16* B3b = B1b + LB;
        const int ar = lane & 15;
        const int br = wc * 16 + (lane & 15);
        #pragma unroll
        for (int ksel = 0; ksel < 2; ++ksel) {
            const int ps = ((ksel << 2) + (lane >> 4)) ^ (lane & 7);
            bf16x8 af[4], b1f, b3f;
            #pragma unroll
            for (int m = 0; m < 4; ++m)
                af[m] = *(const bf16x8*)(Ab + (ar + m * 16) * 64 + ps * 8);
            b1f = *(const bf16x8*)(B1b + br * 64 + ps * 8);
            #pragma unroll
            for (int m = 0; m < 4; ++m)
                acc1[m] = __builtin_amdgcn_mfma_f32_16x16x32_bf16(af[m], b1f, acc1[m], 0, 0, 0);
            if (t >= 16) {
                b3f = *(const bf16x8*)(B3b + br * 64 + ps * 8);
                #pragma unroll
                for (int m = 0; m < 4; ++m)
                    acc3[m] = __builtin_amdgcn_mfma_f32_16x16x32_bf16(af[m], b3f, acc3[m], 0, 0, 0);
            }
        }
        wait_lgkm0();
        __builtin_amdgcn_sched_barrier(0);
        __builtin_amdgcn_s_barrier();
        __builtin_amdgcn_sched_barrier(0);
        if (t + 2 < 32) STAGE(t & 1, t + 2);
    }
    const int crow = row0 + ((lane >> 4) << 2);
    const int ccol = col0 + wc * 16 + (lane & 15);
    #pragma unroll
    for (int m = 0; m < 4; ++m)
        #pragma unroll
        for (int r = 0; r < 4; ++r) {
            size_t idx = (size_t)(crow + m * 16 + r) * 1024 + ccol;
            h2[idx] = h1[idx] + sigm(acc1[m][r]) * acc3[m][r];
        }
}

// ============ Fused MLP-up: a1 = silu(A@W1t^T) * (A@W3t^T), bf16 out ============
__global__ __launch_bounds__(256) void mgemm13(
    const bf16* __restrict__ A, const bf16* __restrict__ B1t, const bf16* __restrict__ B3t,
    bf16* __restrict__ Cout, int K, int lda, int ldb, int ldc)
{
    constexpr int LA = 128 * 64, LB = 64 * 64;
    __shared__ bf16 lds[2 * (LA + 2 * LB)];
    const int gx = gridDim.x;
    const int nwg = gx * gridDim.y;
    const int flat = blockIdx.y * gx + blockIdx.x;
    const int q8 = nwg >> 3, r8 = nwg & 7;
    const int xcd = flat & 7, lid = flat >> 3;
    const int swz = (xcd < r8 ? xcd * (q8 + 1) : r8 * (q8 + 1) + (xcd - r8) * q8) + lid;
    const int band = swz / (8 * gx);
    const int rem  = swz % (8 * gx);
    const int row0 = (band * 8 + (rem & 7)) * 128;
    const int col0 = (rem >> 3) * 64;
    const int tid = threadIdx.x, wid = tid >> 6, lane = tid & 63;
    const int wr = wid >> 1, wc = wid & 1;
    const int srow = lane >> 3;
    const int ssub = (lane & 7) ^ (srow & 7);

    f32x4 acc1[4][2], acc3[4][2];
    #pragma unroll
    for (int m = 0; m < 4; ++m)
        #pragma unroll
        for (int n = 0; n < 2; ++n) {
            acc1[m][n] = (f32x4){0.f, 0.f, 0.f, 0.f};
            acc3[m][n] = (f32x4){0.f, 0.f, 0.f, 0.f};
        }

    auto STAGE = [&](int buf, int k0) {
        bf16* Ab = lds + buf * (LA + 2 * LB);
        bf16* B1b = Ab + LA;
        bf16* B3b = B1b + LB;
        #pragma unroll
        for (int i = 0; i < 4; ++i) {
            int c = wid * 4 + i;
            gload16(A + (size_t)(row0 + c * 8 + srow) * lda + k0 + ssub * 8, Ab + c * 512);
        }
        #pragma unroll
        for (int i = 0; i < 2; ++i) {
            int c = wid * 2 + i;
            gload16(B1t + (size_t)(col0 + c * 8 + srow) * ldb + k0 + ssub * 8, B1b + c * 512);
            gload16(B3t + (size_t)(col0 + c * 8 + srow) * ldb + k0 + ssub * 8, B3b + c * 512);
        }
    };

    const int nt = K >> 6;
    STAGE(0, 0);
    if (nt > 1) STAGE(1, 64);
    for (int t = 0; t < nt; ++t) {
        if (t < nt - 1) wait_vm<8>();
        else            wait_vm<0>();
        __builtin_amdgcn_sched_barrier(0);
        __builtin_amdgcn_s_barrier();
        __builtin_amdgcn_sched_barrier(0);
        const bf16* Ab = lds + (t & 1) * (LA + 2 * LB);
        const bf16* B1b = Ab + LA;
        const bf16* B3b = B1b + LB;
        const int ar = wr * 64 + (lane & 15);
        const int br = wc * 32 + (lane & 15);
        #pragma unroll
        for (int ksel = 0; ksel < 2; ++ksel) {
            const int ps = ((ksel << 2) + (lane >> 4)) ^ (lane & 7);
            bf16x8 af[4], b1f[2], b3f[2];
            #pragma unroll
            for (int m = 0; m < 4; ++m)
                af[m] = *(const bf16x8*)(Ab + (ar + m * 16) * 64 + ps * 8);
            #pragma unroll
            for (int n = 0; n < 2; ++n) {
                b1f[n] = *(const bf16x8*)(B1b + (br + n * 16) * 64 + ps * 8);
                b3f[n] = *(const bf16x8*)(B3b + (br + n * 16) * 64 + ps * 8);
            }
            #pragma unroll
            for (int m = 0; m < 4; ++m)
                #pragma unroll
                for (int n = 0; n < 2; ++n) {
                    acc1[m][n] = __builtin_amdgcn_mfma_f32_16x16x32_bf16(af[m], b1f[n], acc1[m][n], 0, 0, 0);
                    acc3[m][n] = __builtin_amdgcn_mfma_f32_16x16x32_bf16(af[m], b3f[n], acc3[m][n], 0, 0, 0);
                }
        }
        wait_lgkm0();
        __builtin_amdgcn_sched_barrier(0);
        __builtin_amdgcn_s_barrier();
        __builtin_amdgcn_sched_barrier(0);
        if (t + 2 < nt) STAGE(t & 1, (t + 2) << 6);
    }
    const int crow = row0 + wr * 64 + ((lane >> 4) << 2);
    const int ccol = col0 + wc * 32 + (lane & 15);
    #pragma unroll
    for (int m = 0; m < 4; ++m)
        #pragma unroll
        for (int n = 0; n < 2; ++n)
            #pragma unroll
            for (int r = 0; r < 4; ++r) {
                float x = acc1[m][n][r];
                float v = (x * sigm(x)) * acc3[m][n][r];
                Cout[(size_t)(crow + m * 16 + r) * ldc + ccol + n * 16] = (bf16)v;
            }
}

// ============ Fused causal flash attention ============
__global__ __launch_bounds__(256) void flash_attn(
    const bf16* __restrict__ qkv, const bf16* __restrict__ vt,
    bf16* __restrict__ o)
{
    __shared__ bf16 qlds[64 * 64];
    __shared__ bf16 klds[2][64 * 64];
    __shared__ bf16 vlds[2][64 * 64];
    __shared__ bf16 plds[4][16 * 64];
    const int qt = blockIdx.x, hh = blockIdx.y, b = blockIdx.z;
    const int qb0 = qt * 64;
    const int tid = threadIdx.x, wid = tid >> 6, lane = tid & 63;
    const bf16* qg = qkv + (size_t)b * S_ * 3072 + hh * 64;
    const bf16* kg = qg + 1024;
    const bf16* vg = vt + (size_t)(b * H_ + hh) * 64 * 1024;
    const int srow = lane >> 3;
    const int ssub = (lane & 7) ^ (srow & 7);

    #pragma unroll
    for (int i = 0; i < 2; ++i) {
        int c = wid * 2 + i;
        gload16(qg + (size_t)(qb0 + c * 8 + srow) * 3072 + ssub * 8, qlds + c * 512);
    }
    auto STAGE = [&](int buf, int kb) {
        #pragma unroll
        for (int i = 0; i < 2; ++i) {
            int c = wid * 2 + i;
            gload16(kg + (size_t)(kb + c * 8 + srow) * 3072 + ssub * 8, klds[buf] + c * 512);
            gload16(vg + (size_t)(c * 8 + srow) * 1024 + kb + ssub * 8, vlds[buf] + c * 512);
        }
    };

    const int nt = qt + 1;
    STAGE(0, 0);
    if (nt > 1) STAGE(1, 64);

    f32x4 oacc[4];
    #pragma unroll
    for (int n = 0; n < 4; ++n) oacc[n] = (f32x4){0.f, 0.f, 0.f, 0.f};
    float mrow[4] = {-1e30f, -1e30f, -1e30f, -1e30f};
    float lrow[4] = {0.f, 0.f, 0.f, 0.f};
    bf16x8 qf[2];
    bf16* pw = plds[wid];
    const int qlr = (lane >> 4) * 4;

    for (int t = 0; t < nt; ++t) {
        if (t < nt - 1) wait_vm<4>();
        else            wait_vm<0>();
        __builtin_amdgcn_sched_barrier(0);
        __builtin_amdgcn_s_barrier();
        __builtin_amdgcn_sched_barrier(0);
        if (t == 0) {
            const int ar = wid * 16 + (lane & 15);
            #pragma unroll
            for (int ksel = 0; ksel < 2; ++ksel) {
                const int ps = ((ksel << 2) + (lane >> 4)) ^ (lane & 7);
                qf[ksel] = *(const bf16x8*)(qlds + ar * 64 + ps * 8);
            }
        }
        const bf16* Kb = klds[t & 1];
        const bf16* Vb = vlds[t & 1];
        f32x4 sacc[4];
        #pragma unroll
        for (int n = 0; n < 4; ++n) sacc[n] = (f32x4){0.f, 0.f, 0.f, 0.f};
        #pragma unroll
        for (int ksel = 0; ksel < 2; ++ksel) {
            const int ps = ((ksel << 2) + (lane >> 4)) ^ (lane & 7);
            #pragma unroll
            for (int n = 0; n < 4; ++n) {
                bf16x8 kf = *(const bf16x8*)(Kb + (n * 16 + (lane & 15)) * 64 + ps * 8);
                sacc[n] = __builtin_amdgcn_mfma_f32_16x16x32_bf16(qf[ksel], kf, sacc[n], 0, 0, 0);
            }
        }
        if (t == nt - 1) {
            const int qrow = qb0 + wid * 16 + qlr;
            const int kcol = t * 64 + (lane & 15);
            #pragma unroll
            for (int n = 0; n < 4; ++n)
                #pragma unroll
                for (int r = 0; r < 4; ++r)
                    if (kcol + n * 16 > qrow + r) sacc[n][r] = -1e30f;
        }
        #pragma unroll
        for (int r = 0; r < 4; ++r) {
            float mx = fmaxf(fmaxf(sacc[0][r], sacc[1][r]), fmaxf(sacc[2][r], sacc[3][r]));
            #pragma unroll
            for (int off = 8; off > 0; off >>= 1) mx = fmaxf(mx, __shfl_xor(mx, off));
            float mnew = fmaxf(mrow[r], mx);
            float scale = __expf(mrow[r] - mnew);
            float rs = 0.f;
            #pragma unroll
            for (int n = 0; n < 4; ++n) {
                float p = __expf(sacc[n][r] - mnew);
                sacc[n][r] = p;
                rs += p;
            }
            #pragma unroll
            for (int off = 8; off > 0; off >>= 1) rs += __shfl_xor(rs, off);
            lrow[r] = lrow[r] * scale + rs;
            mrow[r] = mnew;
            #pragma unroll
            for (int n = 0; n < 4; ++n) oacc[n][r] *= scale;
        }
        #pragma unroll
        for (int n = 0; n < 4; ++n)
            #pragma unroll
            for (int r = 0; r < 4; ++r) {
                const int qr = qlr + r;
                const int k = n * 16 + (lane & 15);
                const int su = (k >> 3) ^ (qr & 7);
                pw[qr * 64 + su * 8 + (k & 7)] = (bf16)sacc[n][r];
            }
        #pragma unroll
        for (int ksel = 0; ksel < 2; ++ksel) {
            const int ps = ((ksel << 2) + (lane >> 4)) ^ (lane & 7);
            bf16x8 pa = *(const bf16x8*)(pw + (lane & 15) * 64 + ps * 8);
            #pragma unroll
            for (int n = 0; n < 4; ++n) {
                bf16x8 vf = *(const bf16x8*)(Vb + (n * 16 + (lane & 15)) * 64 + ps * 8);
                oacc[n] = __builtin_amdgcn_mfma_f32_16x16x32_bf16(pa, vf, oacc[n], 0, 0, 0);
            }
        }
        wait_lgkm0();
        __builtin_amdgcn_sched_barrier(0);
        __builtin_amdgcn_s_barrier();
        __builtin_amdgcn_sched_barrier(0);
        if (t + 2 < nt) STAGE(t & 1, (t + 2) * 64);
    }
    float inv[4];
    #pragma unroll
    for (int r = 0; r < 4; ++r) inv[r] = 1.f / lrow[r];
    #pragma unroll
    for (int n = 0; n < 4; ++n)
        #pragma unroll
        for (int r = 0; r < 4; ++r) {
            const int q = qb0 + wid * 16 + qlr + r;
            const int d = n * 16 + (lane & 15);
            o[(size_t)(b * S_ + q) * 1024 + hh * 64 + d] = (bf16)(oacc[n][r] * inv[r]);
        }
}

// ============ single mega transpose-cast: all weights ============
struct TCD { const float* src; bf16* dst; int ct; int rt; int start; };
struct TCA { TCD e[12]; };
__global__ __launch_bounds__(256) void tcast_all(TCA p)
{
    __shared__ float t[32][33];
    const int flat = blockIdx.x;
    int i = 0;
    #pragma unroll
    for (int j = 1; j < 12; ++j) if (flat >= p.e[j].start) i = j;
    const TCD d = p.e[i];
    const int local = flat - d.start;
    const int cx = local % d.ct, ry = local / d.ct;
    const int C = d.ct * 32, R = d.rt * 32;
    const int c0 = cx * 32, r0 = ry * 32;
    const int tx = threadIdx.x & 31, ty = threadIdx.x >> 5;
    #pragma unroll
    for (int j = 0; j < 4; ++j)
        t[ty + j * 8][tx] = d.src[(size_t)(r0 + ty + j * 8) * C + c0 + tx];
    __syncthreads();
    #pragma unroll
    for (int j = 0; j < 4; ++j)
        d.dst[(size_t)(c0 + ty + j * 8) * R + r0 + tx] = (bf16)t[tx][ty + j * 8];
}

// ============ RMSNorm -> bf16 out ============
__global__ __launch_bounds__(256) void rmsnorm_bf(
    const float* __restrict__ x, const float* __restrict__ w, bf16* __restrict__ out)
{
    __shared__ float red[4];
    const int row = blockIdx.x, tid = threadIdx.x;
    const float* xr = x + (size_t)row * D_;
    f32x4 v = *(const f32x4*)(xr + tid * 4);
    float ss = v.x * v.x + v.y * v.y + v.z * v.z + v.w * v.w;
    #pragma unroll
    for (int off = 32; off > 0; off >>= 1) ss += __shfl_xor(ss, off);
    if ((tid & 63) == 0) red[tid >> 6] = ss;
    __syncthreads();
    float scn = rsqrtf((red[0] + red[1] + red[2] + red[3]) * (1.f / D_) + 1e-6f);
    f32x4 wv = *(const f32x4*)(w + tid * 4);
    bf16x4 o;
    o[0] = (bf16)(v.x * scn * wv.x); o[1] = (bf16)(v.y * scn * wv.y);
    o[2] = (bf16)(v.z * scn * wv.z); o[3] = (bf16)(v.w * scn * wv.w);
    *(bf16x4*)(out + (size_t)row * D_ + tid * 4) = o;
}

// ============ Fused h1 postlude: strength GEMV + rmsnorm(h1, nmw) ============
__global__ __launch_bounds__(256) void h1_post(
    const float* __restrict__ h1, const float* __restrict__ nmw,
    const float* __restrict__ wst, bf16* __restrict__ nbf, float* __restrict__ stb)
{
    __shared__ float red[4], red2[4];
    const int row = blockIdx.x, tid = threadIdx.x;
    const float* xr = h1 + (size_t)row * D_;
    f32x4 v = *(const f32x4*)(xr + tid * 4);
    f32x4 wv = *(const f32x4*)(wst + tid * 4);
    float ss = v.x * v.x + v.y * v.y + v.z * v.z + v.w * v.w;
    float dt = v.x * wv.x + v.y * wv.y + v.z * wv.z + v.w * wv.w;
    #pragma unroll
    for (int off = 32; off > 0; off >>= 1) {
        ss += __shfl_xor(ss, off);
        dt += __shfl_xor(dt, off);
    }
    if ((tid & 63) == 0) { red[tid >> 6] = ss; red2[tid >> 6] = dt; }
    __syncthreads();
    float scn = rsqrtf((red[0] + red[1] + red[2] + red[3]) * (1.f / D_) + 1e-6f);
    f32x4 nw = *(const f32x4*)(nmw + tid * 4);
    bf16x4 o;
    o[0] = (bf16)(v.x * scn * nw.x); o[1] = (bf16)(v.y * scn * nw.y);
    o[2] = (bf16)(v.z * scn * nw.z); o[3] = (bf16)(v.w * scn * nw.w);
    *(bf16x4*)(nbf + (size_t)row * D_ + tid * 4) = o;
    if (tid == 0) stb[row] = sigm(red2[0] + red2[1] + red2[2] + red2[3]);
}

// ============ Fused RoPE (q,k in-place) + V^T staging ============
__global__ __launch_bounds__(256) void rope_vt(
    bf16* __restrict__ qkv, const float* __restrict__ cosp,
    const float* __restrict__ sinp, bf16* __restrict__ vt)
{
    __shared__ bf16 vl[64][72];
    const int st = blockIdx.x, hh = blockIdx.y, b = blockIdx.z;
    const int tid = threadIdx.x;
    const int r = tid >> 2;
    const int p0 = (tid & 3) * 8;
    const int s = st * 64 + r;
    bf16* base = qkv + ((size_t)(b * S_ + s)) * 3072 + hh * 64;
    {
        f32x4 c1a = *(const f32x4*)(cosp + s * 64 + p0);
        f32x4 c1b = *(const f32x4*)(cosp + s * 64 + p0 + 4);
        f32x4 s1a = *(const f32x4*)(sinp + s * 64 + p0);
        f32x4 s1b = *(const f32x4*)(sinp + s * 64 + p0 + 4);
        f32x4 c2a = *(const f32x4*)(cosp + s * 64 + p0 + 32);
        f32x4 c2b = *(const f32x4*)(cosp + s * 64 + p0 + 36);
        f32x4 s2a = *(const f32x4*)(sinp + s * 64 + p0 + 32);
        f32x4 s2b = *(const f32x4*)(sinp + s * 64 + p0 + 36);
        float c1[8] = {c1a.x,c1a.y,c1a.z,c1a.w,c1b.x,c1b.y,c1b.z,c1b.w};
        float s1[8] = {s1a.x,s1a.y,s1a.z,s1a.w,s1b.x,s1b.y,s1b.z,s1b.w};
        float c2[8] = {c2a.x,c2a.y,c2a.z,c2a.w,c2b.x,c2b.y,c2b.z,c2b.w};
        float s2[8] = {s2a.x,s2a.y,s2a.z,s2a.w,s2b.x,s2b.y,s2b.z,s2b.w};
        #pragma unroll
        for (int which = 0; which < 2; ++which) {
            bf16* ptr = base + which * 1024;
            bf16x8 x1 = *(const bf16x8*)(ptr + p0);
            bf16x8 x2 = *(const bf16x8*)(ptr + p0 + 32);
            bf16x8 o1, o2;
            float qs = which ? 1.f : 0.125f;
            #pragma unroll
            for (int j = 0; j < 8; ++j) {
                float a = (float)x1[j], bb = (float)x2[j];
                o1[j] = (bf16)((a * c1[j] - bb * s1[j]) * qs);
                o2[j] = (bf16)((bb * c2[j] + a * s2[j]) * qs);
            }
            *(bf16x8*)(ptr + p0) = o1;
            *(bf16x8*)(ptr + p0 + 32) = o2;
        }
    }
    {
        const int d0 = (tid & 3) * 16;
        bf16x8 v0 = *(const bf16x8*)(base + 2048 + d0);
        bf16x8 v1 = *(const bf16x8*)(base + 2048 + d0 + 8);
        #pragma unroll
        for (int j = 0; j < 8; ++j) { vl[r][d0 + j] = v0[j]; vl[r][d0 + 8 + j] = v1[j]; }
    }
    __syncthreads();
    {
        const int d = tid >> 2;
        const int sq = (tid & 3) * 16;
        bf16x8 o0, o1;
        #pragma unroll
        for (int j = 0; j < 8; ++j) { o0[j] = vl[sq + j][d]; o1[j] = vl[sq + 8 + j][d]; }
        bf16* dst = vt + (size_t)(b * H_ + hh) * 65536 + (size_t)d * 1024 + st * 64 + sq;
        *(bf16x8*)(dst) = o0;
        *(bf16x8*)(dst + 8) = o1;
    }
}

// ============ memory softmax: bf16 [row][2048] -> bf16 probs, scale 1/16 ============
__global__ __launch_bounds__(256) void mem_softmax(
    const bf16* __restrict__ ms, bf16* __restrict__ out)
{
    __shared__ float red[4];
    const int row = blockIdx.x, tid = threadIdx.x;
    bf16x8 iv = *(const bf16x8*)(ms + (size_t)row * 2048 + tid * 8);
    float xs[8];
    float mx = -1e30f;
    #pragma unroll
    for (int i = 0; i < 8; ++i) { xs[i] = (float)iv[i]; mx = fmaxf(mx, xs[i]); }
    #pragma unroll
    for (int off = 32; off > 0; off >>= 1) mx = fmaxf(mx, __shfl_xor(mx, off));
    if ((tid & 63) == 0) red[tid >> 6] = mx;
    __syncthreads();
    mx = fmaxf(fmaxf(red[0], red[1]), fmaxf(red[2], red[3]));
    __syncthreads();
    float sum = 0.f;
    #pragma unroll
    for (int i = 0; i < 8; ++i) { xs[i] = __expf((xs[i] - mx) * 0.0625f); sum += xs[i]; }
    #pragma unroll
    for (int off = 32; off > 0; off >>= 1) sum += __shfl_xor(sum, off);
    if ((tid & 63) == 0) red[tid >> 6] = sum;
    __syncthreads();
    float inv = 1.f / (red[0] + red[1] + red[2] + red[3]);
    bf16x8 o;
    #pragma unroll
    for (int i = 0; i < 8; ++i) o[i] = (bf16)(xs[i] * inv);
    *(bf16x8*)(out + (size_t)row * 2048 + tid * 8) = o;
}

// ============ memory update + new_values^T in one pass ============
// grid (20, 32, 2): x<16 -> value tiles (64m x 64d) blending + out_v + nvt^T;
// x>=16 -> key tiles (64m x 64dc) blending + out_k + okbf.
__global__ __launch_bounds__(256) void mem_upd2(
    const bf16* __restrict__ ctcp, const float* __restrict__ st,
    const float* __restrict__ memk, const float* __restrict__ memv,
    const int* __restrict__ pos,
    float* __restrict__ outk, float* __restrict__ outv,
    bf16* __restrict__ okbf, bf16* __restrict__ nvt)
{
    __shared__ float tl[64][65];
    const int dt = blockIdx.x, mt = blockIdx.y, b = blockIdx.z;
    const int tid = threadIdx.x;
    const int r = tid >> 2, q = tid & 3;
    const int m = mt * 64 + r;
    int s = (m - pos[0]) % M_; if (s < 0) s += M_;
    const bool upd = (s < S_);
    const float t = upd ? st[b * S_ + s] : 0.f;
    float res[16];
    if (dt < 16) {
        const int c0 = dt * 64 + q * 16;
        size_t vi = ((size_t)b * M_ + m) * D_ + c0;
        #pragma unroll
        for (int j = 0; j < 4; ++j) {
            f32x4 o = *(const f32x4*)(memv + vi + j * 4);
            res[4*j] = o.x; res[4*j+1] = o.y; res[4*j+2] = o.z; res[4*j+3] = o.w;
        }
        if (upd) {
            const bf16* cp = ctcp + ((size_t)(b * S_ + s)) * 1280 + c0;
            bf16x8 ca = *(const bf16x8*)cp;
            bf16x8 cb = *(const bf16x8*)(cp + 8);
            #pragma unroll
            for (int j = 0; j < 8; ++j) {
                res[j]     = t * (float)ca[j] + (1.f - t) * res[j];
                res[8 + j] = t * (float)cb[j] + (1.f - t) * res[8 + j];
            }
        }
        #pragma unroll
        for (int j = 0; j < 4; ++j) {
            f32x4 o = {res[4*j], res[4*j+1], res[4*j+2], res[4*j+3]};
            *(f32x4*)(outv + vi + j * 4) = o;
        }
        #pragma unroll
        for (int j = 0; j < 16; ++j) tl[r][q * 16 + j] = res[j];
        __syncthreads();
        const int rd = tid >> 2;
        bf16x8 oa, ob;
        #pragma unroll
        for (int j = 0; j < 8; ++j) {
            oa[j] = (bf16)tl[q * 16 + j][rd];
            ob[j] = (bf16)tl[q * 16 + 8 + j][rd];
        }
        bf16* dst = nvt + (size_t)b * 1024 * 2048 + (size_t)(dt * 64 + rd) * 2048 + mt * 64 + q * 16;
        *(bf16x8*)dst = oa;
        *(bf16x8*)(dst + 8) = ob;
    } else {
        const int c0 = (dt - 16) * 64 + q * 16;
        size_t ki = ((size_t)b * M_ + m) * DC_ + c0;
        #pragma unroll
        for (int j = 0; j < 4; ++j) {
            f32x4 o = *(const f32x4*)(memk + ki + j * 4);
            res[4*j] = o.x; res[4*j+1] = o.y; res[4*j+2] = o.z; res[4*j+3] = o.w;
        }
        if (upd) {
            const bf16* cp = ctcp + ((size_t)(b * S_ + s)) * 1280 + 1024 + c0;
            bf16x8 ca = *(const bf16x8*)cp;
            bf16x8 cb = *(const bf16x8*)(cp + 8);
            #pragma unroll
            for (int j = 0; j < 8; ++j) {
                res[j]     = t * (float)ca[j] + (1.f - t) * res[j];
                res[8 + j] = t * (float)cb[j] + (1.f - t) * res[8 + j];
            }
        }
        bf16x8 oa, ob;
        #pragma unroll
        for (int j = 0; j < 4; ++j) {
            f32x4 o = {res[4*j], res[4*j+1], res[4*j+2], res[4*j+3]};
            *(f32x4*)(outk + ki + j * 4) = o;
        }
        #pragma unroll
        for (int j = 0; j < 8; ++j) { oa[j] = (bf16)res[j]; ob[j] = (bf16)res[8 + j]; }
        *(bf16x8*)(okbf + ki) = oa;
        *(bf16x8*)(okbf + ki + 8) = ob;
    }
}

extern "C" void kernel_launch(void* const* d_in, const int* in_sizes, int n_in,
                              void* d_out, int out_size, void* d_ws, size_t ws_size,
                              hipStream_t stream)
{
    const float* h0   = (const float*)d_in[0];
    const float* memk = (const float*)d_in[1];
    const float* memv = (const float*)d_in[2];
    const float* cosp = (const float*)d_in[3];
    const float* sinp = (const float*)d_in[4];
    const float* n1w  = (const float*)d_in[5];
    const float* n2w  = (const float*)d_in[6];
    const float* nmw  = (const float*)d_in[7];
    const float* Wq   = (const float*)d_in[8];
    const float* Wk   = (const float*)d_in[9];
    const float* Wv   = (const float*)d_in[10];
    const float* Wo   = (const float*)d_in[11];
    const float* Wct  = (const float*)d_in[12];
    const float* Wcp  = (const float*)d_in[13];
    const float* Wst  = (const float*)d_in[14];
    const float* Wqr  = (const float*)d_in[15];
    const float* Wg   = (const float*)d_in[16];
    const float* Wpj  = (const float*)d_in[17];
    const float* W1   = (const float*)d_in[18];
    const float* W3   = (const float*)d_in[19];
    const float* W2   = (const float*)d_in[20];
    const int*   pos  = (const int*)d_in[21];

    float* out_h = (float*)d_out;
    float* out_k = out_h + (size_t)NTOK * D_;
    float* out_v = out_k + (size_t)B_ * M_ * DC_;

    char* W = (char*)d_ws;
    const size_t MB = 1u << 20;
    bf16*  qkvb = (bf16*)(W);               // 0..12 MB [2048][3072]
    bf16*  vtb  = (bf16*)(W + 12 * MB);     // 12..16 V^T
    bf16*  nbf  = (bf16*)(W + 16 * MB);     // 16..20 rmsnorm out
    bf16*  abf  = (bf16*)(W + 20 * MB);     // 20..24 attn out
    float* h1b  = (float*)(W + 24 * MB);    // 24..32
    bf16*  catbf= (bf16*)(W + 32 * MB);     // 32..40 [2048][2048] = [h1bf | retr]
    bf16*  ctcp = (bf16*)(W + 40 * MB);     // 40..45 bf16 [2048][1280]
    float* stb  = (float*)(W + 51 * MB);    // 8 KB
    bf16*  msbf = (bf16*)(W + 52 * MB);     // 52..60 mem scores bf16
    bf16*  matt = (bf16*)(W + 68 * MB);     // 68..76 mem probs
    bf16*  nvt  = (bf16*)(W + 76 * MB);     // 76..84 new_values^T
    bf16*  a1bf = (bf16*)(W);               // 0..16 MLP act (overlays qkvb+vtb)
    bf16*  okbf = (bf16*)(W + 84 * MB);     // 84..86
    bf16*  qmbf = (bf16*)(W + 86 * MB);     // 86..87
    float* h2b  = (float*)(W + 96 * MB);    // 96..104
    bf16*  WqkvT= (bf16*)(W + 104 * MB);    // 104..110
    bf16*  WoT  = (bf16*)(W + 110 * MB);    // 110..112
    bf16*  WctcpT=(bf16*)(W + 112 * MB);    // 112..114.5
    bf16*  WqrT = (bf16*)(W + 115 * MB);    // 115..115.5
    bf16*  WgT  = (bf16*)(W + 116 * MB);    // 116..120
    bf16*  WpjT = (bf16*)(W + 120 * MB);    // 120..122
    bf16*  W13T = (bf16*)(W + 122 * MB);    // 122..138
    bf16*  W2T  = (bf16*)(W + 138 * MB);    // 138..146

    // ---- single mega weight transpose-cast ----
    {
        TCA p;
        auto set = [&](int i, const float* s, bf16* d, int ct, int rt, int st_) {
            p.e[i].src = s; p.e[i].dst = d; p.e[i].ct = ct; p.e[i].rt = rt; p.e[i].start = st_;
        };
        int off = 0;
        set(0,  Wq,  WqkvT,               32, 32,  off); off += 1024;
        set(1,  Wk,  WqkvT + 1024 * 1024, 32, 32,  off); off += 1024;
        set(2,  Wv,  WqkvT + 2048 * 1024, 32, 32,  off); off += 1024;
        set(3,  Wo,  WoT,                 32, 32,  off); off += 1024;
        set(4,  Wct, WctcpT,              32, 32,  off); off += 1024;
        set(5,  Wpj, WpjT,                32, 32,  off); off += 1024;
        set(6,  Wcp, WctcpT + 1024 * 1024, 8, 32,  off); off += 256;
        set(7,  Wqr, WqrT,                 8, 32,  off); off += 256;
        set(8,  Wg,  WgT,                 32, 64,  off); off += 2048;
        set(9,  W1,  W13T,               128, 32,  off); off += 4096;
        set(10, W3,  W13T + 4096 * 1024, 128, 32,  off); off += 4096;
        set(11, W2,  W2T,                 32, 128, off); off += 4096;
        tcast_all<<<off, 256, 0, stream>>>(p);
    }

    // ---- 1. rmsnorm; QKV; fused RoPE + V^T ----
    rmsnorm_bf<<<NTOK, 256, 0, stream>>>(h0, n1w, nbf);
    mgemm<64, 128, true, 0><<<dim3(24, 32, 1), 256, 0, stream>>>(
        nbf, WqkvT, nullptr, qkvb, 1024, 1024, 1024, 3072, 0, 0, 0, nullptr);
    rope_vt<<<dim3(S_ / 64, H_, B_), 256, 0, stream>>>(qkvb, cosp, sinp, vtb);

    // ---- 2. fused causal flash attention ----
    flash_attn<<<dim3(S_ / 64, H_, B_), 256, 0, stream>>>(qkvb, vtb, abf);

    // ---- 3. h1 = h0 + attn @ Wo (dual write) + fused strength/rmsnorm ----
    mgemm<64, 64, false, 1><<<dim3(16, 32, 1), 256, 0, stream>>>(
        abf, WoT, h0, h1b, 1024, 1024, 1024, 1024, 0, 0, 0, catbf);
    h1_post<<<NTOK, 256, 0, stream>>>(h1b, nmw, Wst, nbf, stb);

    // ---- 4. content|compressed (bf16); memory update + nvt ----
    mgemm<64, 64, true, 0><<<dim3(20, 32, 1), 256, 0, stream>>>(
        catbf, WctcpT, nullptr, ctcp, 1024, 2048, 1024, 1280, 0, 0, 0, nullptr);
    mem_upd2<<<dim3(20, 32, 2), 256, 0, stream>>>(
        ctcp, stb, memk, memv, pos, out_k, out_v, okbf, nvt);

    // ---- 5. memory attention ----
    mgemm<64, 64, true, 0><<<dim3(4, 32, 1), 256, 0, stream>>>(
        nbf, WqrT, nullptr, qmbf, 1024, 1024, 1024, 256, 0, 0, 0, nullptr);
    mgemm<64, 128, true, 0><<<dim3(16, 16, 2), 256, 0, stream>>>(
        qmbf, okbf, nullptr, msbf, 256, 256, 256, 2048,
        (long long)S_ * 256, (long long)M_ * 256, (long long)S_ * 2048, nullptr);
    mem_softmax<<<NTOK, 256, 0, stream>>>(msbf, matt);
    mgemm<64, 128, true, 0><<<dim3(8, 16, 2), 256, 0, stream>>>(
        matt, nvt, nullptr, catbf + 1024, 2048, 2048, 2048, 2048,
        (long long)S_ * 2048, (long long)1024 * 2048, (long long)S_ * 2048, nullptr);

    // ---- 6. merged gate+proj GEMM with sigmoid-gate combine ----
    mgemm_gp<<<dim3(16, 32, 1), 256, 0, stream>>>(catbf, WgT, WpjT, h1b, h2b);

    // ---- 7. MLP (fused up+silu-mul, then down) ----
    rmsnorm_bf<<<NTOK, 256, 0, stream>>>(h2b, n2w, nbf);
    mgemm13<<<dim3(64, 16, 1), 256, 0, stream>>>(
        nbf, W13T, W13T + 4096 * 1024, a1bf, 1024, 1024, 1024, 4096);
    mgemm<64, 64, false, 0><<<dim3(16, 32, 1), 256, 0, stream>>>(
        a1bf, W2T, h2b, out_h, 4096, 4096, 4096, 1024, 0, 0, 0, nullptr);
}